// Round 2
// 1357.873 us; speedup vs baseline: 2.4045x; 2.4045x over previous
//
#include <hip/hip_runtime.h>

// ---------------------------------------------------------------------------
// MoE transformer block, MI355X. Round 6: all GEMM-shaped kernels on bf16
// MFMA via __builtin_amdgcn_mfma_f32_16x16x32_bf16 (f32 accumulate).
// Inputs rounded RTNE to bf16 during LDS staging; residuals/softmax/norms f32.
// No inline asm, no HIP vector-helper types (self-contained ext_vector).
//   ws region A [0, 2.10M floats):  xnorm -> attn_out
//   ws region R1 [2.10M, 8.39M):    qkv -> h_pairs -> hs
//   x_ffn_in [8.39M, 10.49M) ; x_ffn [10.49M, 12.58M) ; sc/ints after (~50MB)
// ---------------------------------------------------------------------------

#define S_LEN   1024
#define T_TOT   2048
#define DMODEL  1024
#define NHEADS  16
#define HDIM    64
#define NEXP    16
#define FDIM    512
#define DSH     2048
#define TOPK    4
#define NPAIR   8192

typedef __attribute__((ext_vector_type(4))) float          f32x4;
typedef __attribute__((ext_vector_type(8))) short          s16x8;   // MFMA A/B frag
typedef __attribute__((ext_vector_type(4))) unsigned short u16x4;

__device__ __forceinline__ float sigm(float x) { return 1.0f / (1.0f + __expf(-x)); }

// RTNE f32 -> bf16 (bit trick)
__device__ __forceinline__ unsigned short bf16r(float f) {
    union { float f; unsigned int u; } v; v.f = f;
    unsigned int r = v.u + 0x7fffu + ((v.u >> 16) & 1u);
    return (unsigned short)(r >> 16);
}

__device__ __forceinline__ u16x4 pack4(float a, float b, float c, float d) {
    u16x4 r;
    r.x = bf16r(a); r.y = bf16r(b); r.z = bf16r(c); r.w = bf16r(d);
    return r;
}

__device__ __forceinline__ int pair2tok(int p) {
    return ((p >> 12) << 10) + ((p & 4095) >> 2);
}

// ---------------- RMSNorm (f32 in, f32 out) ----------------
__global__ void rmsnorm_kernel(const float* __restrict__ x,
                               const float* __restrict__ w,
                               float* __restrict__ out) {
    int t = blockIdx.x, tid = threadIdx.x;
    float4 xv = *(const float4*)(x + (size_t)t * DMODEL + tid * 4);
    __shared__ float rb[256];
    rb[tid] = xv.x*xv.x + xv.y*xv.y + xv.z*xv.z + xv.w*xv.w;
    __syncthreads();
    for (int s = 128; s > 0; s >>= 1) { if (tid < s) rb[tid] += rb[tid+s]; __syncthreads(); }
    float scale = rsqrtf(rb[0] * (1.0f/1024.0f) + 1e-5f);
    float4 wv = *(const float4*)(w + tid * 4);
    float4 o;
    o.x = xv.x * scale * wv.x;
    o.y = xv.y * scale * wv.y;
    o.z = xv.z * scale * wv.z;
    o.w = xv.w * scale * wv.w;
    *(float4*)(out + (size_t)t*DMODEL + tid*4) = o;
}

// ---------------- RoPE, in-place on qkv rows (q and k only) ----------------
__global__ void rope_kernel(float* __restrict__ qkv) {
    int t = blockIdx.x, tid = threadIdx.x;
    int s = t & 1023;                 // position within half-sequence
    float* row = qkv + (size_t)t * 3072;
    for (int pp = tid; pp < 512; pp += 256) {
        int h = pp >> 5, i = pp & 31;
        float fr = (float)s * exp2f(-0.41524101186092028f * (float)i);
        float sn, cs;
        sincosf(fr, &sn, &cs);
        int o1 = (h << 6) + i, o2 = o1 + 32;
        float x1 = row[o1], x2 = row[o2];
        row[o1] = x1 * cs + x2 * sn;
        row[o2] = x2 * cs - x1 * sn;
        x1 = row[1024 + o1]; x2 = row[1024 + o2];
        row[1024 + o1] = x1 * cs + x2 * sn;
        row[1024 + o2] = x2 * cs - x1 * sn;
    }
}

// ---------------- flash attention (causal, online softmax) ----------------
__global__ __launch_bounds__(256) void attn_kernel(
        const float* __restrict__ qkv, float* __restrict__ attn_out) {
    int qt = blockIdx.x, h = blockIdx.y;
    __shared__ float Qs[64][68], Ks[64][68], Vs[64][68];
    int tid = threadIdx.x;
    int r = tid >> 2, qd = tid & 3;
    int lane = tid & 63, gbase = lane & ~3;
    for (int idx = tid * 4; idx < 4096; idx += 1024) {
        int rr = idx >> 6, cc = idx & 63;
        int p = qt * 64 + rr;
        int t = ((p & 1) << 10) + (p >> 1);
        *(float4*)&Qs[rr][cc] = *(const float4*)(qkv + (size_t)t * 3072 + (h << 6) + cc);
    }
    float m = -1e30f, l = 0.0f;
    float acc[16];
    #pragma unroll
    for (int a = 0; a < 16; ++a) acc[a] = 0.0f;
    int pq = qt * 64 + r;
    int j0 = qd << 4;
    for (int kb = 0; kb <= qt; ++kb) {
        __syncthreads();
        for (int idx = tid * 4; idx < 4096; idx += 1024) {
            int rr = idx >> 6, cc = idx & 63;
            int p = kb * 64 + rr;
            int t = ((p & 1) << 10) + (p >> 1);
            const float* base = qkv + (size_t)t * 3072 + (h << 6) + cc;
            *(float4*)&Ks[rr][cc] = *(const float4*)(base + 1024);
            *(float4*)&Vs[rr][cc] = *(const float4*)(base + 2048);
        }
        __syncthreads();
        float sv[16];
        #pragma unroll
        for (int jj = 0; jj < 16; ++jj) sv[jj] = 0.0f;
        for (int a = 0; a < 64; a += 4) {
            float4 qa = *(const float4*)&Qs[r][a];
            #pragma unroll
            for (int jj = 0; jj < 16; ++jj) {
                float4 ka = *(const float4*)&Ks[j0 + jj][a];
                sv[jj] += qa.x*ka.x + qa.y*ka.y + qa.z*ka.z + qa.w*ka.w;
            }
        }
        float mloc = -1e30f;
        #pragma unroll
        for (int jj = 0; jj < 16; ++jj) {
            float v = sv[jj] * 0.125f;
            if (kb == qt && (j0 + jj) > r) v = -1e30f;   // causal (diag tile)
            sv[jj] = v;
            mloc = fmaxf(mloc, v);
        }
        mloc = fmaxf(mloc, __shfl_xor(mloc, 1));
        mloc = fmaxf(mloc, __shfl_xor(mloc, 2));
        float mnew = fmaxf(m, mloc);
        float alpha = __expf(m - mnew);
        float psum = 0.0f;
        #pragma unroll
        for (int jj = 0; jj < 16; ++jj) {
            float pv = __expf(sv[jj] - mnew);
            sv[jj] = pv; psum += pv;
        }
        psum += __shfl_xor(psum, 1);
        psum += __shfl_xor(psum, 2);
        l = l * alpha + psum;
        m = mnew;
        #pragma unroll
        for (int a = 0; a < 16; ++a) acc[a] *= alpha;
        #pragma unroll
        for (int g = 0; g < 4; ++g) {
            #pragma unroll
            for (int jj = 0; jj < 16; ++jj) {
                float pv = __shfl(sv[jj], gbase + g);
                const float* vrow = &Vs[g * 16 + jj][j0];
                float4 v0 = *(const float4*)(vrow);
                float4 v1 = *(const float4*)(vrow + 4);
                float4 v2 = *(const float4*)(vrow + 8);
                float4 v3 = *(const float4*)(vrow + 12);
                acc[0]  += pv*v0.x; acc[1]  += pv*v0.y; acc[2]  += pv*v0.z; acc[3]  += pv*v0.w;
                acc[4]  += pv*v1.x; acc[5]  += pv*v1.y; acc[6]  += pv*v1.z; acc[7]  += pv*v1.w;
                acc[8]  += pv*v2.x; acc[9]  += pv*v2.y; acc[10] += pv*v2.z; acc[11] += pv*v2.w;
                acc[12] += pv*v3.x; acc[13] += pv*v3.y; acc[14] += pv*v3.z; acc[15] += pv*v3.w;
            }
        }
    }
    float invl = 1.0f / l;
    int c = pq & 1, sdx = pq >> 1;
    float* op = attn_out + ((size_t)(c * 1024 + sdx) << 10) + (h << 6) + j0;
    #pragma unroll
    for (int a4 = 0; a4 < 4; ++a4) {
        float4 o = make_float4(acc[a4*4+0]*invl, acc[a4*4+1]*invl,
                               acc[a4*4+2]*invl, acc[a4*4+3]*invl);
        *(float4*)(op + a4 * 4) = o;
    }
}

// ---------------- router ----------------
__global__ void router_kernel(const float* __restrict__ xffn,
        const float* __restrict__ p_keys, const float* __restrict__ f_keys,
        const int* __restrict__ p_idx, const int* __restrict__ f_idx,
        const float* __restrict__ p_val, const float* __restrict__ f_val,
        const float* __restrict__ p_bias, const float* __restrict__ f_bias,
        float* __restrict__ sc) {
    int tl = blockIdx.x, hf = blockIdx.y;
    int t = hf * 1024 + tl;
    const float* keys = hf ? f_keys : p_keys;
    const int* idx    = hf ? f_idx  : p_idx;
    const float* val  = hf ? f_val  : p_val;
    const float* bias = hf ? f_bias : p_bias;
    int tid = threadIdx.x;
    float acc[16];
    #pragma unroll
    for (int e = 0; e < 16; ++e) acc[e] = 0.0f;
    const float* x = xffn + (size_t)t * DMODEL;
    for (int d = tid; d < 1024; d += 256) {
        float xd = x[d];
        const float* kr = keys + d * 16;
        #pragma unroll
        for (int e4 = 0; e4 < 4; ++e4) {
            float4 kv = *(const float4*)(kr + e4 * 4);
            acc[e4*4+0] += xd * kv.x;
            acc[e4*4+1] += xd * kv.y;
            acc[e4*4+2] += xd * kv.z;
            acc[e4*4+3] += xd * kv.w;
        }
    }
    #pragma unroll
    for (int e = 0; e < 16; ++e) {
        float v = acc[e];
        v += __shfl_down(v, 32); v += __shfl_down(v, 16); v += __shfl_down(v, 8);
        v += __shfl_down(v, 4);  v += __shfl_down(v, 2);  v += __shfl_down(v, 1);
        acc[e] = v;
    }
    __shared__ float part[4][16];
    __shared__ float logit[16];
    __shared__ float sg[4];
    int wave = tid >> 6, ln = tid & 63;
    if (ln == 0) {
        #pragma unroll
        for (int e = 0; e < 16; ++e) part[wave][e] = acc[e];
    }
    __syncthreads();
    if (tid < 16) logit[tid] = part[0][tid] + part[1][tid] + part[2][tid] + part[3][tid];
    __syncthreads();
    if (tid < 4) {
        int ii = idx[tl * 4 + tid];
        float v = val[tl * 4 + tid] + logit[ii] + bias[ii];
        sg[tid] = 1.0f / (1.0f + expf(-v));
    }
    __syncthreads();
    if (tid < 4) {
        float ssum = sg[0] + sg[1] + sg[2] + sg[3];
        sc[t * 4 + tid] = sg[tid] / ssum;
    }
}

// ---------------- expert bucketing (single workgroup) ----------------
__global__ __launch_bounds__(1024) void buckets_kernel(
        const int* __restrict__ p_idx, const int* __restrict__ f_idx,
        int* __restrict__ counts, int* __restrict__ offsets,
        int* __restrict__ pair_p) {
    __shared__ int lcnt[32], loff[32], lcur[32];
    int tid = threadIdx.x;
    if (tid < 32) { lcnt[tid] = 0; lcur[tid] = 0; }
    __syncthreads();
    for (int p = tid; p < NPAIR; p += 1024) {
        int hf = p >> 12, rem = p & 4095;
        int e = (hf ? f_idx : p_idx)[rem];
        atomicAdd(&lcnt[(hf << 4) + e], 1);
    }
    __syncthreads();
    if (tid == 0) {
        int o = 0;
        for (int b = 0; b < 32; ++b) { loff[b] = o; o += lcnt[b]; }
    }
    __syncthreads();
    for (int p = tid; p < NPAIR; p += 1024) {
        int hf = p >> 12, rem = p & 4095;
        int e = (hf ? f_idx : p_idx)[rem];
        int b = (hf << 4) + e;
        int pos = atomicAdd(&lcur[b], 1);
        pair_p[loff[b] + pos] = p;
    }
    if (tid < 32) { counts[tid] = lcnt[tid]; offsets[tid] = loff[tid]; }
}

// ---------------------------------------------------------------------------
// MFMA GEMM: C[M,N] = A[M,K] @ B[K,N], bf16 inputs (converted in staging),
// f32 accumulate. BM=128, BK=32, BN2 in {128,64}. 4 waves, wave tile
// 64 x (BN2/2), 4 x NI frags of 16x16. MODE 0: store; 1: C+= ; 2: C=AB+resid.
// LDS rows stride 40 shorts (=80B, 16B-aligned rows, 2-way max bank alias).
// ---------------------------------------------------------------------------
template<int MODE, int BN2>
__global__ __launch_bounds__(256) void mfma_gemm(
        const float* __restrict__ A, const float* __restrict__ B,
        float* __restrict__ C, const float* __restrict__ resid,
        int M, int N, int K) {
    constexpr int NI = BN2 / 32;
    __shared__ alignas(16) unsigned short As[128][40];
    __shared__ alignas(16) unsigned short Bs[BN2][40];
    int tid = threadIdx.x;
    int m0 = blockIdx.y * 128, n0 = blockIdx.x * BN2;
    int w = tid >> 6, lane = tid & 63;
    int wm = (w >> 1) * 64, wn = (w & 1) * (BN2 / 2);
    int lr = lane & 15, lk = (lane >> 4) << 3;
    int arow = tid >> 3, acol = (tid & 7) << 2;
    f32x4 acc[4][NI] = {};
    for (int k0 = 0; k0 < K; k0 += 32) {
        __syncthreads();
        #pragma unroll
        for (int i = 0; i < 4; ++i) {
            int r = arow + 32 * i;
            float4 v = *(const float4*)(A + (size_t)(m0 + r) * K + k0 + acol);
            *(u16x4*)&As[r][acol] = pack4(v.x, v.y, v.z, v.w);
        }
        if constexpr (BN2 == 128) {
            int bn = (tid & 31) << 2, bk = (tid >> 5) << 2;
            const float* bp = B + (size_t)(k0 + bk) * N + n0 + bn;
            float4 r0 = *(const float4*)(bp);
            float4 r1 = *(const float4*)(bp + N);
            float4 r2 = *(const float4*)(bp + 2 * N);
            float4 r3 = *(const float4*)(bp + 3 * N);
            *(u16x4*)&Bs[bn+0][bk] = pack4(r0.x, r1.x, r2.x, r3.x);
            *(u16x4*)&Bs[bn+1][bk] = pack4(r0.y, r1.y, r2.y, r3.y);
            *(u16x4*)&Bs[bn+2][bk] = pack4(r0.z, r1.z, r2.z, r3.z);
            *(u16x4*)&Bs[bn+3][bk] = pack4(r0.w, r1.w, r2.w, r3.w);
        } else {
            if (tid < 128) {
                int bn = (tid & 15) << 2, bk = (tid >> 4) << 2;
                const float* bp = B + (size_t)(k0 + bk) * N + n0 + bn;
                float4 r0 = *(const float4*)(bp);
                float4 r1 = *(const float4*)(bp + N);
                float4 r2 = *(const float4*)(bp + 2 * N);
                float4 r3 = *(const float4*)(bp + 3 * N);
                *(u16x4*)&Bs[bn+0][bk] = pack4(r0.x, r1.x, r2.x, r3.x);
                *(u16x4*)&Bs[bn+1][bk] = pack4(r0.y, r1.y, r2.y, r3.y);
                *(u16x4*)&Bs[bn+2][bk] = pack4(r0.z, r1.z, r2.z, r3.z);
                *(u16x4*)&Bs[bn+3][bk] = pack4(r0.w, r1.w, r2.w, r3.w);
            }
        }
        __syncthreads();
        s16x8 af[4], bfr[NI];
        #pragma unroll
        for (int mi = 0; mi < 4; ++mi)
            af[mi] = *(const s16x8*)&As[wm + mi * 16 + lr][lk];
        #pragma unroll
        for (int ni = 0; ni < NI; ++ni)
            bfr[ni] = *(const s16x8*)&Bs[wn + ni * 16 + lr][lk];
        #pragma unroll
        for (int mi = 0; mi < 4; ++mi)
            #pragma unroll
            for (int ni = 0; ni < NI; ++ni)
                acc[mi][ni] = __builtin_amdgcn_mfma_f32_16x16x32_bf16(
                                  af[mi], bfr[ni], acc[mi][ni], 0, 0, 0);
    }
    #pragma unroll
    for (int mi = 0; mi < 4; ++mi)
        #pragma unroll
        for (int r = 0; r < 4; ++r) {
            int row = m0 + wm + mi * 16 + ((lane >> 4) << 2) + r;
            size_t rb = (size_t)row * N + n0 + wn + lr;
            #pragma unroll
            for (int ni = 0; ni < NI; ++ni) {
                size_t off = rb + ni * 16;
                float v = acc[mi][ni][r];
                if (MODE == 1) v += C[off];
                if (MODE == 2) v += resid[off];
                C[off] = v;
            }
        }
}

// ---------------------------------------------------------------------------
// MFMA gate+up SwiGLU GEMM. BM=128, BN=64 (per matrix), BK=32.
// MOE=1: gathered A rows (pair buckets), expert weights, out h_pairs[slot].
// MOE=0: dense A (x_ffn), ffn_up (g cols 0..2047, u cols 2048..4095), out hs.
// ---------------------------------------------------------------------------
template<int MOE>
__global__ __launch_bounds__(256) void mfma_gateup(
        const float* __restrict__ X, const float* __restrict__ Wp,
        const float* __restrict__ Wf, const int* __restrict__ pair_p,
        const int* __restrict__ counts, const int* __restrict__ offsets,
        float* __restrict__ Hout) {
    __shared__ alignas(16) unsigned short As[128][40];
    __shared__ alignas(16) unsigned short Bsg[64][40];
    __shared__ alignas(16) unsigned short Bsu[64][40];
    __shared__ int toks[128];
    int tid = threadIdx.x;
    int rem = 128, slot0 = 0, m0 = 0, n0, ldb;
    const float *Wg, *Wu;
    if (MOE) {
        int bucket = blockIdx.y;
        int cnt = counts[bucket];
        int tile0 = blockIdx.x * 128;
        if (tile0 >= cnt) return;
        n0 = blockIdx.z * 64;
        int e = bucket & 15;
        const float* base = (bucket >> 4) ? Wf : Wp;
        Wg = base + (size_t)e * (DMODEL * FDIM) + n0;
        Wu = base + (size_t)(NEXP + e) * (DMODEL * FDIM) + n0;
        ldb = FDIM;
        slot0 = offsets[bucket] + tile0;
        rem = cnt - tile0;
        if (tid < 128)
            toks[tid] = (tid < rem) ? pair2tok(pair_p[slot0 + tid]) : 0;
    } else {
        m0 = blockIdx.y * 128;
        n0 = blockIdx.x * 64;
        Wg = Wp + n0;
        Wu = Wp + DSH + n0;
        ldb = 2 * DSH;
    }
    int w = tid >> 6, lane = tid & 63;
    int wm = (w >> 1) * 64, wn = (w & 1) * 32;
    int lr = lane & 15, lk = (lane >> 4) << 3;
    int arow = tid >> 3, acol = (tid & 7) << 2;
    int t2 = tid & 127, wq = tid >> 7;
    int bn = (t2 & 15) << 2, bk = (t2 >> 4) << 2;
    const float* bsrc = wq ? Wu : Wg;
    f32x4 ag[4][2] = {}, au[4][2] = {};
    for (int k0 = 0; k0 < DMODEL; k0 += 32) {
        __syncthreads();
        #pragma unroll
        for (int i = 0; i < 4; ++i) {
            int r = arow + 32 * i;
            int xrow = MOE ? toks[r] : (m0 + r);
            float4 v = *(const float4*)(X + (size_t)xrow * DMODEL + k0 + acol);
            *(u16x4*)&As[r][acol] = pack4(v.x, v.y, v.z, v.w);
        }
        {
            const float* bp = bsrc + (size_t)(k0 + bk) * ldb + bn;
            float4 r0 = *(const float4*)(bp);
            float4 r1 = *(const float4*)(bp + ldb);
            float4 r2 = *(const float4*)(bp + 2 * ldb);
            float4 r3 = *(const float4*)(bp + 3 * ldb);
            unsigned short (*bl)[40] = wq ? Bsu : Bsg;
            *(u16x4*)&bl[bn+0][bk] = pack4(r0.x, r1.x, r2.x, r3.x);
            *(u16x4*)&bl[bn+1][bk] = pack4(r0.y, r1.y, r2.y, r3.y);
            *(u16x4*)&bl[bn+2][bk] = pack4(r0.z, r1.z, r2.z, r3.z);
            *(u16x4*)&bl[bn+3][bk] = pack4(r0.w, r1.w, r2.w, r3.w);
        }
        __syncthreads();
        s16x8 af[4], bg[2], bu[2];
        #pragma unroll
        for (int mi = 0; mi < 4; ++mi)
            af[mi] = *(const s16x8*)&As[wm + mi * 16 + lr][lk];
        #pragma unroll
        for (int ni = 0; ni < 2; ++ni) {
            bg[ni] = *(const s16x8*)&Bsg[wn + ni * 16 + lr][lk];
            bu[ni] = *(const s16x8*)&Bsu[wn + ni * 16 + lr][lk];
        }
        #pragma unroll
        for (int mi = 0; mi < 4; ++mi)
            #pragma unroll
            for (int ni = 0; ni < 2; ++ni) {
                ag[mi][ni] = __builtin_amdgcn_mfma_f32_16x16x32_bf16(
                                 af[mi], bg[ni], ag[mi][ni], 0, 0, 0);
                au[mi][ni] = __builtin_amdgcn_mfma_f32_16x16x32_bf16(
                                 af[mi], bu[ni], au[mi][ni], 0, 0, 0);
            }
    }
    #pragma unroll
    for (int mi = 0; mi < 4; ++mi)
        #pragma unroll
        for (int r = 0; r < 4; ++r) {
            int rloc = wm + mi * 16 + ((lane >> 4) << 2) + r;
            if (MOE && rloc >= rem) continue;
            size_t rowb = MOE ? (size_t)(slot0 + rloc) * FDIM
                              : (size_t)(m0 + rloc) * DSH;
            #pragma unroll
            for (int ni = 0; ni < 2; ++ni) {
                float g = ag[mi][ni][r], u = au[mi][ni][r];
                Hout[rowb + n0 + wn + ni * 16 + lr] = g * sigm(g) * u;
            }
        }
}

// ---------------------------------------------------------------------------
// MFMA MoE down: y[token] += sc * (h_pairs[slot] @ Wd[e]^T). Wd is [d][f]
// i.e. already N-major (B^T layout) -> stage like A. atomicAdd epilogue.
// ---------------------------------------------------------------------------
__global__ __launch_bounds__(256) void mfma_moe_down(
        const float* __restrict__ h_pairs,
        const float* __restrict__ p_experts, const float* __restrict__ f_experts,
        const int* __restrict__ pair_p, const int* __restrict__ counts,
        const int* __restrict__ offsets, const float* __restrict__ sc,
        float* __restrict__ y) {
    __shared__ alignas(16) unsigned short As[128][40];
    __shared__ alignas(16) unsigned short Bs[128][40];
    __shared__ int   tokd[128];
    __shared__ float scd[128];
    int tid = threadIdx.x;
    int bucket = blockIdx.y;
    int cnt = counts[bucket];
    int tile0 = blockIdx.x * 128;
    if (tile0 >= cnt) return;
    int d0 = blockIdx.z * 128;
    int e = bucket & 15;
    const float* base = (bucket >> 4) ? f_experts : p_experts;
    const float* Wd = base + (size_t)(2 * NEXP + e) * (DMODEL * FDIM);
    int slot0 = offsets[bucket] + tile0;
    int rem = cnt - tile0;
    if (tid < 128) {
        int ok = tid < rem;
        int pr = ok ? pair_p[slot0 + tid] : 0;
        tokd[tid] = pair2tok(pr);
        scd[tid]  = ok ? sc[pr] : 0.0f;
    }
    int w = tid >> 6, lane = tid & 63;
    int wm = (w >> 1) * 64, wn = (w & 1) * 64;
    int lr = lane & 15, lk = (lane >> 4) << 3;
    int arow = tid >> 3, acol = (tid & 7) << 2;
    f32x4 acc[4][4] = {};
    for (int k0 = 0; k0 < FDIM; k0 += 32) {
        __syncthreads();
        #pragma unroll
        for (int i = 0; i < 4; ++i) {
            int r = arow + 32 * i;
            float4 v = *(const float4*)(h_pairs + (size_t)(slot0 + r) * FDIM + k0 + acol);
            *(u16x4*)&As[r][acol] = pack4(v.x, v.y, v.z, v.w);
            float4 b = *(const float4*)(Wd + (size_t)(d0 + r) * FDIM + k0 + acol);
            *(u16x4*)&Bs[r][acol] = pack4(b.x, b.y, b.z, b.w);
        }
        __syncthreads();
        s16x8 af[4], bfr[4];
        #pragma unroll
        for (int mi = 0; mi < 4; ++mi)
            af[mi] = *(const s16x8*)&As[wm + mi * 16 + lr][lk];
        #pragma unroll
        for (int ni = 0; ni < 4; ++ni)
            bfr[ni] = *(const s16x8*)&Bs[wn + ni * 16 + lr][lk];
        #pragma unroll
        for (int mi = 0; mi < 4; ++mi)
            #pragma unroll
            for (int ni = 0; ni < 4; ++ni)
                acc[mi][ni] = __builtin_amdgcn_mfma_f32_16x16x32_bf16(
                                  af[mi], bfr[ni], acc[mi][ni], 0, 0, 0);
    }
    #pragma unroll
    for (int mi = 0; mi < 4; ++mi)
        #pragma unroll
        for (int r = 0; r < 4; ++r) {
            int rloc = wm + mi * 16 + ((lane >> 4) << 2) + r;
            if (rloc < rem) {
                int   t = tokd[rloc];
                float s = scd[rloc];
                float* yp = y + (size_t)t * DMODEL + d0 + wn + lr;
                #pragma unroll
                for (int ni = 0; ni < 4; ++ni)
                    atomicAdd(yp + ni * 16, s * acc[mi][ni][r]);
            }
        }
}

// ===========================================================================
extern "C" void kernel_launch(void* const* d_in, const int* in_sizes, int n_in,
                              void* d_out, int out_size, void* d_ws, size_t ws_size,
                              hipStream_t stream) {
    const float* x_input  = (const float*)d_in[0];
    const int*   p_idx    = (const int*)d_in[1];
    const float* p_val    = (const float*)d_in[2];
    const int*   f_idx    = (const int*)d_in[3];
    const float* f_val    = (const float*)d_in[4];
    const float* attn_w   = (const float*)d_in[5];
    const float* ffn_w    = (const float*)d_in[6];
    const float* W_attn   = (const float*)d_in[7];
    const float* W_attn_o = (const float*)d_in[8];
    const float* ffn_up   = (const float*)d_in[9];
    const float* ffn_down = (const float*)d_in[10];
    const float* p_exp    = (const float*)d_in[11];
    const float* f_exp    = (const float*)d_in[12];
    const float* p_keys   = (const float*)d_in[13];
    const float* f_keys   = (const float*)d_in[14];
    const float* p_bias   = (const float*)d_in[15];
    const float* f_bias   = (const float*)d_in[16];
    float* y32 = (float*)d_out;                 // OUTPUT IS F32, accumulate here
    (void)in_sizes; (void)n_in; (void)out_size; (void)ws_size;

    float* ws = (float*)d_ws;
    // region A [0, 2,097,152): xnorm -> attn_out
    float* xnorm     = ws;
    float* attn_out  = ws;
    // region R1 [2,097,152, 8,388,608): qkv -> h_pairs -> hs
    float* R1        = ws + 2097152;
    float* qkv       = R1;                      // 2048*3072 = 6,291,456
    float* h_pairs   = R1;                      // 8192*512  = 4,194,304
    float* hs        = R1;                      // 2048*2048 = 4,194,304
    float* x_ffn_in  = ws + 8388608;            // 2,097,152
    float* x_ffn     = ws + 10485760;           // 2,097,152
    float* sc        = ws + 12582912;           // 8192
    int*   counts    = (int*)(ws + 12591104);   // 32
    int*   offsets   = counts + 32;             // 32
    int*   pair_p    = offsets + 32;            // 8192   (end ~50.4 MB)

    // 1) attn-input RMSNorm
    rmsnorm_kernel<<<T_TOT, 256, 0, stream>>>(x_input, attn_w, xnorm);
    // 2) QKV projection (MFMA bf16)
    mfma_gemm<0, 128><<<dim3(24, 16), 256, 0, stream>>>(xnorm, W_attn, qkv, nullptr,
                                                        T_TOT, 3072, 1024);
    // 3) RoPE in-place on q,k
    rope_kernel<<<T_TOT, 256, 0, stream>>>(qkv);
    // 4) causal attention (reads qkv, writes region A)
    attn_kernel<<<dim3(32, NHEADS), 256, 0, stream>>>(qkv, attn_out);
    // 5) O-projection + residual (MFMA bf16; BN=64 -> 256 blocks)
    mfma_gemm<2, 64><<<dim3(16, 16), 256, 0, stream>>>(attn_out, W_attn_o, x_ffn_in,
                                                       x_input, T_TOT, 1024, 1024);
    // 6) ffn RMSNorm
    rmsnorm_kernel<<<T_TOT, 256, 0, stream>>>(x_ffn_in, ffn_w, x_ffn);
    // 7) router scores
    router_kernel<<<dim3(1024, 2), 256, 0, stream>>>(x_ffn, p_keys, f_keys,
                                                     p_idx, f_idx, p_val, f_val,
                                                     p_bias, f_bias, sc);
    // 8) expert buckets
    buckets_kernel<<<1, 1024, 0, stream>>>(p_idx, f_idx, counts, offsets, pair_p);
    // 9) MoE gate/up + silu (MFMA; qkv dead; h_pairs into R1)
    mfma_gateup<1><<<dim3(4, 32, 8), 256, 0, stream>>>(x_ffn, p_exp, f_exp,
                                                       pair_p, counts, offsets,
                                                       h_pairs);
    // 10) y (d_out) := x_ffn_in
    hipMemcpyAsync(y32, x_ffn_in, (size_t)T_TOT * DMODEL * sizeof(float),
                   hipMemcpyDeviceToDevice, stream);
    // 11) MoE down: atomic accumulate sc * (h @ Wd^T) into y (MFMA)
    mfma_moe_down<<<dim3(4, 32, 8), 256, 0, stream>>>(h_pairs, p_exp, f_exp,
                                                      pair_p, counts, offsets,
                                                      sc, y32);
    // 12) shared expert gate/up fused (MFMA; hs into R1; h_pairs dead after 11)
    mfma_gateup<0><<<dim3(32, 16), 256, 0, stream>>>(x_ffn, ffn_up, nullptr,
                                                     nullptr, nullptr, nullptr, hs);
    // 13) shared expert down, accumulate into y (MFMA; BN=64 -> 256 blocks)
    mfma_gemm<1, 64><<<dim3(16, 16), 256, 0, stream>>>(hs, ffn_down, y32, nullptr,
                                                       T_TOT, 1024, 2048);
}

// Round 3
// 800.414 us; speedup vs baseline: 4.0791x; 1.6965x over previous
//
#include <hip/hip_runtime.h>

// ---------------------------------------------------------------------------
// MoE transformer block, MI355X. Round 7: attention moved to bf16 MFMA flash
// attention (Q/K/V/P bf16, softmax + accum f32). All GEMMs already MFMA.
//   ws region A [0, 2.10M floats):  xnorm -> attn_out
//   ws region R1 [2.10M, 8.39M):    qkv -> h_pairs -> hs
//   x_ffn_in [8.39M, 10.49M) ; x_ffn [10.49M, 12.58M) ; sc/ints after (~50MB)
// ---------------------------------------------------------------------------

#define S_LEN   1024
#define T_TOT   2048
#define DMODEL  1024
#define NHEADS  16
#define HDIM    64
#define NEXP    16
#define FDIM    512
#define DSH     2048
#define TOPK    4
#define NPAIR   8192

typedef __attribute__((ext_vector_type(4))) float          f32x4;
typedef __attribute__((ext_vector_type(8))) short          s16x8;   // MFMA A/B frag
typedef __attribute__((ext_vector_type(4))) unsigned short u16x4;

__device__ __forceinline__ float sigm(float x) { return 1.0f / (1.0f + __expf(-x)); }

// RTNE f32 -> bf16 (bit trick)
__device__ __forceinline__ unsigned short bf16r(float f) {
    union { float f; unsigned int u; } v; v.f = f;
    unsigned int r = v.u + 0x7fffu + ((v.u >> 16) & 1u);
    return (unsigned short)(r >> 16);
}

__device__ __forceinline__ u16x4 pack4(float a, float b, float c, float d) {
    u16x4 r;
    r.x = bf16r(a); r.y = bf16r(b); r.z = bf16r(c); r.w = bf16r(d);
    return r;
}

__device__ __forceinline__ int pair2tok(int p) {
    return ((p >> 12) << 10) + ((p & 4095) >> 2);
}

// ---------------- RMSNorm (f32 in, f32 out) ----------------
__global__ void rmsnorm_kernel(const float* __restrict__ x,
                               const float* __restrict__ w,
                               float* __restrict__ out) {
    int t = blockIdx.x, tid = threadIdx.x;
    float4 xv = *(const float4*)(x + (size_t)t * DMODEL + tid * 4);
    __shared__ float rb[256];
    rb[tid] = xv.x*xv.x + xv.y*xv.y + xv.z*xv.z + xv.w*xv.w;
    __syncthreads();
    for (int s = 128; s > 0; s >>= 1) { if (tid < s) rb[tid] += rb[tid+s]; __syncthreads(); }
    float scale = rsqrtf(rb[0] * (1.0f/1024.0f) + 1e-5f);
    float4 wv = *(const float4*)(w + tid * 4);
    float4 o;
    o.x = xv.x * scale * wv.x;
    o.y = xv.y * scale * wv.y;
    o.z = xv.z * scale * wv.z;
    o.w = xv.w * scale * wv.w;
    *(float4*)(out + (size_t)t*DMODEL + tid*4) = o;
}

// ---------------- RoPE, in-place on qkv rows (q and k only) ----------------
__global__ void rope_kernel(float* __restrict__ qkv) {
    int t = blockIdx.x, tid = threadIdx.x;
    int s = t & 1023;                 // position within half-sequence
    float* row = qkv + (size_t)t * 3072;
    for (int pp = tid; pp < 512; pp += 256) {
        int h = pp >> 5, i = pp & 31;
        float fr = (float)s * exp2f(-0.41524101186092028f * (float)i);
        float sn, cs;
        sincosf(fr, &sn, &cs);
        int o1 = (h << 6) + i, o2 = o1 + 32;
        float x1 = row[o1], x2 = row[o2];
        row[o1] = x1 * cs + x2 * sn;
        row[o2] = x2 * cs - x1 * sn;
        x1 = row[1024 + o1]; x2 = row[1024 + o2];
        row[1024 + o1] = x1 * cs + x2 * sn;
        row[1024 + o2] = x2 * cs - x1 * sn;
    }
}

// ---------------- MFMA flash attention (causal, online softmax) -------------
// Block = (q-tile of 64 interleaved positions) x head. 4 waves; wave w owns
// q-strip rows [w*16, w*16+16). Frag conventions identical to mfma_gemm
// (verified): A[row][k], B stored transposed [col][k], C/D col=lane&15,
// row=(lane>>4)*4+reg. LDS rows padded to 72 shorts (144B: 4-bank row shift).
__global__ __launch_bounds__(256) void attn_mfma_kernel(
        const float* __restrict__ qkv, float* __restrict__ attn_out) {
    int qt = blockIdx.x, h = blockIdx.y;
    __shared__ alignas(16) unsigned short Qs[64][72];   // [q][d], pre-scaled
    __shared__ alignas(16) unsigned short Ks[64][72];   // [key][d]
    __shared__ alignas(16) unsigned short Vt[64][72];   // [d][key]
    __shared__ alignas(16) unsigned short Ps[4][16][72];// per-wave P strip
    int tid = threadIdx.x;
    int w = tid >> 6, lane = tid & 63;
    int lr = lane & 15, lkg = lane >> 4, lk = lkg << 3;

    // stage Q once (fold 1/sqrt(64) scale into bf16 conversion)
    for (int idx = tid * 4; idx < 4096; idx += 1024) {
        int rr = idx >> 6, cc = idx & 63;
        int p = qt * 64 + rr;
        int t = ((p & 1) << 10) + (p >> 1);
        float4 v = *(const float4*)(qkv + (size_t)t * 3072 + (h << 6) + cc);
        *(u16x4*)&Qs[rr][cc] = pack4(v.x * 0.125f, v.y * 0.125f,
                                     v.z * 0.125f, v.w * 0.125f);
    }
    __syncthreads();
    s16x8 qa0 = *(const s16x8*)&Qs[(w << 4) + lr][lk];
    s16x8 qa1 = *(const s16x8*)&Qs[(w << 4) + lr][32 + lk];

    float m[4], l[4];
    f32x4 oacc[4];
    #pragma unroll
    for (int r = 0; r < 4; ++r) { m[r] = -1e30f; l[r] = 0.0f; }
    #pragma unroll
    for (int df = 0; df < 4; ++df) oacc[df] = (f32x4)0.0f;

    int qrow_base = qt * 64 + w * 16 + lkg * 4;   // + reg

    for (int kb = 0; kb <= qt; ++kb) {
        __syncthreads();
        for (int idx = tid * 4; idx < 4096; idx += 1024) {
            int rr = idx >> 6, cc = idx & 63;
            int p = kb * 64 + rr;
            int t = ((p & 1) << 10) + (p >> 1);
            const float* base = qkv + (size_t)t * 3072 + (h << 6) + cc;
            float4 kv = *(const float4*)(base + 1024);
            *(u16x4*)&Ks[rr][cc] = pack4(kv.x, kv.y, kv.z, kv.w);
            float4 vv = *(const float4*)(base + 2048);
            Vt[cc + 0][rr] = bf16r(vv.x);
            Vt[cc + 1][rr] = bf16r(vv.y);
            Vt[cc + 2][rr] = bf16r(vv.z);
            Vt[cc + 3][rr] = bf16r(vv.w);
        }
        __syncthreads();

        // ---- QK^T: wave strip 16 q-rows x 64 keys ----
        f32x4 s[4];
        #pragma unroll
        for (int nf = 0; nf < 4; ++nf) {
            s16x8 b0 = *(const s16x8*)&Ks[nf * 16 + lr][lk];
            s16x8 b1 = *(const s16x8*)&Ks[nf * 16 + lr][32 + lk];
            f32x4 z = (f32x4)0.0f;
            z = __builtin_amdgcn_mfma_f32_16x16x32_bf16(qa0, b0, z, 0, 0, 0);
            z = __builtin_amdgcn_mfma_f32_16x16x32_bf16(qa1, b1, z, 0, 0, 0);
            s[nf] = z;
        }
        // ---- causal mask (diag tile only; earlier tiles fully valid) ----
        if (kb == qt) {
            #pragma unroll
            for (int nf = 0; nf < 4; ++nf) {
                int kcol = kb * 64 + nf * 16 + lr;
                #pragma unroll
                for (int r = 0; r < 4; ++r)
                    if (kcol > qrow_base + r) s[nf][r] = -1e30f;
            }
        }
        // ---- online softmax (rows are lane-group-local in C layout) ----
        float mloc[4];
        #pragma unroll
        for (int r = 0; r < 4; ++r)
            mloc[r] = fmaxf(fmaxf(s[0][r], s[1][r]), fmaxf(s[2][r], s[3][r]));
        #pragma unroll
        for (int r = 0; r < 4; ++r) {
            mloc[r] = fmaxf(mloc[r], __shfl_xor(mloc[r], 1));
            mloc[r] = fmaxf(mloc[r], __shfl_xor(mloc[r], 2));
            mloc[r] = fmaxf(mloc[r], __shfl_xor(mloc[r], 4));
            mloc[r] = fmaxf(mloc[r], __shfl_xor(mloc[r], 8));
        }
        float alpha[4], psum[4];
        #pragma unroll
        for (int r = 0; r < 4; ++r) {
            float mnew = fmaxf(m[r], mloc[r]);
            alpha[r] = __expf(m[r] - mnew);
            m[r] = mnew;
            psum[r] = 0.0f;
        }
        #pragma unroll
        for (int nf = 0; nf < 4; ++nf)
            #pragma unroll
            for (int r = 0; r < 4; ++r) {
                float pv = __expf(s[nf][r] - m[r]);
                s[nf][r] = pv;
                psum[r] += pv;
            }
        #pragma unroll
        for (int r = 0; r < 4; ++r) {
            psum[r] += __shfl_xor(psum[r], 1);
            psum[r] += __shfl_xor(psum[r], 2);
            psum[r] += __shfl_xor(psum[r], 4);
            psum[r] += __shfl_xor(psum[r], 8);
            l[r] = l[r] * alpha[r] + psum[r];
        }
        // ---- P -> LDS (wave-private strip; DS ops wave-ordered, no barrier)
        #pragma unroll
        for (int nf = 0; nf < 4; ++nf)
            #pragma unroll
            for (int r = 0; r < 4; ++r)
                Ps[w][lkg * 4 + r][nf * 16 + lr] = bf16r(s[nf][r]);
        // ---- rescale O ----
        #pragma unroll
        for (int df = 0; df < 4; ++df)
            #pragma unroll
            for (int r = 0; r < 4; ++r)
                oacc[df][r] *= alpha[r];
        // ---- PV: A = P strip [q][key], B = Vt [d][key] ----
        s16x8 pa0 = *(const s16x8*)&Ps[w][lr][lk];
        s16x8 pa1 = *(const s16x8*)&Ps[w][lr][32 + lk];
        #pragma unroll
        for (int df = 0; df < 4; ++df) {
            s16x8 v0 = *(const s16x8*)&Vt[df * 16 + lr][lk];
            s16x8 v1 = *(const s16x8*)&Vt[df * 16 + lr][32 + lk];
            oacc[df] = __builtin_amdgcn_mfma_f32_16x16x32_bf16(pa0, v0, oacc[df], 0, 0, 0);
            oacc[df] = __builtin_amdgcn_mfma_f32_16x16x32_bf16(pa1, v1, oacc[df], 0, 0, 0);
        }
    }

    float invl[4];
    #pragma unroll
    for (int r = 0; r < 4; ++r) invl[r] = 1.0f / l[r];
    #pragma unroll
    for (int r = 0; r < 4; ++r) {
        int qrow = qrow_base + r;
        int t = ((qrow & 1) << 10) + (qrow >> 1);
        float* op = attn_out + (size_t)t * 1024 + (h << 6) + lr;
        #pragma unroll
        for (int df = 0; df < 4; ++df)
            op[df * 16] = oacc[df][r] * invl[r];
    }
}

// ---------------- router ----------------
__global__ void router_kernel(const float* __restrict__ xffn,
        const float* __restrict__ p_keys, const float* __restrict__ f_keys,
        const int* __restrict__ p_idx, const int* __restrict__ f_idx,
        const float* __restrict__ p_val, const float* __restrict__ f_val,
        const float* __restrict__ p_bias, const float* __restrict__ f_bias,
        float* __restrict__ sc) {
    int tl = blockIdx.x, hf = blockIdx.y;
    int t = hf * 1024 + tl;
    const float* keys = hf ? f_keys : p_keys;
    const int* idx    = hf ? f_idx  : p_idx;
    const float* val  = hf ? f_val  : p_val;
    const float* bias = hf ? f_bias : p_bias;
    int tid = threadIdx.x;
    float acc[16];
    #pragma unroll
    for (int e = 0; e < 16; ++e) acc[e] = 0.0f;
    const float* x = xffn + (size_t)t * DMODEL;
    for (int d = tid; d < 1024; d += 256) {
        float xd = x[d];
        const float* kr = keys + d * 16;
        #pragma unroll
        for (int e4 = 0; e4 < 4; ++e4) {
            float4 kv = *(const float4*)(kr + e4 * 4);
            acc[e4*4+0] += xd * kv.x;
            acc[e4*4+1] += xd * kv.y;
            acc[e4*4+2] += xd * kv.z;
            acc[e4*4+3] += xd * kv.w;
        }
    }
    #pragma unroll
    for (int e = 0; e < 16; ++e) {
        float v = acc[e];
        v += __shfl_down(v, 32); v += __shfl_down(v, 16); v += __shfl_down(v, 8);
        v += __shfl_down(v, 4);  v += __shfl_down(v, 2);  v += __shfl_down(v, 1);
        acc[e] = v;
    }
    __shared__ float part[4][16];
    __shared__ float logit[16];
    __shared__ float sg[4];
    int wave = tid >> 6, ln = tid & 63;
    if (ln == 0) {
        #pragma unroll
        for (int e = 0; e < 16; ++e) part[wave][e] = acc[e];
    }
    __syncthreads();
    if (tid < 16) logit[tid] = part[0][tid] + part[1][tid] + part[2][tid] + part[3][tid];
    __syncthreads();
    if (tid < 4) {
        int ii = idx[tl * 4 + tid];
        float v = val[tl * 4 + tid] + logit[ii] + bias[ii];
        sg[tid] = 1.0f / (1.0f + expf(-v));
    }
    __syncthreads();
    if (tid < 4) {
        float ssum = sg[0] + sg[1] + sg[2] + sg[3];
        sc[t * 4 + tid] = sg[tid] / ssum;
    }
}

// ---------------- expert bucketing (single workgroup) ----------------
__global__ __launch_bounds__(1024) void buckets_kernel(
        const int* __restrict__ p_idx, const int* __restrict__ f_idx,
        int* __restrict__ counts, int* __restrict__ offsets,
        int* __restrict__ pair_p) {
    __shared__ int lcnt[32], loff[32], lcur[32];
    int tid = threadIdx.x;
    if (tid < 32) { lcnt[tid] = 0; lcur[tid] = 0; }
    __syncthreads();
    for (int p = tid; p < NPAIR; p += 1024) {
        int hf = p >> 12, rem = p & 4095;
        int e = (hf ? f_idx : p_idx)[rem];
        atomicAdd(&lcnt[(hf << 4) + e], 1);
    }
    __syncthreads();
    if (tid == 0) {
        int o = 0;
        for (int b = 0; b < 32; ++b) { loff[b] = o; o += lcnt[b]; }
    }
    __syncthreads();
    for (int p = tid; p < NPAIR; p += 1024) {
        int hf = p >> 12, rem = p & 4095;
        int e = (hf ? f_idx : p_idx)[rem];
        int b = (hf << 4) + e;
        int pos = atomicAdd(&lcur[b], 1);
        pair_p[loff[b] + pos] = p;
    }
    if (tid < 32) { counts[tid] = lcnt[tid]; offsets[tid] = loff[tid]; }
}

// ---------------------------------------------------------------------------
// MFMA GEMM: C[M,N] = A[M,K] @ B[K,N], bf16 inputs (converted in staging),
// f32 accumulate. BM=128, BK=32, BN2 in {128,64}. 4 waves, wave tile
// 64 x (BN2/2), 4 x NI frags of 16x16. MODE 0: store; 1: C+= ; 2: C=AB+resid.
// ---------------------------------------------------------------------------
template<int MODE, int BN2>
__global__ __launch_bounds__(256) void mfma_gemm(
        const float* __restrict__ A, const float* __restrict__ B,
        float* __restrict__ C, const float* __restrict__ resid,
        int M, int N, int K) {
    constexpr int NI = BN2 / 32;
    __shared__ alignas(16) unsigned short As[128][40];
    __shared__ alignas(16) unsigned short Bs[BN2][40];
    int tid = threadIdx.x;
    int m0 = blockIdx.y * 128, n0 = blockIdx.x * BN2;
    int w = tid >> 6, lane = tid & 63;
    int wm = (w >> 1) * 64, wn = (w & 1) * (BN2 / 2);
    int lr = lane & 15, lk = (lane >> 4) << 3;
    int arow = tid >> 3, acol = (tid & 7) << 2;
    f32x4 acc[4][NI] = {};
    for (int k0 = 0; k0 < K; k0 += 32) {
        __syncthreads();
        #pragma unroll
        for (int i = 0; i < 4; ++i) {
            int r = arow + 32 * i;
            float4 v = *(const float4*)(A + (size_t)(m0 + r) * K + k0 + acol);
            *(u16x4*)&As[r][acol] = pack4(v.x, v.y, v.z, v.w);
        }
        if constexpr (BN2 == 128) {
            int bn = (tid & 31) << 2, bk = (tid >> 5) << 2;
            const float* bp = B + (size_t)(k0 + bk) * N + n0 + bn;
            float4 r0 = *(const float4*)(bp);
            float4 r1 = *(const float4*)(bp + N);
            float4 r2 = *(const float4*)(bp + 2 * N);
            float4 r3 = *(const float4*)(bp + 3 * N);
            *(u16x4*)&Bs[bn+0][bk] = pack4(r0.x, r1.x, r2.x, r3.x);
            *(u16x4*)&Bs[bn+1][bk] = pack4(r0.y, r1.y, r2.y, r3.y);
            *(u16x4*)&Bs[bn+2][bk] = pack4(r0.z, r1.z, r2.z, r3.z);
            *(u16x4*)&Bs[bn+3][bk] = pack4(r0.w, r1.w, r2.w, r3.w);
        } else {
            if (tid < 128) {
                int bn = (tid & 15) << 2, bk = (tid >> 4) << 2;
                const float* bp = B + (size_t)(k0 + bk) * N + n0 + bn;
                float4 r0 = *(const float4*)(bp);
                float4 r1 = *(const float4*)(bp + N);
                float4 r2 = *(const float4*)(bp + 2 * N);
                float4 r3 = *(const float4*)(bp + 3 * N);
                *(u16x4*)&Bs[bn+0][bk] = pack4(r0.x, r1.x, r2.x, r3.x);
                *(u16x4*)&Bs[bn+1][bk] = pack4(r0.y, r1.y, r2.y, r3.y);
                *(u16x4*)&Bs[bn+2][bk] = pack4(r0.z, r1.z, r2.z, r3.z);
                *(u16x4*)&Bs[bn+3][bk] = pack4(r0.w, r1.w, r2.w, r3.w);
            }
        }
        __syncthreads();
        s16x8 af[4], bfr[NI];
        #pragma unroll
        for (int mi = 0; mi < 4; ++mi)
            af[mi] = *(const s16x8*)&As[wm + mi * 16 + lr][lk];
        #pragma unroll
        for (int ni = 0; ni < NI; ++ni)
            bfr[ni] = *(const s16x8*)&Bs[wn + ni * 16 + lr][lk];
        #pragma unroll
        for (int mi = 0; mi < 4; ++mi)
            #pragma unroll
            for (int ni = 0; ni < NI; ++ni)
                acc[mi][ni] = __builtin_amdgcn_mfma_f32_16x16x32_bf16(
                                  af[mi], bfr[ni], acc[mi][ni], 0, 0, 0);
    }
    #pragma unroll
    for (int mi = 0; mi < 4; ++mi)
        #pragma unroll
        for (int r = 0; r < 4; ++r) {
            int row = m0 + wm + mi * 16 + ((lane >> 4) << 2) + r;
            size_t rb = (size_t)row * N + n0 + wn + lr;
            #pragma unroll
            for (int ni = 0; ni < NI; ++ni) {
                size_t off = rb + ni * 16;
                float v = acc[mi][ni][r];
                if (MODE == 1) v += C[off];
                if (MODE == 2) v += resid[off];
                C[off] = v;
            }
        }
}

// ---------------------------------------------------------------------------
// MFMA gate+up SwiGLU GEMM. BM=128, BN=64 (per matrix), BK=32.
// MOE=1: gathered A rows (pair buckets), expert weights, out h_pairs[slot].
// MOE=0: dense A (x_ffn), ffn_up (g cols 0..2047, u cols 2048..4095), out hs.
// ---------------------------------------------------------------------------
template<int MOE>
__global__ __launch_bounds__(256) void mfma_gateup(
        const float* __restrict__ X, const float* __restrict__ Wp,
        const float* __restrict__ Wf, const int* __restrict__ pair_p,
        const int* __restrict__ counts, const int* __restrict__ offsets,
        float* __restrict__ Hout) {
    __shared__ alignas(16) unsigned short As[128][40];
    __shared__ alignas(16) unsigned short Bsg[64][40];
    __shared__ alignas(16) unsigned short Bsu[64][40];
    __shared__ int toks[128];
    int tid = threadIdx.x;
    int rem = 128, slot0 = 0, m0 = 0, n0, ldb;
    const float *Wg, *Wu;
    if (MOE) {
        int bucket = blockIdx.y;
        int cnt = counts[bucket];
        int tile0 = blockIdx.x * 128;
        if (tile0 >= cnt) return;
        n0 = blockIdx.z * 64;
        int e = bucket & 15;
        const float* base = (bucket >> 4) ? Wf : Wp;
        Wg = base + (size_t)e * (DMODEL * FDIM) + n0;
        Wu = base + (size_t)(NEXP + e) * (DMODEL * FDIM) + n0;
        ldb = FDIM;
        slot0 = offsets[bucket] + tile0;
        rem = cnt - tile0;
        if (tid < 128)
            toks[tid] = (tid < rem) ? pair2tok(pair_p[slot0 + tid]) : 0;
    } else {
        m0 = blockIdx.y * 128;
        n0 = blockIdx.x * 64;
        Wg = Wp + n0;
        Wu = Wp + DSH + n0;
        ldb = 2 * DSH;
    }
    int w = tid >> 6, lane = tid & 63;
    int wm = (w >> 1) * 64, wn = (w & 1) * 32;
    int lr = lane & 15, lk = (lane >> 4) << 3;
    int arow = tid >> 3, acol = (tid & 7) << 2;
    int t2 = tid & 127, wq = tid >> 7;
    int bn = (t2 & 15) << 2, bk = (t2 >> 4) << 2;
    const float* bsrc = wq ? Wu : Wg;
    f32x4 ag[4][2] = {}, au[4][2] = {};
    for (int k0 = 0; k0 < DMODEL; k0 += 32) {
        __syncthreads();
        #pragma unroll
        for (int i = 0; i < 4; ++i) {
            int r = arow + 32 * i;
            int xrow = MOE ? toks[r] : (m0 + r);
            float4 v = *(const float4*)(X + (size_t)xrow * DMODEL + k0 + acol);
            *(u16x4*)&As[r][acol] = pack4(v.x, v.y, v.z, v.w);
        }
        {
            const float* bp = bsrc + (size_t)(k0 + bk) * ldb + bn;
            float4 r0 = *(const float4*)(bp);
            float4 r1 = *(const float4*)(bp + ldb);
            float4 r2 = *(const float4*)(bp + 2 * ldb);
            float4 r3 = *(const float4*)(bp + 3 * ldb);
            unsigned short (*bl)[40] = wq ? Bsu : Bsg;
            *(u16x4*)&bl[bn+0][bk] = pack4(r0.x, r1.x, r2.x, r3.x);
            *(u16x4*)&bl[bn+1][bk] = pack4(r0.y, r1.y, r2.y, r3.y);
            *(u16x4*)&bl[bn+2][bk] = pack4(r0.z, r1.z, r2.z, r3.z);
            *(u16x4*)&bl[bn+3][bk] = pack4(r0.w, r1.w, r2.w, r3.w);
        }
        __syncthreads();
        s16x8 af[4], bg[2], bu[2];
        #pragma unroll
        for (int mi = 0; mi < 4; ++mi)
            af[mi] = *(const s16x8*)&As[wm + mi * 16 + lr][lk];
        #pragma unroll
        for (int ni = 0; ni < 2; ++ni) {
            bg[ni] = *(const s16x8*)&Bsg[wn + ni * 16 + lr][lk];
            bu[ni] = *(const s16x8*)&Bsu[wn + ni * 16 + lr][lk];
        }
        #pragma unroll
        for (int mi = 0; mi < 4; ++mi)
            #pragma unroll
            for (int ni = 0; ni < 2; ++ni) {
                ag[mi][ni] = __builtin_amdgcn_mfma_f32_16x16x32_bf16(
                                 af[mi], bg[ni], ag[mi][ni], 0, 0, 0);
                au[mi][ni] = __builtin_amdgcn_mfma_f32_16x16x32_bf16(
                                 af[mi], bu[ni], au[mi][ni], 0, 0, 0);
            }
    }
    #pragma unroll
    for (int mi = 0; mi < 4; ++mi)
        #pragma unroll
        for (int r = 0; r < 4; ++r) {
            int rloc = wm + mi * 16 + ((lane >> 4) << 2) + r;
            if (MOE && rloc >= rem) continue;
            size_t rowb = MOE ? (size_t)(slot0 + rloc) * FDIM
                              : (size_t)(m0 + rloc) * DSH;
            #pragma unroll
            for (int ni = 0; ni < 2; ++ni) {
                float g = ag[mi][ni][r], u = au[mi][ni][r];
                Hout[rowb + n0 + wn + ni * 16 + lr] = g * sigm(g) * u;
            }
        }
}

// ---------------------------------------------------------------------------
// MFMA MoE down: y[token] += sc * (h_pairs[slot] @ Wd[e]^T). Wd is [d][f]
// i.e. already N-major (B^T layout) -> stage like A. atomicAdd epilogue.
// ---------------------------------------------------------------------------
__global__ __launch_bounds__(256) void mfma_moe_down(
        const float* __restrict__ h_pairs,
        const float* __restrict__ p_experts, const float* __restrict__ f_experts,
        const int* __restrict__ pair_p, const int* __restrict__ counts,
        const int* __restrict__ offsets, const float* __restrict__ sc,
        float* __restrict__ y) {
    __shared__ alignas(16) unsigned short As[128][40];
    __shared__ alignas(16) unsigned short Bs[128][40];
    __shared__ int   tokd[128];
    __shared__ float scd[128];
    int tid = threadIdx.x;
    int bucket = blockIdx.y;
    int cnt = counts[bucket];
    int tile0 = blockIdx.x * 128;
    if (tile0 >= cnt) return;
    int d0 = blockIdx.z * 128;
    int e = bucket & 15;
    const float* base = (bucket >> 4) ? f_experts : p_experts;
    const float* Wd = base + (size_t)(2 * NEXP + e) * (DMODEL * FDIM);
    int slot0 = offsets[bucket] + tile0;
    int rem = cnt - tile0;
    if (tid < 128) {
        int ok = tid < rem;
        int pr = ok ? pair_p[slot0 + tid] : 0;
        tokd[tid] = pair2tok(pr);
        scd[tid]  = ok ? sc[pr] : 0.0f;
    }
    int w = tid >> 6, lane = tid & 63;
    int wm = (w >> 1) * 64, wn = (w & 1) * 64;
    int lr = lane & 15, lk = (lane >> 4) << 3;
    int arow = tid >> 3, acol = (tid & 7) << 2;
    f32x4 acc[4][4] = {};
    for (int k0 = 0; k0 < FDIM; k0 += 32) {
        __syncthreads();
        #pragma unroll
        for (int i = 0; i < 4; ++i) {
            int r = arow + 32 * i;
            float4 v = *(const float4*)(h_pairs + (size_t)(slot0 + r) * FDIM + k0 + acol);
            *(u16x4*)&As[r][acol] = pack4(v.x, v.y, v.z, v.w);
            float4 b = *(const float4*)(Wd + (size_t)(d0 + r) * FDIM + k0 + acol);
            *(u16x4*)&Bs[r][acol] = pack4(b.x, b.y, b.z, b.w);
        }
        __syncthreads();
        s16x8 af[4], bfr[4];
        #pragma unroll
        for (int mi = 0; mi < 4; ++mi)
            af[mi] = *(const s16x8*)&As[wm + mi * 16 + lr][lk];
        #pragma unroll
        for (int ni = 0; ni < 4; ++ni)
            bfr[ni] = *(const s16x8*)&Bs[wn + ni * 16 + lr][lk];
        #pragma unroll
        for (int mi = 0; mi < 4; ++mi)
            #pragma unroll
            for (int ni = 0; ni < 4; ++ni)
                acc[mi][ni] = __builtin_amdgcn_mfma_f32_16x16x32_bf16(
                                  af[mi], bfr[ni], acc[mi][ni], 0, 0, 0);
    }
    #pragma unroll
    for (int mi = 0; mi < 4; ++mi)
        #pragma unroll
        for (int r = 0; r < 4; ++r) {
            int rloc = wm + mi * 16 + ((lane >> 4) << 2) + r;
            if (rloc < rem) {
                int   t = tokd[rloc];
                float s = scd[rloc];
                float* yp = y + (size_t)t * DMODEL + d0 + wn + lr;
                #pragma unroll
                for (int ni = 0; ni < 4; ++ni)
                    atomicAdd(yp + ni * 16, s * acc[mi][ni][r]);
            }
        }
}

// ===========================================================================
extern "C" void kernel_launch(void* const* d_in, const int* in_sizes, int n_in,
                              void* d_out, int out_size, void* d_ws, size_t ws_size,
                              hipStream_t stream) {
    const float* x_input  = (const float*)d_in[0];
    const int*   p_idx    = (const int*)d_in[1];
    const float* p_val    = (const float*)d_in[2];
    const int*   f_idx    = (const int*)d_in[3];
    const float* f_val    = (const float*)d_in[4];
    const float* attn_w   = (const float*)d_in[5];
    const float* ffn_w    = (const float*)d_in[6];
    const float* W_attn   = (const float*)d_in[7];
    const float* W_attn_o = (const float*)d_in[8];
    const float* ffn_up   = (const float*)d_in[9];
    const float* ffn_down = (const float*)d_in[10];
    const float* p_exp    = (const float*)d_in[11];
    const float* f_exp    = (const float*)d_in[12];
    const float* p_keys   = (const float*)d_in[13];
    const float* f_keys   = (const float*)d_in[14];
    const float* p_bias   = (const float*)d_in[15];
    const float* f_bias   = (const float*)d_in[16];
    float* y32 = (float*)d_out;                 // OUTPUT IS F32, accumulate here
    (void)in_sizes; (void)n_in; (void)out_size; (void)ws_size;

    float* ws = (float*)d_ws;
    // region A [0, 2,097,152): xnorm -> attn_out
    float* xnorm     = ws;
    float* attn_out  = ws;
    // region R1 [2,097,152, 8,388,608): qkv -> h_pairs -> hs
    float* R1        = ws + 2097152;
    float* qkv       = R1;                      // 2048*3072 = 6,291,456
    float* h_pairs   = R1;                      // 8192*512  = 4,194,304
    float* hs        = R1;                      // 2048*2048 = 4,194,304
    float* x_ffn_in  = ws + 8388608;            // 2,097,152
    float* x_ffn     = ws + 10485760;           // 2,097,152
    float* sc        = ws + 12582912;           // 8192
    int*   counts    = (int*)(ws + 12591104);   // 32
    int*   offsets   = counts + 32;             // 32
    int*   pair_p    = offsets + 32;            // 8192   (end ~50.4 MB)

    // 1) attn-input RMSNorm
    rmsnorm_kernel<<<T_TOT, 256, 0, stream>>>(x_input, attn_w, xnorm);
    // 2) QKV projection (MFMA bf16)
    mfma_gemm<0, 128><<<dim3(24, 16), 256, 0, stream>>>(xnorm, W_attn, qkv, nullptr,
                                                        T_TOT, 3072, 1024);
    // 3) RoPE in-place on q,k
    rope_kernel<<<T_TOT, 256, 0, stream>>>(qkv);
    // 4) causal attention, MFMA flash (reads qkv, writes region A)
    attn_mfma_kernel<<<dim3(32, NHEADS), 256, 0, stream>>>(qkv, attn_out);
    // 5) O-projection + residual (MFMA bf16; BN=64 -> 256 blocks)
    mfma_gemm<2, 64><<<dim3(16, 16), 256, 0, stream>>>(attn_out, W_attn_o, x_ffn_in,
                                                       x_input, T_TOT, 1024, 1024);
    // 6) ffn RMSNorm
    rmsnorm_kernel<<<T_TOT, 256, 0, stream>>>(x_ffn_in, ffn_w, x_ffn);
    // 7) router scores
    router_kernel<<<dim3(1024, 2), 256, 0, stream>>>(x_ffn, p_keys, f_keys,
                                                     p_idx, f_idx, p_val, f_val,
                                                     p_bias, f_bias, sc);
    // 8) expert buckets
    buckets_kernel<<<1, 1024, 0, stream>>>(p_idx, f_idx, counts, offsets, pair_p);
    // 9) MoE gate/up + silu (MFMA; qkv dead; h_pairs into R1)
    mfma_gateup<1><<<dim3(4, 32, 8), 256, 0, stream>>>(x_ffn, p_exp, f_exp,
                                                       pair_p, counts, offsets,
                                                       h_pairs);
    // 10) y (d_out) := x_ffn_in
    hipMemcpyAsync(y32, x_ffn_in, (size_t)T_TOT * DMODEL * sizeof(float),
                   hipMemcpyDeviceToDevice, stream);
    // 11) MoE down: atomic accumulate sc * (h @ Wd^T) into y (MFMA)
    mfma_moe_down<<<dim3(4, 32, 8), 256, 0, stream>>>(h_pairs, p_exp, f_exp,
                                                      pair_p, counts, offsets,
                                                      sc, y32);
    // 12) shared expert gate/up fused (MFMA; hs into R1; h_pairs dead after 11)
    mfma_gateup<0><<<dim3(32, 16), 256, 0, stream>>>(x_ffn, ffn_up, nullptr,
                                                     nullptr, nullptr, nullptr, hs);
    // 13) shared expert down, accumulate into y (MFMA; BN=64 -> 256 blocks)
    mfma_gemm<1, 64><<<dim3(16, 16), 256, 0, stream>>>(hs, ffn_down, y32, nullptr,
                                                       T_TOT, 1024, 2048);
}

// Round 4
// 725.747 us; speedup vs baseline: 4.4988x; 1.1029x over previous
//
#include <hip/hip_runtime.h>

// ---------------------------------------------------------------------------
// MoE transformer block, MI355X. Round 8: register-prefetch (issue-early /
// write-late, T14) added to every MFMA GEMM and to flash-attention K/V
// staging. Global loads for K-step k+1 are issued before the convert+LDS
// phase of step k, hiding HBM latency under MFMA/VALU work.
// Numerics identical to round 7 (same RTNE bit-trick, same op order).
//   ws region A [0, 2.10M floats):  xnorm -> attn_out
//   ws region R1 [2.10M, 8.39M):    qkv -> h_pairs -> hs
//   x_ffn_in [8.39M, 10.49M) ; x_ffn [10.49M, 12.58M) ; sc/ints after (~50MB)
// ---------------------------------------------------------------------------

#define S_LEN   1024
#define T_TOT   2048
#define DMODEL  1024
#define NHEADS  16
#define HDIM    64
#define NEXP    16
#define FDIM    512
#define DSH     2048
#define TOPK    4
#define NPAIR   8192

typedef __attribute__((ext_vector_type(4))) float          f32x4;
typedef __attribute__((ext_vector_type(8))) short          s16x8;   // MFMA A/B frag
typedef __attribute__((ext_vector_type(4))) unsigned short u16x4;

__device__ __forceinline__ float sigm(float x) { return 1.0f / (1.0f + __expf(-x)); }

// RTNE f32 -> bf16 (bit trick)
__device__ __forceinline__ unsigned short bf16r(float f) {
    union { float f; unsigned int u; } v; v.f = f;
    unsigned int r = v.u + 0x7fffu + ((v.u >> 16) & 1u);
    return (unsigned short)(r >> 16);
}

__device__ __forceinline__ u16x4 pack4(float a, float b, float c, float d) {
    u16x4 r;
    r.x = bf16r(a); r.y = bf16r(b); r.z = bf16r(c); r.w = bf16r(d);
    return r;
}

__device__ __forceinline__ int pair2tok(int p) {
    return ((p >> 12) << 10) + ((p & 4095) >> 2);
}

// ---------------- RMSNorm (f32 in, f32 out) ----------------
__global__ void rmsnorm_kernel(const float* __restrict__ x,
                               const float* __restrict__ w,
                               float* __restrict__ out) {
    int t = blockIdx.x, tid = threadIdx.x;
    float4 xv = *(const float4*)(x + (size_t)t * DMODEL + tid * 4);
    __shared__ float rb[256];
    rb[tid] = xv.x*xv.x + xv.y*xv.y + xv.z*xv.z + xv.w*xv.w;
    __syncthreads();
    for (int s = 128; s > 0; s >>= 1) { if (tid < s) rb[tid] += rb[tid+s]; __syncthreads(); }
    float scale = rsqrtf(rb[0] * (1.0f/1024.0f) + 1e-5f);
    float4 wv = *(const float4*)(w + tid * 4);
    float4 o;
    o.x = xv.x * scale * wv.x;
    o.y = xv.y * scale * wv.y;
    o.z = xv.z * scale * wv.z;
    o.w = xv.w * scale * wv.w;
    *(float4*)(out + (size_t)t*DMODEL + tid*4) = o;
}

// ---------------- RoPE, in-place on qkv rows (q and k only) ----------------
__global__ void rope_kernel(float* __restrict__ qkv) {
    int t = blockIdx.x, tid = threadIdx.x;
    int s = t & 1023;                 // position within half-sequence
    float* row = qkv + (size_t)t * 3072;
    for (int pp = tid; pp < 512; pp += 256) {
        int h = pp >> 5, i = pp & 31;
        float fr = (float)s * exp2f(-0.41524101186092028f * (float)i);
        float sn, cs;
        sincosf(fr, &sn, &cs);
        int o1 = (h << 6) + i, o2 = o1 + 32;
        float x1 = row[o1], x2 = row[o2];
        row[o1] = x1 * cs + x2 * sn;
        row[o2] = x2 * cs - x1 * sn;
        x1 = row[1024 + o1]; x2 = row[1024 + o2];
        row[1024 + o1] = x1 * cs + x2 * sn;
        row[1024 + o2] = x2 * cs - x1 * sn;
    }
}

// ---------------- MFMA flash attention (causal, online softmax) -------------
// Block = (q-tile of 64 interleaved positions) x head. 4 waves; wave w owns
// q-strip rows [w*16, w*16+16). K/V staged with register prefetch across
// k-tiles. Frag conventions identical to mfma_gemm.
__global__ __launch_bounds__(256) void attn_mfma_kernel(
        const float* __restrict__ qkv, float* __restrict__ attn_out) {
    int qt = blockIdx.x, h = blockIdx.y;
    __shared__ alignas(16) unsigned short Qs[64][72];   // [q][d], pre-scaled
    __shared__ alignas(16) unsigned short Ks[64][72];   // [key][d]
    __shared__ alignas(16) unsigned short Vt[64][72];   // [d][key]
    __shared__ alignas(16) unsigned short Ps[4][16][72];// per-wave P strip
    int tid = threadIdx.x;
    int w = tid >> 6, lane = tid & 63;
    int lr = lane & 15, lkg = lane >> 4, lk = lkg << 3;

    int rrj[4], ccj[4];
    #pragma unroll
    for (int j = 0; j < 4; ++j) {
        int idx = tid * 4 + j * 1024;
        rrj[j] = idx >> 6; ccj[j] = idx & 63;
    }

    // stage Q once (fold 1/sqrt(64) scale into bf16 conversion)
    #pragma unroll
    for (int j = 0; j < 4; ++j) {
        int p = qt * 64 + rrj[j];
        int t = ((p & 1) << 10) + (p >> 1);
        float4 v = *(const float4*)(qkv + (size_t)t * 3072 + (h << 6) + ccj[j]);
        *(u16x4*)&Qs[rrj[j]][ccj[j]] = pack4(v.x * 0.125f, v.y * 0.125f,
                                             v.z * 0.125f, v.w * 0.125f);
    }
    // prologue: prefetch K/V tile kb=0 into registers
    float4 pk[4], pv[4];
    #pragma unroll
    for (int j = 0; j < 4; ++j) {
        int p = rrj[j];
        int t = ((p & 1) << 10) + (p >> 1);
        const float* b = qkv + (size_t)t * 3072 + (h << 6) + ccj[j];
        pk[j] = *(const float4*)(b + 1024);
        pv[j] = *(const float4*)(b + 2048);
    }
    __syncthreads();
    s16x8 qa0 = *(const s16x8*)&Qs[(w << 4) + lr][lk];
    s16x8 qa1 = *(const s16x8*)&Qs[(w << 4) + lr][32 + lk];

    float m[4], l[4];
    f32x4 oacc[4];
    #pragma unroll
    for (int r = 0; r < 4; ++r) { m[r] = -1e30f; l[r] = 0.0f; }
    #pragma unroll
    for (int df = 0; df < 4; ++df) oacc[df] = (f32x4)0.0f;

    int qrow_base = qt * 64 + w * 16 + lkg * 4;   // + reg

    for (int kb = 0; kb <= qt; ++kb) {
        __syncthreads();
        float4 ck[4], cv[4];
        #pragma unroll
        for (int j = 0; j < 4; ++j) { ck[j] = pk[j]; cv[j] = pv[j]; }
        if (kb + 1 <= qt) {
            #pragma unroll
            for (int j = 0; j < 4; ++j) {
                int p = (kb + 1) * 64 + rrj[j];
                int t = ((p & 1) << 10) + (p >> 1);
                const float* b = qkv + (size_t)t * 3072 + (h << 6) + ccj[j];
                pk[j] = *(const float4*)(b + 1024);
                pv[j] = *(const float4*)(b + 2048);
            }
        }
        #pragma unroll
        for (int j = 0; j < 4; ++j) {
            int rr = rrj[j], cc = ccj[j];
            *(u16x4*)&Ks[rr][cc] = pack4(ck[j].x, ck[j].y, ck[j].z, ck[j].w);
            Vt[cc + 0][rr] = bf16r(cv[j].x);
            Vt[cc + 1][rr] = bf16r(cv[j].y);
            Vt[cc + 2][rr] = bf16r(cv[j].z);
            Vt[cc + 3][rr] = bf16r(cv[j].w);
        }
        __syncthreads();

        // ---- QK^T: wave strip 16 q-rows x 64 keys ----
        f32x4 s[4];
        #pragma unroll
        for (int nf = 0; nf < 4; ++nf) {
            s16x8 b0 = *(const s16x8*)&Ks[nf * 16 + lr][lk];
            s16x8 b1 = *(const s16x8*)&Ks[nf * 16 + lr][32 + lk];
            f32x4 z = (f32x4)0.0f;
            z = __builtin_amdgcn_mfma_f32_16x16x32_bf16(qa0, b0, z, 0, 0, 0);
            z = __builtin_amdgcn_mfma_f32_16x16x32_bf16(qa1, b1, z, 0, 0, 0);
            s[nf] = z;
        }
        // ---- causal mask (diag tile only; earlier tiles fully valid) ----
        if (kb == qt) {
            #pragma unroll
            for (int nf = 0; nf < 4; ++nf) {
                int kcol = kb * 64 + nf * 16 + lr;
                #pragma unroll
                for (int r = 0; r < 4; ++r)
                    if (kcol > qrow_base + r) s[nf][r] = -1e30f;
            }
        }
        // ---- online softmax (rows are lane-group-local in C layout) ----
        float mloc[4];
        #pragma unroll
        for (int r = 0; r < 4; ++r)
            mloc[r] = fmaxf(fmaxf(s[0][r], s[1][r]), fmaxf(s[2][r], s[3][r]));
        #pragma unroll
        for (int r = 0; r < 4; ++r) {
            mloc[r] = fmaxf(mloc[r], __shfl_xor(mloc[r], 1));
            mloc[r] = fmaxf(mloc[r], __shfl_xor(mloc[r], 2));
            mloc[r] = fmaxf(mloc[r], __shfl_xor(mloc[r], 4));
            mloc[r] = fmaxf(mloc[r], __shfl_xor(mloc[r], 8));
        }
        float alpha[4], psum[4];
        #pragma unroll
        for (int r = 0; r < 4; ++r) {
            float mnew = fmaxf(m[r], mloc[r]);
            alpha[r] = __expf(m[r] - mnew);
            m[r] = mnew;
            psum[r] = 0.0f;
        }
        #pragma unroll
        for (int nf = 0; nf < 4; ++nf)
            #pragma unroll
            for (int r = 0; r < 4; ++r) {
                float pv2 = __expf(s[nf][r] - m[r]);
                s[nf][r] = pv2;
                psum[r] += pv2;
            }
        #pragma unroll
        for (int r = 0; r < 4; ++r) {
            psum[r] += __shfl_xor(psum[r], 1);
            psum[r] += __shfl_xor(psum[r], 2);
            psum[r] += __shfl_xor(psum[r], 4);
            psum[r] += __shfl_xor(psum[r], 8);
            l[r] = l[r] * alpha[r] + psum[r];
        }
        // ---- P -> LDS (wave-private strip; DS ops wave-ordered, no barrier)
        #pragma unroll
        for (int nf = 0; nf < 4; ++nf)
            #pragma unroll
            for (int r = 0; r < 4; ++r)
                Ps[w][lkg * 4 + r][nf * 16 + lr] = bf16r(s[nf][r]);
        // ---- rescale O ----
        #pragma unroll
        for (int df = 0; df < 4; ++df)
            #pragma unroll
            for (int r = 0; r < 4; ++r)
                oacc[df][r] *= alpha[r];
        // ---- PV: A = P strip [q][key], B = Vt [d][key] ----
        s16x8 pa0 = *(const s16x8*)&Ps[w][lr][lk];
        s16x8 pa1 = *(const s16x8*)&Ps[w][lr][32 + lk];
        #pragma unroll
        for (int df = 0; df < 4; ++df) {
            s16x8 v0 = *(const s16x8*)&Vt[df * 16 + lr][lk];
            s16x8 v1 = *(const s16x8*)&Vt[df * 16 + lr][32 + lk];
            oacc[df] = __builtin_amdgcn_mfma_f32_16x16x32_bf16(pa0, v0, oacc[df], 0, 0, 0);
            oacc[df] = __builtin_amdgcn_mfma_f32_16x16x32_bf16(pa1, v1, oacc[df], 0, 0, 0);
        }
    }

    float invl[4];
    #pragma unroll
    for (int r = 0; r < 4; ++r) invl[r] = 1.0f / l[r];
    #pragma unroll
    for (int r = 0; r < 4; ++r) {
        int qrow = qrow_base + r;
        int t = ((qrow & 1) << 10) + (qrow >> 1);
        float* op = attn_out + (size_t)t * 1024 + (h << 6) + lr;
        #pragma unroll
        for (int df = 0; df < 4; ++df)
            op[df * 16] = oacc[df][r] * invl[r];
    }
}

// ---------------- router ----------------
__global__ void router_kernel(const float* __restrict__ xffn,
        const float* __restrict__ p_keys, const float* __restrict__ f_keys,
        const int* __restrict__ p_idx, const int* __restrict__ f_idx,
        const float* __restrict__ p_val, const float* __restrict__ f_val,
        const float* __restrict__ p_bias, const float* __restrict__ f_bias,
        float* __restrict__ sc) {
    int tl = blockIdx.x, hf = blockIdx.y;
    int t = hf * 1024 + tl;
    const float* keys = hf ? f_keys : p_keys;
    const int* idx    = hf ? f_idx  : p_idx;
    const float* val  = hf ? f_val  : p_val;
    const float* bias = hf ? f_bias : p_bias;
    int tid = threadIdx.x;
    float acc[16];
    #pragma unroll
    for (int e = 0; e < 16; ++e) acc[e] = 0.0f;
    const float* x = xffn + (size_t)t * DMODEL;
    for (int d = tid; d < 1024; d += 256) {
        float xd = x[d];
        const float* kr = keys + d * 16;
        #pragma unroll
        for (int e4 = 0; e4 < 4; ++e4) {
            float4 kv = *(const float4*)(kr + e4 * 4);
            acc[e4*4+0] += xd * kv.x;
            acc[e4*4+1] += xd * kv.y;
            acc[e4*4+2] += xd * kv.z;
            acc[e4*4+3] += xd * kv.w;
        }
    }
    #pragma unroll
    for (int e = 0; e < 16; ++e) {
        float v = acc[e];
        v += __shfl_down(v, 32); v += __shfl_down(v, 16); v += __shfl_down(v, 8);
        v += __shfl_down(v, 4);  v += __shfl_down(v, 2);  v += __shfl_down(v, 1);
        acc[e] = v;
    }
    __shared__ float part[4][16];
    __shared__ float logit[16];
    __shared__ float sg[4];
    int wave = tid >> 6, ln = tid & 63;
    if (ln == 0) {
        #pragma unroll
        for (int e = 0; e < 16; ++e) part[wave][e] = acc[e];
    }
    __syncthreads();
    if (tid < 16) logit[tid] = part[0][tid] + part[1][tid] + part[2][tid] + part[3][tid];
    __syncthreads();
    if (tid < 4) {
        int ii = idx[tl * 4 + tid];
        float v = val[tl * 4 + tid] + logit[ii] + bias[ii];
        sg[tid] = 1.0f / (1.0f + expf(-v));
    }
    __syncthreads();
    if (tid < 4) {
        float ssum = sg[0] + sg[1] + sg[2] + sg[3];
        sc[t * 4 + tid] = sg[tid] / ssum;
    }
}

// ---------------- expert bucketing (single workgroup) ----------------
__global__ __launch_bounds__(1024) void buckets_kernel(
        const int* __restrict__ p_idx, const int* __restrict__ f_idx,
        int* __restrict__ counts, int* __restrict__ offsets,
        int* __restrict__ pair_p) {
    __shared__ int lcnt[32], loff[32], lcur[32];
    int tid = threadIdx.x;
    if (tid < 32) { lcnt[tid] = 0; lcur[tid] = 0; }
    __syncthreads();
    for (int p = tid; p < NPAIR; p += 1024) {
        int hf = p >> 12, rem = p & 4095;
        int e = (hf ? f_idx : p_idx)[rem];
        atomicAdd(&lcnt[(hf << 4) + e], 1);
    }
    __syncthreads();
    if (tid == 0) {
        int o = 0;
        for (int b = 0; b < 32; ++b) { loff[b] = o; o += lcnt[b]; }
    }
    __syncthreads();
    for (int p = tid; p < NPAIR; p += 1024) {
        int hf = p >> 12, rem = p & 4095;
        int e = (hf ? f_idx : p_idx)[rem];
        int b = (hf << 4) + e;
        int pos = atomicAdd(&lcur[b], 1);
        pair_p[loff[b] + pos] = p;
    }
    if (tid < 32) { counts[tid] = lcnt[tid]; offsets[tid] = loff[tid]; }
}

// ---------------------------------------------------------------------------
// MFMA GEMM: C[M,N] = A[M,K] @ B[K,N], bf16 inputs (converted in staging),
// f32 accumulate. BM=128, BK=32, BN2 in {128,64}. 4 waves, wave tile
// 64 x (BN2/2). Register prefetch across K-steps (issue-early/write-late).
// MODE 0: store; 1: C+= ; 2: C=AB+resid.
// ---------------------------------------------------------------------------
template<int MODE, int BN2>
__global__ __launch_bounds__(256) void mfma_gemm(
        const float* __restrict__ A, const float* __restrict__ B,
        float* __restrict__ C, const float* __restrict__ resid,
        int M, int N, int K) {
    constexpr int NI = BN2 / 32;
    __shared__ alignas(16) unsigned short As[128][40];
    __shared__ alignas(16) unsigned short Bs[BN2][40];
    int tid = threadIdx.x;
    int m0 = blockIdx.y * 128, n0 = blockIdx.x * BN2;
    int w = tid >> 6, lane = tid & 63;
    int wm = (w >> 1) * 64, wn = (w & 1) * (BN2 / 2);
    int lr = lane & 15, lk = (lane >> 4) << 3;
    int arow = tid >> 3, acol = (tid & 7) << 2;
    int bn, bk;
    bool bact;
    if (BN2 == 128) { bn = (tid & 31) << 2; bk = (tid >> 5) << 2; bact = true; }
    else            { bn = (tid & 15) << 2; bk = (tid >> 4) << 2; bact = (tid < 128); }
    const float* Ap = A + (size_t)(m0 + arow) * K + acol;

    f32x4 acc[4][NI] = {};
    float4 a_cur[4], b_cur[4], a_nxt[4], b_nxt[4];
    // prologue: k0 = 0
    #pragma unroll
    for (int i = 0; i < 4; ++i)
        a_cur[i] = *(const float4*)(Ap + (size_t)(32 * i) * K);
    if (bact) {
        const float* bp = B + (size_t)bk * N + n0 + bn;
        #pragma unroll
        for (int j = 0; j < 4; ++j)
            b_cur[j] = *(const float4*)(bp + (size_t)j * N);
    }

    for (int k0 = 0; k0 < K; k0 += 32) {
        __syncthreads();
        // issue next-step loads first (stay in flight across the barrier)
        if (k0 + 32 < K) {
            #pragma unroll
            for (int i = 0; i < 4; ++i)
                a_nxt[i] = *(const float4*)(Ap + (size_t)(32 * i) * K + k0 + 32);
            if (bact) {
                const float* bp = B + (size_t)(k0 + 32 + bk) * N + n0 + bn;
                #pragma unroll
                for (int j = 0; j < 4; ++j)
                    b_nxt[j] = *(const float4*)(bp + (size_t)j * N);
            }
        }
        // convert + store current step to LDS
        #pragma unroll
        for (int i = 0; i < 4; ++i)
            *(u16x4*)&As[arow + 32 * i][acol] =
                pack4(a_cur[i].x, a_cur[i].y, a_cur[i].z, a_cur[i].w);
        if (bact) {
            *(u16x4*)&Bs[bn+0][bk] = pack4(b_cur[0].x, b_cur[1].x, b_cur[2].x, b_cur[3].x);
            *(u16x4*)&Bs[bn+1][bk] = pack4(b_cur[0].y, b_cur[1].y, b_cur[2].y, b_cur[3].y);
            *(u16x4*)&Bs[bn+2][bk] = pack4(b_cur[0].z, b_cur[1].z, b_cur[2].z, b_cur[3].z);
            *(u16x4*)&Bs[bn+3][bk] = pack4(b_cur[0].w, b_cur[1].w, b_cur[2].w, b_cur[3].w);
        }
        __syncthreads();
        s16x8 af[4], bfr[NI];
        #pragma unroll
        for (int mi = 0; mi < 4; ++mi)
            af[mi] = *(const s16x8*)&As[wm + mi * 16 + lr][lk];
        #pragma unroll
        for (int ni = 0; ni < NI; ++ni)
            bfr[ni] = *(const s16x8*)&Bs[wn + ni * 16 + lr][lk];
        #pragma unroll
        for (int mi = 0; mi < 4; ++mi)
            #pragma unroll
            for (int ni = 0; ni < NI; ++ni)
                acc[mi][ni] = __builtin_amdgcn_mfma_f32_16x16x32_bf16(
                                  af[mi], bfr[ni], acc[mi][ni], 0, 0, 0);
        #pragma unroll
        for (int i = 0; i < 4; ++i) { a_cur[i] = a_nxt[i]; b_cur[i] = b_nxt[i]; }
    }
    #pragma unroll
    for (int mi = 0; mi < 4; ++mi)
        #pragma unroll
        for (int r = 0; r < 4; ++r) {
            int row = m0 + wm + mi * 16 + ((lane >> 4) << 2) + r;
            size_t rb = (size_t)row * N + n0 + wn + lr;
            #pragma unroll
            for (int ni = 0; ni < NI; ++ni) {
                size_t off = rb + ni * 16;
                float v = acc[mi][ni][r];
                if (MODE == 1) v += C[off];
                if (MODE == 2) v += resid[off];
                C[off] = v;
            }
        }
}

// ---------------------------------------------------------------------------
// MFMA gate+up SwiGLU GEMM. BM=128, BN=64 (per matrix), BK=32. Register
// prefetch across K-steps.
// MOE=1: gathered A rows (pair buckets), expert weights, out h_pairs[slot].
// MOE=0: dense A (x_ffn), ffn_up (g cols 0..2047, u cols 2048..4095), out hs.
// ---------------------------------------------------------------------------
template<int MOE>
__global__ __launch_bounds__(256) void mfma_gateup(
        const float* __restrict__ X, const float* __restrict__ Wp,
        const float* __restrict__ Wf, const int* __restrict__ pair_p,
        const int* __restrict__ counts, const int* __restrict__ offsets,
        float* __restrict__ Hout) {
    __shared__ alignas(16) unsigned short As[128][40];
    __shared__ alignas(16) unsigned short Bsg[64][40];
    __shared__ alignas(16) unsigned short Bsu[64][40];
    __shared__ int toks[128];
    int tid = threadIdx.x;
    int rem = 128, slot0 = 0, m0 = 0, n0, ldb;
    const float *Wg, *Wu;
    if (MOE) {
        int bucket = blockIdx.y;
        int cnt = counts[bucket];
        int tile0 = blockIdx.x * 128;
        if (tile0 >= cnt) return;
        n0 = blockIdx.z * 64;
        int e = bucket & 15;
        const float* base = (bucket >> 4) ? Wf : Wp;
        Wg = base + (size_t)e * (DMODEL * FDIM) + n0;
        Wu = base + (size_t)(NEXP + e) * (DMODEL * FDIM) + n0;
        ldb = FDIM;
        slot0 = offsets[bucket] + tile0;
        rem = cnt - tile0;
        if (tid < 128)
            toks[tid] = (tid < rem) ? pair2tok(pair_p[slot0 + tid]) : 0;
    } else {
        m0 = blockIdx.y * 128;
        n0 = blockIdx.x * 64;
        Wg = Wp + n0;
        Wu = Wp + DSH + n0;
        ldb = 2 * DSH;
    }
    int w = tid >> 6, lane = tid & 63;
    int wm = (w >> 1) * 64, wn = (w & 1) * 32;
    int lr = lane & 15, lk = (lane >> 4) << 3;
    int arow = tid >> 3, acol = (tid & 7) << 2;
    int t2 = tid & 127, wq = tid >> 7;
    int bn = (t2 & 15) << 2, bk = (t2 >> 4) << 2;
    const float* bsrc = wq ? Wu : Wg;
    if (MOE) __syncthreads();       // toks visible before prologue gather
    const float* Xr[4];
    #pragma unroll
    for (int i = 0; i < 4; ++i) {
        int r = arow + 32 * i;
        int xrow = MOE ? toks[r] : (m0 + r);
        Xr[i] = X + (size_t)xrow * DMODEL + acol;
    }
    f32x4 ag[4][2] = {}, au[4][2] = {};
    float4 a_cur[4], b_cur[4], a_nxt[4], b_nxt[4];
    // prologue k0 = 0
    #pragma unroll
    for (int i = 0; i < 4; ++i) a_cur[i] = *(const float4*)(Xr[i]);
    {
        const float* bp = bsrc + (size_t)bk * ldb + bn;
        #pragma unroll
        for (int j = 0; j < 4; ++j)
            b_cur[j] = *(const float4*)(bp + (size_t)j * ldb);
    }
    for (int k0 = 0; k0 < DMODEL; k0 += 32) {
        __syncthreads();
        if (k0 + 32 < DMODEL) {
            #pragma unroll
            for (int i = 0; i < 4; ++i)
                a_nxt[i] = *(const float4*)(Xr[i] + k0 + 32);
            const float* bp = bsrc + (size_t)(k0 + 32 + bk) * ldb + bn;
            #pragma unroll
            for (int j = 0; j < 4; ++j)
                b_nxt[j] = *(const float4*)(bp + (size_t)j * ldb);
        }
        #pragma unroll
        for (int i = 0; i < 4; ++i)
            *(u16x4*)&As[arow + 32 * i][acol] =
                pack4(a_cur[i].x, a_cur[i].y, a_cur[i].z, a_cur[i].w);
        {
            unsigned short (*bl)[40] = wq ? Bsu : Bsg;
            *(u16x4*)&bl[bn+0][bk] = pack4(b_cur[0].x, b_cur[1].x, b_cur[2].x, b_cur[3].x);
            *(u16x4*)&bl[bn+1][bk] = pack4(b_cur[0].y, b_cur[1].y, b_cur[2].y, b_cur[3].y);
            *(u16x4*)&bl[bn+2][bk] = pack4(b_cur[0].z, b_cur[1].z, b_cur[2].z, b_cur[3].z);
            *(u16x4*)&bl[bn+3][bk] = pack4(b_cur[0].w, b_cur[1].w, b_cur[2].w, b_cur[3].w);
        }
        __syncthreads();
        s16x8 af[4], bg[2], bu[2];
        #pragma unroll
        for (int mi = 0; mi < 4; ++mi)
            af[mi] = *(const s16x8*)&As[wm + mi * 16 + lr][lk];
        #pragma unroll
        for (int ni = 0; ni < 2; ++ni) {
            bg[ni] = *(const s16x8*)&Bsg[wn + ni * 16 + lr][lk];
            bu[ni] = *(const s16x8*)&Bsu[wn + ni * 16 + lr][lk];
        }
        #pragma unroll
        for (int mi = 0; mi < 4; ++mi)
            #pragma unroll
            for (int ni = 0; ni < 2; ++ni) {
                ag[mi][ni] = __builtin_amdgcn_mfma_f32_16x16x32_bf16(
                                 af[mi], bg[ni], ag[mi][ni], 0, 0, 0);
                au[mi][ni] = __builtin_amdgcn_mfma_f32_16x16x32_bf16(
                                 af[mi], bu[ni], au[mi][ni], 0, 0, 0);
            }
        #pragma unroll
        for (int i = 0; i < 4; ++i) { a_cur[i] = a_nxt[i]; b_cur[i] = b_nxt[i]; }
    }
    #pragma unroll
    for (int mi = 0; mi < 4; ++mi)
        #pragma unroll
        for (int r = 0; r < 4; ++r) {
            int rloc = wm + mi * 16 + ((lane >> 4) << 2) + r;
            if (MOE && rloc >= rem) continue;
            size_t rowb = MOE ? (size_t)(slot0 + rloc) * FDIM
                              : (size_t)(m0 + rloc) * DSH;
            #pragma unroll
            for (int ni = 0; ni < 2; ++ni) {
                float g = ag[mi][ni][r], u = au[mi][ni][r];
                Hout[rowb + n0 + wn + ni * 16 + lr] = g * sigm(g) * u;
            }
        }
}

// ---------------------------------------------------------------------------
// MFMA MoE down: y[token] += sc * (h_pairs[slot] @ Wd[e]^T). Wd is [d][f]
// i.e. already N-major (B^T layout) -> stage like A. Register prefetch.
// atomicAdd epilogue.
// ---------------------------------------------------------------------------
__global__ __launch_bounds__(256) void mfma_moe_down(
        const float* __restrict__ h_pairs,
        const float* __restrict__ p_experts, const float* __restrict__ f_experts,
        const int* __restrict__ pair_p, const int* __restrict__ counts,
        const int* __restrict__ offsets, const float* __restrict__ sc,
        float* __restrict__ y) {
    __shared__ alignas(16) unsigned short As[128][40];
    __shared__ alignas(16) unsigned short Bs[128][40];
    __shared__ int   tokd[128];
    __shared__ float scd[128];
    int tid = threadIdx.x;
    int bucket = blockIdx.y;
    int cnt = counts[bucket];
    int tile0 = blockIdx.x * 128;
    if (tile0 >= cnt) return;
    int d0 = blockIdx.z * 128;
    int e = bucket & 15;
    const float* base = (bucket >> 4) ? f_experts : p_experts;
    const float* Wd = base + (size_t)(2 * NEXP + e) * (DMODEL * FDIM);
    int slot0 = offsets[bucket] + tile0;
    int rem = cnt - tile0;
    if (tid < 128) {
        int ok = tid < rem;
        int pr = ok ? pair_p[slot0 + tid] : 0;
        tokd[tid] = pair2tok(pr);
        scd[tid]  = ok ? sc[pr] : 0.0f;
    }
    int w = tid >> 6, lane = tid & 63;
    int wm = (w >> 1) * 64, wn = (w & 1) * 64;
    int lr = lane & 15, lk = (lane >> 4) << 3;
    int arow = tid >> 3, acol = (tid & 7) << 2;
    const float* Apb = h_pairs + (size_t)(slot0 + arow) * FDIM + acol;
    const float* Bpb = Wd + (size_t)(d0 + arow) * FDIM + acol;
    f32x4 acc[4][4] = {};
    float4 a_cur[4], b_cur[4], a_nxt[4], b_nxt[4];
    #pragma unroll
    for (int i = 0; i < 4; ++i) {
        a_cur[i] = *(const float4*)(Apb + (size_t)(32 * i) * FDIM);
        b_cur[i] = *(const float4*)(Bpb + (size_t)(32 * i) * FDIM);
    }
    for (int k0 = 0; k0 < FDIM; k0 += 32) {
        __syncthreads();
        if (k0 + 32 < FDIM) {
            #pragma unroll
            for (int i = 0; i < 4; ++i) {
                a_nxt[i] = *(const float4*)(Apb + (size_t)(32 * i) * FDIM + k0 + 32);
                b_nxt[i] = *(const float4*)(Bpb + (size_t)(32 * i) * FDIM + k0 + 32);
            }
        }
        #pragma unroll
        for (int i = 0; i < 4; ++i) {
            int r = arow + 32 * i;
            *(u16x4*)&As[r][acol] = pack4(a_cur[i].x, a_cur[i].y, a_cur[i].z, a_cur[i].w);
            *(u16x4*)&Bs[r][acol] = pack4(b_cur[i].x, b_cur[i].y, b_cur[i].z, b_cur[i].w);
        }
        __syncthreads();
        s16x8 af[4], bfr[4];
        #pragma unroll
        for (int mi = 0; mi < 4; ++mi)
            af[mi] = *(const s16x8*)&As[wm + mi * 16 + lr][lk];
        #pragma unroll
        for (int ni = 0; ni < 4; ++ni)
            bfr[ni] = *(const s16x8*)&Bs[wn + ni * 16 + lr][lk];
        #pragma unroll
        for (int mi = 0; mi < 4; ++mi)
            #pragma unroll
            for (int ni = 0; ni < 4; ++ni)
                acc[mi][ni] = __builtin_amdgcn_mfma_f32_16x16x32_bf16(
                                  af[mi], bfr[ni], acc[mi][ni], 0, 0, 0);
        #pragma unroll
        for (int i = 0; i < 4; ++i) { a_cur[i] = a_nxt[i]; b_cur[i] = b_nxt[i]; }
    }
    #pragma unroll
    for (int mi = 0; mi < 4; ++mi)
        #pragma unroll
        for (int r = 0; r < 4; ++r) {
            int rloc = wm + mi * 16 + ((lane >> 4) << 2) + r;
            if (rloc < rem) {
                int   t = tokd[rloc];
                float s = scd[rloc];
                float* yp = y + (size_t)t * DMODEL + d0 + wn + lr;
                #pragma unroll
                for (int ni = 0; ni < 4; ++ni)
                    atomicAdd(yp + ni * 16, s * acc[mi][ni][r]);
            }
        }
}

// ===========================================================================
extern "C" void kernel_launch(void* const* d_in, const int* in_sizes, int n_in,
                              void* d_out, int out_size, void* d_ws, size_t ws_size,
                              hipStream_t stream) {
    const float* x_input  = (const float*)d_in[0];
    const int*   p_idx    = (const int*)d_in[1];
    const float* p_val    = (const float*)d_in[2];
    const int*   f_idx    = (const int*)d_in[3];
    const float* f_val    = (const float*)d_in[4];
    const float* attn_w   = (const float*)d_in[5];
    const float* ffn_w    = (const float*)d_in[6];
    const float* W_attn   = (const float*)d_in[7];
    const float* W_attn_o = (const float*)d_in[8];
    const float* ffn_up   = (const float*)d_in[9];
    const float* ffn_down = (const float*)d_in[10];
    const float* p_exp    = (const float*)d_in[11];
    const float* f_exp    = (const float*)d_in[12];
    const float* p_keys   = (const float*)d_in[13];
    const float* f_keys   = (const float*)d_in[14];
    const float* p_bias   = (const float*)d_in[15];
    const float* f_bias   = (const float*)d_in[16];
    float* y32 = (float*)d_out;                 // OUTPUT IS F32, accumulate here
    (void)in_sizes; (void)n_in; (void)out_size; (void)ws_size;

    float* ws = (float*)d_ws;
    // region A [0, 2,097,152): xnorm -> attn_out
    float* xnorm     = ws;
    float* attn_out  = ws;
    // region R1 [2,097,152, 8,388,608): qkv -> h_pairs -> hs
    float* R1        = ws + 2097152;
    float* qkv       = R1;                      // 2048*3072 = 6,291,456
    float* h_pairs   = R1;                      // 8192*512  = 4,194,304
    float* hs        = R1;                      // 2048*2048 = 4,194,304
    float* x_ffn_in  = ws + 8388608;            // 2,097,152
    float* x_ffn     = ws + 10485760;           // 2,097,152
    float* sc        = ws + 12582912;           // 8192
    int*   counts    = (int*)(ws + 12591104);   // 32
    int*   offsets   = counts + 32;             // 32
    int*   pair_p    = offsets + 32;            // 8192   (end ~50.4 MB)

    // 1) attn-input RMSNorm
    rmsnorm_kernel<<<T_TOT, 256, 0, stream>>>(x_input, attn_w, xnorm);
    // 2) QKV projection (MFMA bf16)
    mfma_gemm<0, 128><<<dim3(24, 16), 256, 0, stream>>>(xnorm, W_attn, qkv, nullptr,
                                                        T_TOT, 3072, 1024);
    // 3) RoPE in-place on q,k
    rope_kernel<<<T_TOT, 256, 0, stream>>>(qkv);
    // 4) causal attention, MFMA flash (reads qkv, writes region A)
    attn_mfma_kernel<<<dim3(32, NHEADS), 256, 0, stream>>>(qkv, attn_out);
    // 5) O-projection + residual (MFMA bf16; BN=64 -> 256 blocks)
    mfma_gemm<2, 64><<<dim3(16, 16), 256, 0, stream>>>(attn_out, W_attn_o, x_ffn_in,
                                                       x_input, T_TOT, 1024, 1024);
    // 6) ffn RMSNorm
    rmsnorm_kernel<<<T_TOT, 256, 0, stream>>>(x_ffn_in, ffn_w, x_ffn);
    // 7) router scores
    router_kernel<<<dim3(1024, 2), 256, 0, stream>>>(x_ffn, p_keys, f_keys,
                                                     p_idx, f_idx, p_val, f_val,
                                                     p_bias, f_bias, sc);
    // 8) expert buckets
    buckets_kernel<<<1, 1024, 0, stream>>>(p_idx, f_idx, counts, offsets, pair_p);
    // 9) MoE gate/up + silu (MFMA; qkv dead; h_pairs into R1)
    mfma_gateup<1><<<dim3(4, 32, 8), 256, 0, stream>>>(x_ffn, p_exp, f_exp,
                                                       pair_p, counts, offsets,
                                                       h_pairs);
    // 10) y (d_out) := x_ffn_in
    hipMemcpyAsync(y32, x_ffn_in, (size_t)T_TOT * DMODEL * sizeof(float),
                   hipMemcpyDeviceToDevice, stream);
    // 11) MoE down: atomic accumulate sc * (h @ Wd^T) into y (MFMA)
    mfma_moe_down<<<dim3(4, 32, 8), 256, 0, stream>>>(h_pairs, p_exp, f_exp,
                                                      pair_p, counts, offsets,
                                                      sc, y32);
    // 12) shared expert gate/up fused (MFMA; hs into R1; h_pairs dead after 11)
    mfma_gateup<0><<<dim3(32, 16), 256, 0, stream>>>(x_ffn, ffn_up, nullptr,
                                                     nullptr, nullptr, nullptr, hs);
    // 13) shared expert down, accumulate into y (MFMA; BN=64 -> 256 blocks)
    mfma_gemm<1, 64><<<dim3(16, 16), 256, 0, stream>>>(hs, ffn_down, y32, nullptr,
                                                       T_TOT, 1024, 2048);
}

// Round 5
// 688.021 us; speedup vs baseline: 4.7454x; 1.0548x over previous
//
#include <hip/hip_runtime.h>

// ---------------------------------------------------------------------------
// MoE transformer block, MI355X. Round 9: bf16 operand pipeline.
//  - all activations stored bf16 (producers write bf16 directly; same RNE
//    roundings that consumers previously applied at staging)
//  - weight (B-side) f32->bf16 via v_cvt_pk_bf16_f32 (1 op / 2 elems)
//  - B-staging lane map rewritten: consecutive lanes write along k
//    (8B-apart LDS addresses, conflict-free; was 16-way on a 320B stride)
//  - attention V-transpose XOR-swizzled (was 16-way conflict)
// Workspace (float offsets):
//   [0,1.05M)      xnormh / attn_outh (bf16, aliased)
//   [2.10M,8.39M)  qkvh -> h_pairsh -> hsh (bf16, aliased)
//   [8.39M,10.49M) x_ffn_in (f32)
//   [10.49M,11.53M) x_ffnh (bf16)
//   [12.58M...)    sc, counts, offsets, pair_p
// ---------------------------------------------------------------------------

#define T_TOT   2048
#define DMODEL  1024
#define NHEADS  16
#define NEXP    16
#define FDIM    512
#define DSH     2048
#define NPAIR   8192

typedef __attribute__((ext_vector_type(4))) float          f32x4;
typedef __attribute__((ext_vector_type(8))) short          s16x8;   // MFMA A/B frag
typedef __attribute__((ext_vector_type(8))) unsigned short u16x8;
typedef __attribute__((ext_vector_type(2))) unsigned int   u32x2;

__device__ __forceinline__ float sigm(float x) { return 1.0f / (1.0f + __expf(-x)); }

// RTNE f32 -> bf16 (bit trick; used in scalar epilogues)
__device__ __forceinline__ unsigned short bf16r(float f) {
    union { float f; unsigned int u; } v; v.f = f;
    unsigned int r = v.u + 0x7fffu + ((v.u >> 16) & 1u);
    return (unsigned short)(r >> 16);
}

// hw packed convert: dst.lo = bf16(lo), dst.hi = bf16(hi)  (RNE)
__device__ __forceinline__ unsigned int cvtpk(float lo, float hi) {
    unsigned int r;
    asm("v_cvt_pk_bf16_f32 %0, %1, %2" : "=v"(r) : "v"(lo), "v"(hi));
    return r;
}

__device__ __forceinline__ float ubf(unsigned short u) {
    union { unsigned int i; float f; } v; v.i = (unsigned int)u << 16; return v.f;
}

__device__ __forceinline__ int pair2tok(int p) {
    return ((p >> 12) << 10) + ((p & 4095) >> 2);
}

// ---------------- RMSNorm (f32 in, bf16 out) ----------------
__global__ void rmsnorm_kernel(const float* __restrict__ x,
                               const float* __restrict__ w,
                               unsigned short* __restrict__ out) {
    int t = blockIdx.x, tid = threadIdx.x;
    float4 xv = *(const float4*)(x + (size_t)t * DMODEL + tid * 4);
    __shared__ float rb[256];
    rb[tid] = xv.x*xv.x + xv.y*xv.y + xv.z*xv.z + xv.w*xv.w;
    __syncthreads();
    for (int s = 128; s > 0; s >>= 1) { if (tid < s) rb[tid] += rb[tid+s]; __syncthreads(); }
    float scale = rsqrtf(rb[0] * (1.0f/1024.0f) + 1e-5f);
    float4 wv = *(const float4*)(w + tid * 4);
    u32x2 pv;
    pv.x = cvtpk(xv.x * scale * wv.x, xv.y * scale * wv.y);
    pv.y = cvtpk(xv.z * scale * wv.z, xv.w * scale * wv.w);
    *(u32x2*)(out + (size_t)t * DMODEL + tid * 4) = pv;
}

// ---------------- RoPE, in-place on bf16 qkv rows (q and k only) -----------
__global__ void rope_kernel(unsigned short* __restrict__ qkv) {
    int t = blockIdx.x, tid = threadIdx.x;
    int s = t & 1023;
    unsigned short* row = qkv + (size_t)t * 3072;
    for (int pp = tid; pp < 512; pp += 256) {
        int h = pp >> 5, i = pp & 31;
        float fr = (float)s * exp2f(-0.41524101186092028f * (float)i);
        float sn, cs;
        sincosf(fr, &sn, &cs);
        int o1 = (h << 6) + i, o2 = o1 + 32;
        float x1 = ubf(row[o1]), x2 = ubf(row[o2]);
        row[o1] = bf16r(x1 * cs + x2 * sn);
        row[o2] = bf16r(x2 * cs - x1 * sn);
        x1 = ubf(row[1024 + o1]); x2 = ubf(row[1024 + o2]);
        row[1024 + o1] = bf16r(x1 * cs + x2 * sn);
        row[1024 + o2] = bf16r(x2 * cs - x1 * sn);
    }
}

// ---------------- MFMA flash attention (causal, online softmax) -------------
// qkv bf16 in, attn_out bf16. K copied straight (bf16), V transposed into
// XOR-swizzled LDS (kcol ^= ((drow>>3)&7)<<3) to kill the 16-way conflict.
__global__ __launch_bounds__(256) void attn_mfma_kernel(
        const unsigned short* __restrict__ qkv,
        unsigned short* __restrict__ attn_out) {
    int qt = blockIdx.x, h = blockIdx.y;
    __shared__ alignas(16) unsigned short Qs[64][72];
    __shared__ alignas(16) unsigned short Ks[64][72];
    __shared__ alignas(16) unsigned short Vt[64][72];    // [d][key^swz]
    __shared__ alignas(16) unsigned short Ps[4][16][72];
    int tid = threadIdx.x;
    int w = tid >> 6, lane = tid & 63;
    int lr = lane & 15, lkg = lane >> 4, lk = lkg << 3;
    int kr = tid >> 3, kc = (tid & 7) << 3;   // chunk row (0..31), col8 (shorts)

    // stage Q (scale 0.125 folded)
    #pragma unroll
    for (int i = 0; i < 2; ++i) {
        int rr = kr + 32 * i;
        int p = qt * 64 + rr;
        int t = ((p & 1) << 10) + (p >> 1);
        u16x8 q = *(const u16x8*)(qkv + (size_t)t * 3072 + (h << 6) + kc);
        unsigned int* dst = (unsigned int*)&Qs[rr][kc];
        dst[0] = cvtpk(ubf(q[0]) * 0.125f, ubf(q[1]) * 0.125f);
        dst[1] = cvtpk(ubf(q[2]) * 0.125f, ubf(q[3]) * 0.125f);
        dst[2] = cvtpk(ubf(q[4]) * 0.125f, ubf(q[5]) * 0.125f);
        dst[3] = cvtpk(ubf(q[6]) * 0.125f, ubf(q[7]) * 0.125f);
    }
    // prologue: prefetch K/V tile 0
    u16x8 pkv[2], pvv[2];
    #pragma unroll
    for (int i = 0; i < 2; ++i) {
        int rr = kr + 32 * i;
        int t = ((rr & 1) << 10) + (rr >> 1);
        const unsigned short* b = qkv + (size_t)t * 3072 + (h << 6) + kc;
        pkv[i] = *(const u16x8*)(b + 1024);
        pvv[i] = *(const u16x8*)(b + 2048);
    }
    __syncthreads();
    s16x8 qa0 = *(const s16x8*)&Qs[(w << 4) + lr][lk];
    s16x8 qa1 = *(const s16x8*)&Qs[(w << 4) + lr][32 + lk];

    float m[4], l[4];
    f32x4 oacc[4];
    #pragma unroll
    for (int r = 0; r < 4; ++r) { m[r] = -1e30f; l[r] = 0.0f; }
    #pragma unroll
    for (int df = 0; df < 4; ++df) oacc[df] = (f32x4)0.0f;

    int qrow_base = qt * 64 + w * 16 + lkg * 4;

    for (int kb = 0; kb <= qt; ++kb) {
        __syncthreads();
        u16x8 ck[2], cv[2];
        #pragma unroll
        for (int i = 0; i < 2; ++i) { ck[i] = pkv[i]; cv[i] = pvv[i]; }
        if (kb + 1 <= qt) {
            #pragma unroll
            for (int i = 0; i < 2; ++i) {
                int rr = kr + 32 * i;
                int p = (kb + 1) * 64 + rr;
                int t = ((p & 1) << 10) + (p >> 1);
                const unsigned short* b = qkv + (size_t)t * 3072 + (h << 6) + kc;
                pkv[i] = *(const u16x8*)(b + 1024);
                pvv[i] = *(const u16x8*)(b + 2048);
            }
        }
        #pragma unroll
        for (int i = 0; i < 2; ++i) {
            int rr = kr + 32 * i;
            *(u16x8*)&Ks[rr][kc] = ck[i];
            #pragma unroll
            for (int j = 0; j < 8; ++j) {
                int vrow = kc + j;
                int sw = ((vrow >> 3) & 7) << 3;
                Vt[vrow][rr ^ sw] = cv[i][j];
            }
        }
        __syncthreads();

        // ---- QK^T ----
        f32x4 s[4];
        #pragma unroll
        for (int nf = 0; nf < 4; ++nf) {
            s16x8 b0 = *(const s16x8*)&Ks[nf * 16 + lr][lk];
            s16x8 b1 = *(const s16x8*)&Ks[nf * 16 + lr][32 + lk];
            f32x4 z = (f32x4)0.0f;
            z = __builtin_amdgcn_mfma_f32_16x16x32_bf16(qa0, b0, z, 0, 0, 0);
            z = __builtin_amdgcn_mfma_f32_16x16x32_bf16(qa1, b1, z, 0, 0, 0);
            s[nf] = z;
        }
        if (kb == qt) {
            #pragma unroll
            for (int nf = 0; nf < 4; ++nf) {
                int kcol = kb * 64 + nf * 16 + lr;
                #pragma unroll
                for (int r = 0; r < 4; ++r)
                    if (kcol > qrow_base + r) s[nf][r] = -1e30f;
            }
        }
        // ---- online softmax ----
        float mloc[4];
        #pragma unroll
        for (int r = 0; r < 4; ++r)
            mloc[r] = fmaxf(fmaxf(s[0][r], s[1][r]), fmaxf(s[2][r], s[3][r]));
        #pragma unroll
        for (int r = 0; r < 4; ++r) {
            mloc[r] = fmaxf(mloc[r], __shfl_xor(mloc[r], 1));
            mloc[r] = fmaxf(mloc[r], __shfl_xor(mloc[r], 2));
            mloc[r] = fmaxf(mloc[r], __shfl_xor(mloc[r], 4));
            mloc[r] = fmaxf(mloc[r], __shfl_xor(mloc[r], 8));
        }
        float alpha[4], psum[4];
        #pragma unroll
        for (int r = 0; r < 4; ++r) {
            float mnew = fmaxf(m[r], mloc[r]);
            alpha[r] = __expf(m[r] - mnew);
            m[r] = mnew;
            psum[r] = 0.0f;
        }
        #pragma unroll
        for (int nf = 0; nf < 4; ++nf)
            #pragma unroll
            for (int r = 0; r < 4; ++r) {
                float pv2 = __expf(s[nf][r] - m[r]);
                s[nf][r] = pv2;
                psum[r] += pv2;
            }
        #pragma unroll
        for (int r = 0; r < 4; ++r) {
            psum[r] += __shfl_xor(psum[r], 1);
            psum[r] += __shfl_xor(psum[r], 2);
            psum[r] += __shfl_xor(psum[r], 4);
            psum[r] += __shfl_xor(psum[r], 8);
            l[r] = l[r] * alpha[r] + psum[r];
        }
        // ---- P -> wave-private LDS strip ----
        #pragma unroll
        for (int nf = 0; nf < 4; ++nf)
            #pragma unroll
            for (int r = 0; r < 4; ++r)
                Ps[w][lkg * 4 + r][nf * 16 + lr] = bf16r(s[nf][r]);
        #pragma unroll
        for (int df = 0; df < 4; ++df)
            #pragma unroll
            for (int r = 0; r < 4; ++r)
                oacc[df][r] *= alpha[r];
        // ---- PV ----
        s16x8 pa0 = *(const s16x8*)&Ps[w][lr][lk];
        s16x8 pa1 = *(const s16x8*)&Ps[w][lr][32 + lk];
        #pragma unroll
        for (int df = 0; df < 4; ++df) {
            int vr = df * 16 + lr;
            int sw = ((vr >> 3) & 7) << 3;
            s16x8 v0 = *(const s16x8*)&Vt[vr][lk ^ sw];
            s16x8 v1 = *(const s16x8*)&Vt[vr][(32 + lk) ^ sw];
            oacc[df] = __builtin_amdgcn_mfma_f32_16x16x32_bf16(pa0, v0, oacc[df], 0, 0, 0);
            oacc[df] = __builtin_amdgcn_mfma_f32_16x16x32_bf16(pa1, v1, oacc[df], 0, 0, 0);
        }
    }

    float invl[4];
    #pragma unroll
    for (int r = 0; r < 4; ++r) invl[r] = 1.0f / l[r];
    #pragma unroll
    for (int r = 0; r < 4; ++r) {
        int qrow = qrow_base + r;
        int t = ((qrow & 1) << 10) + (qrow >> 1);
        unsigned short* op = attn_out + (size_t)t * 1024 + (h << 6) + lr;
        #pragma unroll
        for (int df = 0; df < 4; ++df)
            op[df * 16] = bf16r(oacc[df][r] * invl[r]);
    }
}

// ---------------- router (bf16 x) ----------------
__global__ void router_kernel(const unsigned short* __restrict__ xffn,
        const float* __restrict__ p_keys, const float* __restrict__ f_keys,
        const int* __restrict__ p_idx, const int* __restrict__ f_idx,
        const float* __restrict__ p_val, const float* __restrict__ f_val,
        const float* __restrict__ p_bias, const float* __restrict__ f_bias,
        float* __restrict__ sc) {
    int tl = blockIdx.x, hf = blockIdx.y;
    int t = hf * 1024 + tl;
    const float* keys = hf ? f_keys : p_keys;
    const int* idx    = hf ? f_idx  : p_idx;
    const float* val  = hf ? f_val  : p_val;
    const float* bias = hf ? f_bias : p_bias;
    int tid = threadIdx.x;
    float acc[16];
    #pragma unroll
    for (int e = 0; e < 16; ++e) acc[e] = 0.0f;
    const unsigned short* x = xffn + (size_t)t * DMODEL;
    for (int d = tid; d < 1024; d += 256) {
        float xd = ubf(x[d]);
        const float* kr = keys + d * 16;
        #pragma unroll
        for (int e4 = 0; e4 < 4; ++e4) {
            float4 kv = *(const float4*)(kr + e4 * 4);
            acc[e4*4+0] += xd * kv.x;
            acc[e4*4+1] += xd * kv.y;
            acc[e4*4+2] += xd * kv.z;
            acc[e4*4+3] += xd * kv.w;
        }
    }
    #pragma unroll
    for (int e = 0; e < 16; ++e) {
        float v = acc[e];
        v += __shfl_down(v, 32); v += __shfl_down(v, 16); v += __shfl_down(v, 8);
        v += __shfl_down(v, 4);  v += __shfl_down(v, 2);  v += __shfl_down(v, 1);
        acc[e] = v;
    }
    __shared__ float part[4][16];
    __shared__ float logit[16];
    __shared__ float sg[4];
    int wave = tid >> 6, ln = tid & 63;
    if (ln == 0) {
        #pragma unroll
        for (int e = 0; e < 16; ++e) part[wave][e] = acc[e];
    }
    __syncthreads();
    if (tid < 16) logit[tid] = part[0][tid] + part[1][tid] + part[2][tid] + part[3][tid];
    __syncthreads();
    if (tid < 4) {
        int ii = idx[tl * 4 + tid];
        float v = val[tl * 4 + tid] + logit[ii] + bias[ii];
        sg[tid] = 1.0f / (1.0f + expf(-v));
    }
    __syncthreads();
    if (tid < 4) {
        float ssum = sg[0] + sg[1] + sg[2] + sg[3];
        sc[t * 4 + tid] = sg[tid] / ssum;
    }
}

// ---------------- expert bucketing (single workgroup) ----------------
__global__ __launch_bounds__(1024) void buckets_kernel(
        const int* __restrict__ p_idx, const int* __restrict__ f_idx,
        int* __restrict__ counts, int* __restrict__ offsets,
        int* __restrict__ pair_p) {
    __shared__ int lcnt[32], loff[32], lcur[32];
    int tid = threadIdx.x;
    if (tid < 32) { lcnt[tid] = 0; lcur[tid] = 0; }
    __syncthreads();
    for (int p = tid; p < NPAIR; p += 1024) {
        int hf = p >> 12, rem = p & 4095;
        int e = (hf ? f_idx : p_idx)[rem];
        atomicAdd(&lcnt[(hf << 4) + e], 1);
    }
    __syncthreads();
    if (tid == 0) {
        int o = 0;
        for (int b = 0; b < 32; ++b) { loff[b] = o; o += lcnt[b]; }
    }
    __syncthreads();
    for (int p = tid; p < NPAIR; p += 1024) {
        int hf = p >> 12, rem = p & 4095;
        int e = (hf ? f_idx : p_idx)[rem];
        int b = (hf << 4) + e;
        int pos = atomicAdd(&lcur[b], 1);
        pair_p[loff[b] + pos] = p;
    }
    if (tid < 32) { counts[tid] = lcnt[tid]; offsets[tid] = loff[tid]; }
}

// ---------------------------------------------------------------------------
// MFMA GEMM: C = A(bf16)[M,K] @ B(f32->bf16)[K,N]. BM=128, BK=32.
// A-staging: pure 16B copies. B-staging: lanes along k (conflict-free),
// cvt via v_cvt_pk. Register prefetch. OUTBF: bf16 output.
// MODE 0: store; 1: C+= ; 2: C=AB+resid.
// ---------------------------------------------------------------------------
template<int MODE, int BN2, int OUTBF>
__global__ __launch_bounds__(256) void mfma_gemm(
        const unsigned short* __restrict__ A, const float* __restrict__ B,
        void* __restrict__ Cv, const float* __restrict__ resid,
        int M, int N, int K) {
    constexpr int NI = BN2 / 32;
    __shared__ alignas(16) unsigned short As[128][40];
    __shared__ alignas(16) unsigned short Bs[BN2][40];
    int tid = threadIdx.x;
    int m0 = blockIdx.y * 128, n0 = blockIdx.x * BN2;
    int w = tid >> 6, lane = tid & 63;
    int wm = (w >> 1) * 64, wn = (w & 1) * (BN2 / 2);
    int lr = lane & 15, lk = (lane >> 4) << 3;
    int ar = tid >> 2, ac = (tid & 3) << 3;
    int bn = (tid >> 3) << 2, bk = (tid & 7) << 2;
    bool bact = true;
    if (BN2 == 64) bact = (tid < 128);
    const unsigned short* Ap0 = A + (size_t)(m0 + ar) * K + ac;
    const unsigned short* Ap1 = Ap0 + (size_t)64 * K;
    const float* Bp = B + (size_t)bk * N + n0 + bn;

    f32x4 acc[4][NI] = {};
    u16x8 a0c, a1c, a0n, a1n;
    f32x4 b_c[4], b_n[4];
    a0c = *(const u16x8*)Ap0;
    a1c = *(const u16x8*)Ap1;
    if (bact) {
        #pragma unroll
        for (int j = 0; j < 4; ++j)
            b_c[j] = *(const f32x4*)(Bp + (size_t)j * N);
    }
    for (int k0 = 0; k0 < K; k0 += 32) {
        __syncthreads();
        if (k0 + 32 < K) {
            a0n = *(const u16x8*)(Ap0 + k0 + 32);
            a1n = *(const u16x8*)(Ap1 + k0 + 32);
            if (bact) {
                const float* bp = Bp + (size_t)(k0 + 32) * N;
                #pragma unroll
                for (int j = 0; j < 4; ++j)
                    b_n[j] = *(const f32x4*)(bp + (size_t)j * N);
            }
        }
        *(u16x8*)&As[ar][ac] = a0c;
        *(u16x8*)&As[ar + 64][ac] = a1c;
        if (bact) {
            #pragma unroll
            for (int jj = 0; jj < 4; ++jj) {
                u32x2 pv;
                pv.x = cvtpk(b_c[0][jj], b_c[1][jj]);
                pv.y = cvtpk(b_c[2][jj], b_c[3][jj]);
                *(u32x2*)&Bs[bn + jj][bk] = pv;
            }
        }
        __syncthreads();
        s16x8 af[4], bfr[NI];
        #pragma unroll
        for (int mi = 0; mi < 4; ++mi)
            af[mi] = *(const s16x8*)&As[wm + mi * 16 + lr][lk];
        #pragma unroll
        for (int ni = 0; ni < NI; ++ni)
            bfr[ni] = *(const s16x8*)&Bs[wn + ni * 16 + lr][lk];
        #pragma unroll
        for (int mi = 0; mi < 4; ++mi)
            #pragma unroll
            for (int ni = 0; ni < NI; ++ni)
                acc[mi][ni] = __builtin_amdgcn_mfma_f32_16x16x32_bf16(
                                  af[mi], bfr[ni], acc[mi][ni], 0, 0, 0);
        a0c = a0n; a1c = a1n;
        #pragma unroll
        for (int j = 0; j < 4; ++j) b_c[j] = b_n[j];
    }
    #pragma unroll
    for (int mi = 0; mi < 4; ++mi)
        #pragma unroll
        for (int r = 0; r < 4; ++r) {
            int row = m0 + wm + mi * 16 + ((lane >> 4) << 2) + r;
            size_t rb = (size_t)row * N + n0 + wn + lr;
            #pragma unroll
            for (int ni = 0; ni < NI; ++ni) {
                size_t off = rb + ni * 16;
                float v = acc[mi][ni][r];
                if constexpr (OUTBF) {
                    ((unsigned short*)Cv)[off] = bf16r(v);
                } else {
                    float* Cf = (float*)Cv;
                    if (MODE == 1) v += Cf[off];
                    if (MODE == 2) v += resid[off];
                    Cf[off] = v;
                }
            }
        }
}

// ---------------------------------------------------------------------------
// MFMA gate+up SwiGLU. A bf16 (gathered or dense), B f32->cvt_pk, out bf16.
// ---------------------------------------------------------------------------
template<int MOE>
__global__ __launch_bounds__(256) void mfma_gateup(
        const unsigned short* __restrict__ X, const float* __restrict__ Wp,
        const float* __restrict__ Wf, const int* __restrict__ pair_p,
        const int* __restrict__ counts, const int* __restrict__ offsets,
        unsigned short* __restrict__ Hout) {
    __shared__ alignas(16) unsigned short As[128][40];
    __shared__ alignas(16) unsigned short Bsg[64][40];
    __shared__ alignas(16) unsigned short Bsu[64][40];
    __shared__ int toks[128];
    int tid = threadIdx.x;
    int rem = 128, slot0 = 0, m0 = 0, n0, ldb;
    const float *Wg, *Wu;
    if (MOE) {
        int bucket = blockIdx.y;
        int cnt = counts[bucket];
        int tile0 = blockIdx.x * 128;
        if (tile0 >= cnt) return;
        n0 = blockIdx.z * 64;
        int e = bucket & 15;
        const float* base = (bucket >> 4) ? Wf : Wp;
        Wg = base + (size_t)e * (DMODEL * FDIM) + n0;
        Wu = base + (size_t)(NEXP + e) * (DMODEL * FDIM) + n0;
        ldb = FDIM;
        slot0 = offsets[bucket] + tile0;
        rem = cnt - tile0;
        if (tid < 128)
            toks[tid] = (tid < rem) ? pair2tok(pair_p[slot0 + tid]) : 0;
    } else {
        m0 = blockIdx.y * 128;
        n0 = blockIdx.x * 64;
        Wg = Wp + n0;
        Wu = Wp + DSH + n0;
        ldb = 2 * DSH;
    }
    int w = tid >> 6, lane = tid & 63;
    int wm = (w >> 1) * 64, wn = (w & 1) * 32;
    int lr = lane & 15, lk = (lane >> 4) << 3;
    int ar = tid >> 2, ac = (tid & 3) << 3;
    int t2 = tid & 127, wq = tid >> 7;
    int bn = (t2 >> 3) << 2, bk = (t2 & 7) << 2;
    const float* bsrc = wq ? Wu : Wg;
    if (MOE) __syncthreads();
    const unsigned short *Xp0, *Xp1;
    {
        int x0 = MOE ? toks[ar] : (m0 + ar);
        int x1 = MOE ? toks[ar + 64] : (m0 + ar + 64);
        Xp0 = X + (size_t)x0 * DMODEL + ac;
        Xp1 = X + (size_t)x1 * DMODEL + ac;
    }
    f32x4 ag[4][2] = {}, au[4][2] = {};
    u16x8 a0c, a1c, a0n, a1n;
    f32x4 b_c[4], b_n[4];
    a0c = *(const u16x8*)Xp0;
    a1c = *(const u16x8*)Xp1;
    const float* Bp = bsrc + (size_t)bk * ldb + bn;
    #pragma unroll
    for (int j = 0; j < 4; ++j)
        b_c[j] = *(const f32x4*)(Bp + (size_t)j * ldb);
    for (int k0 = 0; k0 < DMODEL; k0 += 32) {
        __syncthreads();
        if (k0 + 32 < DMODEL) {
            a0n = *(const u16x8*)(Xp0 + k0 + 32);
            a1n = *(const u16x8*)(Xp1 + k0 + 32);
            const float* bp = Bp + (size_t)(k0 + 32) * ldb;
            #pragma unroll
            for (int j = 0; j < 4; ++j)
                b_n[j] = *(const f32x4*)(bp + (size_t)j * ldb);
        }
        *(u16x8*)&As[ar][ac] = a0c;
        *(u16x8*)&As[ar + 64][ac] = a1c;
        {
            unsigned short (*bl)[40] = wq ? Bsu : Bsg;
            #pragma unroll
            for (int jj = 0; jj < 4; ++jj) {
                u32x2 pv;
                pv.x = cvtpk(b_c[0][jj], b_c[1][jj]);
                pv.y = cvtpk(b_c[2][jj], b_c[3][jj]);
                *(u32x2*)&bl[bn + jj][bk] = pv;
            }
        }
        __syncthreads();
        s16x8 af[4], bg[2], bu[2];
        #pragma unroll
        for (int mi = 0; mi < 4; ++mi)
            af[mi] = *(const s16x8*)&As[wm + mi * 16 + lr][lk];
        #pragma unroll
        for (int ni = 0; ni < 2; ++ni) {
            bg[ni] = *(const s16x8*)&Bsg[wn + ni * 16 + lr][lk];
            bu[ni] = *(const s16x8*)&Bsu[wn + ni * 16 + lr][lk];
        }
        #pragma unroll
        for (int mi = 0; mi < 4; ++mi)
            #pragma unroll
            for (int ni = 0; ni < 2; ++ni) {
                ag[mi][ni] = __builtin_amdgcn_mfma_f32_16x16x32_bf16(
                                 af[mi], bg[ni], ag[mi][ni], 0, 0, 0);
                au[mi][ni] = __builtin_amdgcn_mfma_f32_16x16x32_bf16(
                                 af[mi], bu[ni], au[mi][ni], 0, 0, 0);
            }
        a0c = a0n; a1c = a1n;
        #pragma unroll
        for (int j = 0; j < 4; ++j) b_c[j] = b_n[j];
    }
    #pragma unroll
    for (int mi = 0; mi < 4; ++mi)
        #pragma unroll
        for (int r = 0; r < 4; ++r) {
            int rloc = wm + mi * 16 + ((lane >> 4) << 2) + r;
            if (MOE && rloc >= rem) continue;
            size_t rowb = MOE ? (size_t)(slot0 + rloc) * FDIM
                              : (size_t)(m0 + rloc) * DSH;
            #pragma unroll
            for (int ni = 0; ni < 2; ++ni) {
                float g = ag[mi][ni][r], u = au[mi][ni][r];
                Hout[rowb + n0 + wn + ni * 16 + lr] = bf16r(g * sigm(g) * u);
            }
        }
}

// ---------------------------------------------------------------------------
// MFMA MoE down: y += sc * (h(bf16) @ Wd^T). Wd staged row-major along k.
// ---------------------------------------------------------------------------
__global__ __launch_bounds__(256) void mfma_moe_down(
        const unsigned short* __restrict__ h_pairs,
        const float* __restrict__ p_experts, const float* __restrict__ f_experts,
        const int* __restrict__ pair_p, const int* __restrict__ counts,
        const int* __restrict__ offsets, const float* __restrict__ sc,
        float* __restrict__ y) {
    __shared__ alignas(16) unsigned short As[128][40];
    __shared__ alignas(16) unsigned short Bs[128][40];
    __shared__ int   tokd[128];
    __shared__ float scd[128];
    int tid = threadIdx.x;
    int bucket = blockIdx.y;
    int cnt = counts[bucket];
    int tile0 = blockIdx.x * 128;
    if (tile0 >= cnt) return;
    int d0 = blockIdx.z * 128;
    int e = bucket & 15;
    const float* base = (bucket >> 4) ? f_experts : p_experts;
    const float* Wd = base + (size_t)(2 * NEXP + e) * (DMODEL * FDIM);
    int slot0 = offsets[bucket] + tile0;
    int rem = cnt - tile0;
    if (tid < 128) {
        int ok = tid < rem;
        int pr = ok ? pair_p[slot0 + tid] : 0;
        tokd[tid] = pair2tok(pr);
        scd[tid]  = ok ? sc[pr] : 0.0f;
    }
    int w = tid >> 6, lane = tid & 63;
    int wm = (w >> 1) * 64, wn = (w & 1) * 64;
    int lr = lane & 15, lk = (lane >> 4) << 3;
    int ar = tid >> 2, ac = (tid & 3) << 3;
    int br = tid >> 3, bc = (tid & 7) << 2;
    const unsigned short* Ap0 = h_pairs + (size_t)(slot0 + ar) * FDIM + ac;
    const unsigned short* Ap1 = Ap0 + (size_t)64 * FDIM;
    const float* Bp0 = Wd + (size_t)(d0 + br) * FDIM + bc;
    f32x4 acc[4][4] = {};
    u16x8 a0c, a1c, a0n, a1n;
    f32x4 b_c[4], b_n[4];
    a0c = *(const u16x8*)Ap0;
    a1c = *(const u16x8*)Ap1;
    #pragma unroll
    for (int i = 0; i < 4; ++i)
        b_c[i] = *(const f32x4*)(Bp0 + (size_t)(32 * i) * FDIM);
    for (int k0 = 0; k0 < FDIM; k0 += 32) {
        __syncthreads();
        if (k0 + 32 < FDIM) {
            a0n = *(const u16x8*)(Ap0 + k0 + 32);
            a1n = *(const u16x8*)(Ap1 + k0 + 32);
            #pragma unroll
            for (int i = 0; i < 4; ++i)
                b_n[i] = *(const f32x4*)(Bp0 + (size_t)(32 * i) * FDIM + k0 + 32);
        }
        *(u16x8*)&As[ar][ac] = a0c;
        *(u16x8*)&As[ar + 64][ac] = a1c;
        #pragma unroll
        for (int i = 0; i < 4; ++i) {
            u32x2 pv;
            pv.x = cvtpk(b_c[i][0], b_c[i][1]);
            pv.y = cvtpk(b_c[i][2], b_c[i][3]);
            *(u32x2*)&Bs[br + 32 * i][bc] = pv;
        }
        __syncthreads();
        s16x8 af[4], bfr[4];
        #pragma unroll
        for (int mi = 0; mi < 4; ++mi)
            af[mi] = *(const s16x8*)&As[wm + mi * 16 + lr][lk];
        #pragma unroll
        for (int ni = 0; ni < 4; ++ni)
            bfr[ni] = *(const s16x8*)&Bs[wn + ni * 16 + lr][lk];
        #pragma unroll
        for (int mi = 0; mi < 4; ++mi)
            #pragma unroll
            for (int ni = 0; ni < 4; ++ni)
                acc[mi][ni] = __builtin_amdgcn_mfma_f32_16x16x32_bf16(
                                  af[mi], bfr[ni], acc[mi][ni], 0, 0, 0);
        a0c = a0n; a1c = a1n;
        #pragma unroll
        for (int i = 0; i < 4; ++i) b_c[i] = b_n[i];
    }
    #pragma unroll
    for (int mi = 0; mi < 4; ++mi)
        #pragma unroll
        for (int r = 0; r < 4; ++r) {
            int rloc = wm + mi * 16 + ((lane >> 4) << 2) + r;
            if (rloc < rem) {
                int   t = tokd[rloc];
                float s = scd[rloc];
                float* yp = y + (size_t)t * DMODEL + d0 + wn + lr;
                #pragma unroll
                for (int ni = 0; ni < 4; ++ni)
                    atomicAdd(yp + ni * 16, s * acc[mi][ni][r]);
            }
        }
}

// ===========================================================================
extern "C" void kernel_launch(void* const* d_in, const int* in_sizes, int n_in,
                              void* d_out, int out_size, void* d_ws, size_t ws_size,
                              hipStream_t stream) {
    const float* x_input  = (const float*)d_in[0];
    const int*   p_idx    = (const int*)d_in[1];
    const float* p_val    = (const float*)d_in[2];
    const int*   f_idx    = (const int*)d_in[3];
    const float* f_val    = (const float*)d_in[4];
    const float* attn_w   = (const float*)d_in[5];
    const float* ffn_w    = (const float*)d_in[6];
    const float* W_attn   = (const float*)d_in[7];
    const float* W_attn_o = (const float*)d_in[8];
    const float* ffn_up   = (const float*)d_in[9];
    const float* ffn_down = (const float*)d_in[10];
    const float* p_exp    = (const float*)d_in[11];
    const float* f_exp    = (const float*)d_in[12];
    const float* p_keys   = (const float*)d_in[13];
    const float* f_keys   = (const float*)d_in[14];
    const float* p_bias   = (const float*)d_in[15];
    const float* f_bias   = (const float*)d_in[16];
    float* y32 = (float*)d_out;
    (void)in_sizes; (void)n_in; (void)out_size; (void)ws_size;

    float* ws = (float*)d_ws;
    unsigned short* xnormh    = (unsigned short*)ws;               // 2048x1024 bf16
    unsigned short* attn_outh = (unsigned short*)ws;               // alias (xnorm dead)
    unsigned short* qkvh      = (unsigned short*)(ws + 2097152);   // 2048x3072 bf16
    unsigned short* h_pairsh  = (unsigned short*)(ws + 2097152);   // alias (qkv dead)
    unsigned short* hsh       = (unsigned short*)(ws + 2097152);   // alias (h_pairs dead)
    float* x_ffn_in  = ws + 8388608;                               // f32
    unsigned short* x_ffnh = (unsigned short*)(ws + 10485760);     // 2048x1024 bf16
    float* sc        = ws + 12582912;
    int*   counts    = (int*)(ws + 12591104);
    int*   offsets   = counts + 32;
    int*   pair_p    = offsets + 32;

    // 1) attn-input RMSNorm -> bf16
    rmsnorm_kernel<<<T_TOT, 256, 0, stream>>>(x_input, attn_w, xnormh);
    // 2) QKV projection (bf16 A, bf16 out)
    mfma_gemm<0, 128, 1><<<dim3(24, 16), 256, 0, stream>>>(xnormh, W_attn, qkvh,
                                                           nullptr, T_TOT, 3072, 1024);
    // 3) RoPE in-place on bf16 q,k
    rope_kernel<<<T_TOT, 256, 0, stream>>>(qkvh);
    // 4) causal MFMA flash attention -> bf16
    attn_mfma_kernel<<<dim3(32, NHEADS), 256, 0, stream>>>(qkvh, attn_outh);
    // 5) O-projection + residual -> f32 x_ffn_in
    mfma_gemm<2, 64, 0><<<dim3(16, 16), 256, 0, stream>>>(attn_outh, W_attn_o,
                                                          x_ffn_in, x_input,
                                                          T_TOT, 1024, 1024);
    // 6) ffn RMSNorm -> bf16
    rmsnorm_kernel<<<T_TOT, 256, 0, stream>>>(x_ffn_in, ffn_w, x_ffnh);
    // 7) router scores (bf16 x)
    router_kernel<<<dim3(1024, 2), 256, 0, stream>>>(x_ffnh, p_keys, f_keys,
                                                     p_idx, f_idx, p_val, f_val,
                                                     p_bias, f_bias, sc);
    // 8) expert buckets
    buckets_kernel<<<1, 1024, 0, stream>>>(p_idx, f_idx, counts, offsets, pair_p);
    // 9) MoE gate/up + silu -> bf16 h_pairs
    mfma_gateup<1><<<dim3(4, 32, 8), 256, 0, stream>>>(x_ffnh, p_exp, f_exp,
                                                       pair_p, counts, offsets,
                                                       h_pairsh);
    // 10) y := x_ffn_in
    hipMemcpyAsync(y32, x_ffn_in, (size_t)T_TOT * DMODEL * sizeof(float),
                   hipMemcpyDeviceToDevice, stream);
    // 11) MoE down: atomic accumulate into y
    mfma_moe_down<<<dim3(4, 32, 8), 256, 0, stream>>>(h_pairsh, p_exp, f_exp,
                                                      pair_p, counts, offsets,
                                                      sc, y32);
    // 12) shared expert gate/up -> bf16 hs
    mfma_gateup<0><<<dim3(32, 16), 256, 0, stream>>>(x_ffnh, ffn_up, nullptr,
                                                     nullptr, nullptr, nullptr, hsh);
    // 13) shared expert down, accumulate into y
    mfma_gemm<1, 64, 0><<<dim3(16, 16), 256, 0, stream>>>(hsh, ffn_down, y32,
                                                          nullptr, T_TOT, 1024, 2048);
}

// Round 6
// 628.230 us; speedup vs baseline: 5.1971x; 1.0952x over previous
//
#include <hip/hip_runtime.h>

// ---------------------------------------------------------------------------
// MoE transformer block, MI355X. Round 10: latency-structure fix for all
// MFMA GEMMs — LDS double-buffer (ONE barrier per K-step) + depth-2 register
// prefetch with statically-named slots (unroll-by-2 K loop). Global loads for
// step k+2 issue before compute of step k (~2 sub-steps of vmcnt slack).
// Numerics identical to round 9. Attention/norms/router unchanged.
// Workspace (float offsets):
//   [0,1.05M)      xnormh / attn_outh (bf16, aliased)
//   [2.10M,8.39M)  qkvh -> h_pairsh -> hsh (bf16, aliased)
//   [8.39M,10.49M) x_ffn_in (f32)
//   [10.49M,11.53M) x_ffnh (bf16)
//   [12.58M...)    sc, counts, offsets, pair_p
// ---------------------------------------------------------------------------

#define T_TOT   2048
#define DMODEL  1024
#define NHEADS  16
#define NEXP    16
#define FDIM    512
#define DSH     2048
#define NPAIR   8192

typedef __attribute__((ext_vector_type(4))) float          f32x4;
typedef __attribute__((ext_vector_type(8))) short          s16x8;   // MFMA A/B frag
typedef __attribute__((ext_vector_type(8))) unsigned short u16x8;
typedef __attribute__((ext_vector_type(2))) unsigned int   u32x2;

__device__ __forceinline__ float sigm(float x) { return 1.0f / (1.0f + __expf(-x)); }

// RTNE f32 -> bf16 (bit trick; scalar epilogues)
__device__ __forceinline__ unsigned short bf16r(float f) {
    union { float f; unsigned int u; } v; v.f = f;
    unsigned int r = v.u + 0x7fffu + ((v.u >> 16) & 1u);
    return (unsigned short)(r >> 16);
}

// hw packed convert: dst.lo = bf16(lo), dst.hi = bf16(hi)  (RNE)
__device__ __forceinline__ unsigned int cvtpk(float lo, float hi) {
    unsigned int r;
    asm("v_cvt_pk_bf16_f32 %0, %1, %2" : "=v"(r) : "v"(lo), "v"(hi));
    return r;
}

__device__ __forceinline__ float ubf(unsigned short u) {
    union { unsigned int i; float f; } v; v.i = (unsigned int)u << 16; return v.f;
}

__device__ __forceinline__ int pair2tok(int p) {
    return ((p >> 12) << 10) + ((p & 4095) >> 2);
}

// shared MFMA micro-tile: 4xNI frags from LDS buffers
template<int NI>
__device__ __forceinline__ void tile_mma(
        const unsigned short (*Asb)[40], const unsigned short (*Bsb)[40],
        int wm, int wn, int lr, int lk, f32x4 (&acc)[4][NI]) {
    s16x8 af[4], bfr[NI];
    #pragma unroll
    for (int mi = 0; mi < 4; ++mi)
        af[mi] = *(const s16x8*)&Asb[wm + mi * 16 + lr][lk];
    #pragma unroll
    for (int ni = 0; ni < NI; ++ni)
        bfr[ni] = *(const s16x8*)&Bsb[wn + ni * 16 + lr][lk];
    #pragma unroll
    for (int mi = 0; mi < 4; ++mi)
        #pragma unroll
        for (int ni = 0; ni < NI; ++ni)
            acc[mi][ni] = __builtin_amdgcn_mfma_f32_16x16x32_bf16(
                              af[mi], bfr[ni], acc[mi][ni], 0, 0, 0);
}

// gate+up micro-tile: one A-frag set feeds both B buffers
__device__ __forceinline__ void gu_mma(
        const unsigned short (*Asb)[40], const unsigned short (*Bg)[40],
        const unsigned short (*Bu)[40], int wm, int wn, int lr, int lk,
        f32x4 (&ag)[4][2], f32x4 (&au)[4][2]) {
    s16x8 af[4], bg[2], bu[2];
    #pragma unroll
    for (int mi = 0; mi < 4; ++mi)
        af[mi] = *(const s16x8*)&Asb[wm + mi * 16 + lr][lk];
    #pragma unroll
    for (int ni = 0; ni < 2; ++ni) {
        bg[ni] = *(const s16x8*)&Bg[wn + ni * 16 + lr][lk];
        bu[ni] = *(const s16x8*)&Bu[wn + ni * 16 + lr][lk];
    }
    #pragma unroll
    for (int mi = 0; mi < 4; ++mi)
        #pragma unroll
        for (int ni = 0; ni < 2; ++ni) {
            ag[mi][ni] = __builtin_amdgcn_mfma_f32_16x16x32_bf16(
                             af[mi], bg[ni], ag[mi][ni], 0, 0, 0);
            au[mi][ni] = __builtin_amdgcn_mfma_f32_16x16x32_bf16(
                             af[mi], bu[ni], au[mi][ni], 0, 0, 0);
        }
}

// ---------------- RMSNorm (f32 in, bf16 out) ----------------
__global__ void rmsnorm_kernel(const float* __restrict__ x,
                               const float* __restrict__ w,
                               unsigned short* __restrict__ out) {
    int t = blockIdx.x, tid = threadIdx.x;
    float4 xv = *(const float4*)(x + (size_t)t * DMODEL + tid * 4);
    __shared__ float rb[256];
    rb[tid] = xv.x*xv.x + xv.y*xv.y + xv.z*xv.z + xv.w*xv.w;
    __syncthreads();
    for (int s = 128; s > 0; s >>= 1) { if (tid < s) rb[tid] += rb[tid+s]; __syncthreads(); }
    float scale = rsqrtf(rb[0] * (1.0f/1024.0f) + 1e-5f);
    float4 wv = *(const float4*)(w + tid * 4);
    u32x2 pv;
    pv.x = cvtpk(xv.x * scale * wv.x, xv.y * scale * wv.y);
    pv.y = cvtpk(xv.z * scale * wv.z, xv.w * scale * wv.w);
    *(u32x2*)(out + (size_t)t * DMODEL + tid * 4) = pv;
}

// ---------------- RoPE, in-place on bf16 qkv rows (q and k only) -----------
__global__ void rope_kernel(unsigned short* __restrict__ qkv) {
    int t = blockIdx.x, tid = threadIdx.x;
    int s = t & 1023;
    unsigned short* row = qkv + (size_t)t * 3072;
    for (int pp = tid; pp < 512; pp += 256) {
        int h = pp >> 5, i = pp & 31;
        float fr = (float)s * exp2f(-0.41524101186092028f * (float)i);
        float sn, cs;
        sincosf(fr, &sn, &cs);
        int o1 = (h << 6) + i, o2 = o1 + 32;
        float x1 = ubf(row[o1]), x2 = ubf(row[o2]);
        row[o1] = bf16r(x1 * cs + x2 * sn);
        row[o2] = bf16r(x2 * cs - x1 * sn);
        x1 = ubf(row[1024 + o1]); x2 = ubf(row[1024 + o2]);
        row[1024 + o1] = bf16r(x1 * cs + x2 * sn);
        row[1024 + o2] = bf16r(x2 * cs - x1 * sn);
    }
}

// ---------------- MFMA flash attention (causal, online softmax) -------------
__global__ __launch_bounds__(256) void attn_mfma_kernel(
        const unsigned short* __restrict__ qkv,
        unsigned short* __restrict__ attn_out) {
    int qt = blockIdx.x, h = blockIdx.y;
    __shared__ alignas(16) unsigned short Qs[64][72];
    __shared__ alignas(16) unsigned short Ks[64][72];
    __shared__ alignas(16) unsigned short Vt[64][72];    // [d][key^swz]
    __shared__ alignas(16) unsigned short Ps[4][16][72];
    int tid = threadIdx.x;
    int w = tid >> 6, lane = tid & 63;
    int lr = lane & 15, lkg = lane >> 4, lk = lkg << 3;
    int kr = tid >> 3, kc = (tid & 7) << 3;

    #pragma unroll
    for (int i = 0; i < 2; ++i) {
        int rr = kr + 32 * i;
        int p = qt * 64 + rr;
        int t = ((p & 1) << 10) + (p >> 1);
        u16x8 q = *(const u16x8*)(qkv + (size_t)t * 3072 + (h << 6) + kc);
        unsigned int* dst = (unsigned int*)&Qs[rr][kc];
        dst[0] = cvtpk(ubf(q[0]) * 0.125f, ubf(q[1]) * 0.125f);
        dst[1] = cvtpk(ubf(q[2]) * 0.125f, ubf(q[3]) * 0.125f);
        dst[2] = cvtpk(ubf(q[4]) * 0.125f, ubf(q[5]) * 0.125f);
        dst[3] = cvtpk(ubf(q[6]) * 0.125f, ubf(q[7]) * 0.125f);
    }
    u16x8 pkv[2], pvv[2];
    #pragma unroll
    for (int i = 0; i < 2; ++i) {
        int rr = kr + 32 * i;
        int t = ((rr & 1) << 10) + (rr >> 1);
        const unsigned short* b = qkv + (size_t)t * 3072 + (h << 6) + kc;
        pkv[i] = *(const u16x8*)(b + 1024);
        pvv[i] = *(const u16x8*)(b + 2048);
    }
    __syncthreads();
    s16x8 qa0 = *(const s16x8*)&Qs[(w << 4) + lr][lk];
    s16x8 qa1 = *(const s16x8*)&Qs[(w << 4) + lr][32 + lk];

    float m[4], l[4];
    f32x4 oacc[4];
    #pragma unroll
    for (int r = 0; r < 4; ++r) { m[r] = -1e30f; l[r] = 0.0f; }
    #pragma unroll
    for (int df = 0; df < 4; ++df) oacc[df] = (f32x4)0.0f;

    int qrow_base = qt * 64 + w * 16 + lkg * 4;

    for (int kb = 0; kb <= qt; ++kb) {
        __syncthreads();
        u16x8 ck[2], cv[2];
        #pragma unroll
        for (int i = 0; i < 2; ++i) { ck[i] = pkv[i]; cv[i] = pvv[i]; }
        if (kb + 1 <= qt) {
            #pragma unroll
            for (int i = 0; i < 2; ++i) {
                int rr = kr + 32 * i;
                int p = (kb + 1) * 64 + rr;
                int t = ((p & 1) << 10) + (p >> 1);
                const unsigned short* b = qkv + (size_t)t * 3072 + (h << 6) + kc;
                pkv[i] = *(const u16x8*)(b + 1024);
                pvv[i] = *(const u16x8*)(b + 2048);
            }
        }
        #pragma unroll
        for (int i = 0; i < 2; ++i) {
            int rr = kr + 32 * i;
            *(u16x8*)&Ks[rr][kc] = ck[i];
            #pragma unroll
            for (int j = 0; j < 8; ++j) {
                int vrow = kc + j;
                int sw = ((vrow >> 3) & 7) << 3;
                Vt[vrow][rr ^ sw] = cv[i][j];
            }
        }
        __syncthreads();

        f32x4 s[4];
        #pragma unroll
        for (int nf = 0; nf < 4; ++nf) {
            s16x8 b0 = *(const s16x8*)&Ks[nf * 16 + lr][lk];
            s16x8 b1 = *(const s16x8*)&Ks[nf * 16 + lr][32 + lk];
            f32x4 z = (f32x4)0.0f;
            z = __builtin_amdgcn_mfma_f32_16x16x32_bf16(qa0, b0, z, 0, 0, 0);
            z = __builtin_amdgcn_mfma_f32_16x16x32_bf16(qa1, b1, z, 0, 0, 0);
            s[nf] = z;
        }
        if (kb == qt) {
            #pragma unroll
            for (int nf = 0; nf < 4; ++nf) {
                int kcol = kb * 64 + nf * 16 + lr;
                #pragma unroll
                for (int r = 0; r < 4; ++r)
                    if (kcol > qrow_base + r) s[nf][r] = -1e30f;
            }
        }
        float mloc[4];
        #pragma unroll
        for (int r = 0; r < 4; ++r)
            mloc[r] = fmaxf(fmaxf(s[0][r], s[1][r]), fmaxf(s[2][r], s[3][r]));
        #pragma unroll
        for (int r = 0; r < 4; ++r) {
            mloc[r] = fmaxf(mloc[r], __shfl_xor(mloc[r], 1));
            mloc[r] = fmaxf(mloc[r], __shfl_xor(mloc[r], 2));
            mloc[r] = fmaxf(mloc[r], __shfl_xor(mloc[r], 4));
            mloc[r] = fmaxf(mloc[r], __shfl_xor(mloc[r], 8));
        }
        float alpha[4], psum[4];
        #pragma unroll
        for (int r = 0; r < 4; ++r) {
            float mnew = fmaxf(m[r], mloc[r]);
            alpha[r] = __expf(m[r] - mnew);
            m[r] = mnew;
            psum[r] = 0.0f;
        }
        #pragma unroll
        for (int nf = 0; nf < 4; ++nf)
            #pragma unroll
            for (int r = 0; r < 4; ++r) {
                float pv2 = __expf(s[nf][r] - m[r]);
                s[nf][r] = pv2;
                psum[r] += pv2;
            }
        #pragma unroll
        for (int r = 0; r < 4; ++r) {
            psum[r] += __shfl_xor(psum[r], 1);
            psum[r] += __shfl_xor(psum[r], 2);
            psum[r] += __shfl_xor(psum[r], 4);
            psum[r] += __shfl_xor(psum[r], 8);
            l[r] = l[r] * alpha[r] + psum[r];
        }
        #pragma unroll
        for (int nf = 0; nf < 4; ++nf)
            #pragma unroll
            for (int r = 0; r < 4; ++r)
                Ps[w][lkg * 4 + r][nf * 16 + lr] = bf16r(s[nf][r]);
        #pragma unroll
        for (int df = 0; df < 4; ++df)
            #pragma unroll
            for (int r = 0; r < 4; ++r)
                oacc[df][r] *= alpha[r];
        s16x8 pa0 = *(const s16x8*)&Ps[w][lr][lk];
        s16x8 pa1 = *(const s16x8*)&Ps[w][lr][32 + lk];
        #pragma unroll
        for (int df = 0; df < 4; ++df) {
            int vr = df * 16 + lr;
            int sw = ((vr >> 3) & 7) << 3;
            s16x8 v0 = *(const s16x8*)&Vt[vr][lk ^ sw];
            s16x8 v1 = *(const s16x8*)&Vt[vr][(32 + lk) ^ sw];
            oacc[df] = __builtin_amdgcn_mfma_f32_16x16x32_bf16(pa0, v0, oacc[df], 0, 0, 0);
            oacc[df] = __builtin_amdgcn_mfma_f32_16x16x32_bf16(pa1, v1, oacc[df], 0, 0, 0);
        }
    }

    float invl[4];
    #pragma unroll
    for (int r = 0; r < 4; ++r) invl[r] = 1.0f / l[r];
    #pragma unroll
    for (int r = 0; r < 4; ++r) {
        int qrow = qrow_base + r;
        int t = ((qrow & 1) << 10) + (qrow >> 1);
        unsigned short* op = attn_out + (size_t)t * 1024 + (h << 6) + lr;
        #pragma unroll
        for (int df = 0; df < 4; ++df)
            op[df * 16] = bf16r(oacc[df][r] * invl[r]);
    }
}

// ---------------- router (bf16 x) ----------------
__global__ void router_kernel(const unsigned short* __restrict__ xffn,
        const float* __restrict__ p_keys, const float* __restrict__ f_keys,
        const int* __restrict__ p_idx, const int* __restrict__ f_idx,
        const float* __restrict__ p_val, const float* __restrict__ f_val,
        const float* __restrict__ p_bias, const float* __restrict__ f_bias,
        float* __restrict__ sc) {
    int tl = blockIdx.x, hf = blockIdx.y;
    int t = hf * 1024 + tl;
    const float* keys = hf ? f_keys : p_keys;
    const int* idx    = hf ? f_idx  : p_idx;
    const float* val  = hf ? f_val  : p_val;
    const float* bias = hf ? f_bias : p_bias;
    int tid = threadIdx.x;
    float acc[16];
    #pragma unroll
    for (int e = 0; e < 16; ++e) acc[e] = 0.0f;
    const unsigned short* x = xffn + (size_t)t * DMODEL;
    for (int d = tid; d < 1024; d += 256) {
        float xd = ubf(x[d]);
        const float* kr = keys + d * 16;
        #pragma unroll
        for (int e4 = 0; e4 < 4; ++e4) {
            float4 kv = *(const float4*)(kr + e4 * 4);
            acc[e4*4+0] += xd * kv.x;
            acc[e4*4+1] += xd * kv.y;
            acc[e4*4+2] += xd * kv.z;
            acc[e4*4+3] += xd * kv.w;
        }
    }
    #pragma unroll
    for (int e = 0; e < 16; ++e) {
        float v = acc[e];
        v += __shfl_down(v, 32); v += __shfl_down(v, 16); v += __shfl_down(v, 8);
        v += __shfl_down(v, 4);  v += __shfl_down(v, 2);  v += __shfl_down(v, 1);
        acc[e] = v;
    }
    __shared__ float part[4][16];
    __shared__ float logit[16];
    __shared__ float sg[4];
    int wave = tid >> 6, ln = tid & 63;
    if (ln == 0) {
        #pragma unroll
        for (int e = 0; e < 16; ++e) part[wave][e] = acc[e];
    }
    __syncthreads();
    if (tid < 16) logit[tid] = part[0][tid] + part[1][tid] + part[2][tid] + part[3][tid];
    __syncthreads();
    if (tid < 4) {
        int ii = idx[tl * 4 + tid];
        float v = val[tl * 4 + tid] + logit[ii] + bias[ii];
        sg[tid] = 1.0f / (1.0f + expf(-v));
    }
    __syncthreads();
    if (tid < 4) {
        float ssum = sg[0] + sg[1] + sg[2] + sg[3];
        sc[t * 4 + tid] = sg[tid] / ssum;
    }
}

// ---------------- expert bucketing (single workgroup) ----------------
__global__ __launch_bounds__(1024) void buckets_kernel(
        const int* __restrict__ p_idx, const int* __restrict__ f_idx,
        int* __restrict__ counts, int* __restrict__ offsets,
        int* __restrict__ pair_p) {
    __shared__ int lcnt[32], loff[32], lcur[32];
    int tid = threadIdx.x;
    if (tid < 32) { lcnt[tid] = 0; lcur[tid] = 0; }
    __syncthreads();
    for (int p = tid; p < NPAIR; p += 1024) {
        int hf = p >> 12, rem = p & 4095;
        int e = (hf ? f_idx : p_idx)[rem];
        atomicAdd(&lcnt[(hf << 4) + e], 1);
    }
    __syncthreads();
    if (tid == 0) {
        int o = 0;
        for (int b = 0; b < 32; ++b) { loff[b] = o; o += lcnt[b]; }
    }
    __syncthreads();
    for (int p = tid; p < NPAIR; p += 1024) {
        int hf = p >> 12, rem = p & 4095;
        int e = (hf ? f_idx : p_idx)[rem];
        int b = (hf << 4) + e;
        int pos = atomicAdd(&lcur[b], 1);
        pair_p[loff[b] + pos] = p;
    }
    if (tid < 32) { counts[tid] = lcnt[tid]; offsets[tid] = loff[tid]; }
}

// ---------------------------------------------------------------------------
// MFMA GEMM: C = A(bf16)[M,K] @ B(f32->bf16)[K,N]. BM=128, BK=32.
// LDS double-buffer, one barrier per K-step, depth-2 reg prefetch (static
// slots, unroll-by-2 K loop). K must be a multiple of 64.
// MODE 0: store; 1: C+= ; 2: C=AB+resid. OUTBF: bf16 output.
// ---------------------------------------------------------------------------
template<int MODE, int BN2, int OUTBF>
__global__ __launch_bounds__(256) void mfma_gemm(
        const unsigned short* __restrict__ A, const float* __restrict__ B,
        void* __restrict__ Cv, const float* __restrict__ resid,
        int M, int N, int K) {
    constexpr int NI = BN2 / 32;
    __shared__ alignas(16) unsigned short As[2][128][40];
    __shared__ alignas(16) unsigned short Bs[2][BN2][40];
    int tid = threadIdx.x;
    int m0 = blockIdx.y * 128, n0 = blockIdx.x * BN2;
    int w = tid >> 6, lane = tid & 63;
    int wm = (w >> 1) * 64, wn = (w & 1) * (BN2 / 2);
    int lr = lane & 15, lk = (lane >> 4) << 3;
    int ar = tid >> 2, ac = (tid & 3) << 3;
    int bn = (tid >> 3) << 2, bk = (tid & 7) << 2;
    bool bact = true;
    if (BN2 == 64) bact = (tid < 128);
    const unsigned short* Ap0 = A + (size_t)(m0 + ar) * K + ac;
    const unsigned short* Ap1 = Ap0 + (size_t)64 * K;
    const float* Bp = B + (size_t)bk * N + n0 + bn;

    f32x4 acc[4][NI] = {};
    u16x8 aA0, aA1, aB0, aB1;
    f32x4 bA[4], bB[4];

#define GM_LOAD(A0, A1, BV, KK) do {                                      \
        A0 = *(const u16x8*)(Ap0 + (KK));                                 \
        A1 = *(const u16x8*)(Ap1 + (KK));                                 \
        if (bact) {                                                       \
            const float* bp_ = Bp + (size_t)(KK) * N;                     \
            _Pragma("unroll")                                             \
            for (int j = 0; j < 4; ++j)                                   \
                BV[j] = *(const f32x4*)(bp_ + (size_t)j * N);             \
        }                                                                 \
    } while (0)

#define GM_WRITE(BUF, A0, A1, BV) do {                                    \
        *(u16x8*)&As[BUF][ar][ac] = A0;                                   \
        *(u16x8*)&As[BUF][ar + 64][ac] = A1;                              \
        if (bact) {                                                       \
            _Pragma("unroll")                                             \
            for (int jj = 0; jj < 4; ++jj) {                              \
                u32x2 pv_;                                                \
                pv_.x = cvtpk(BV[0][jj], BV[1][jj]);                      \
                pv_.y = cvtpk(BV[2][jj], BV[3][jj]);                      \
                *(u32x2*)&Bs[BUF][bn + jj][bk] = pv_;                     \
            }                                                             \
        }                                                                 \
    } while (0)

    GM_LOAD(aA0, aA1, bA, 0);
    GM_LOAD(aB0, aB1, bB, 32);
    GM_WRITE(0, aA0, aA1, bA);
    __syncthreads();
    for (int k0 = 0; k0 < K; k0 += 64) {
        if (k0 + 64 < K) GM_LOAD(aA0, aA1, bA, k0 + 64);
        tile_mma<NI>(As[0], Bs[0], wm, wn, lr, lk, acc);
        GM_WRITE(1, aB0, aB1, bB);
        __syncthreads();
        if (k0 + 96 < K) GM_LOAD(aB0, aB1, bB, k0 + 96);
        tile_mma<NI>(As[1], Bs[1], wm, wn, lr, lk, acc);
        if (k0 + 64 < K) GM_WRITE(0, aA0, aA1, bA);
        __syncthreads();
    }
#undef GM_LOAD
#undef GM_WRITE

    #pragma unroll
    for (int mi = 0; mi < 4; ++mi)
        #pragma unroll
        for (int r = 0; r < 4; ++r) {
            int row = m0 + wm + mi * 16 + ((lane >> 4) << 2) + r;
            size_t rb = (size_t)row * N + n0 + wn + lr;
            #pragma unroll
            for (int ni = 0; ni < NI; ++ni) {
                size_t off = rb + ni * 16;
                float v = acc[mi][ni][r];
                if constexpr (OUTBF) {
                    ((unsigned short*)Cv)[off] = bf16r(v);
                } else {
                    float* Cf = (float*)Cv;
                    if (MODE == 1) v += Cf[off];
                    if (MODE == 2) v += resid[off];
                    Cf[off] = v;
                }
            }
        }
}

// ---------------------------------------------------------------------------
// MFMA gate+up SwiGLU. Same dbuf/prefetch structure; dual B buffers.
// ---------------------------------------------------------------------------
template<int MOE>
__global__ __launch_bounds__(256) void mfma_gateup(
        const unsigned short* __restrict__ X, const float* __restrict__ Wp,
        const float* __restrict__ Wf, const int* __restrict__ pair_p,
        const int* __restrict__ counts, const int* __restrict__ offsets,
        unsigned short* __restrict__ Hout) {
    __shared__ alignas(16) unsigned short As[2][128][40];
    __shared__ alignas(16) unsigned short Bsg[2][64][40];
    __shared__ alignas(16) unsigned short Bsu[2][64][40];
    __shared__ int toks[128];
    int tid = threadIdx.x;
    int rem = 128, slot0 = 0, m0 = 0, n0, ldb;
    const float *Wg, *Wu;
    if (MOE) {
        int bucket = blockIdx.y;
        int cnt = counts[bucket];
        int tile0 = blockIdx.x * 128;
        if (tile0 >= cnt) return;
        n0 = blockIdx.z * 64;
        int e = bucket & 15;
        const float* base = (bucket >> 4) ? Wf : Wp;
        Wg = base + (size_t)e * (DMODEL * FDIM) + n0;
        Wu = base + (size_t)(NEXP + e) * (DMODEL * FDIM) + n0;
        ldb = FDIM;
        slot0 = offsets[bucket] + tile0;
        rem = cnt - tile0;
        if (tid < 128)
            toks[tid] = (tid < rem) ? pair2tok(pair_p[slot0 + tid]) : 0;
    } else {
        m0 = blockIdx.y * 128;
        n0 = blockIdx.x * 64;
        Wg = Wp + n0;
        Wu = Wp + DSH + n0;
        ldb = 2 * DSH;
    }
    int w = tid >> 6, lane = tid & 63;
    int wm = (w >> 1) * 64, wn = (w & 1) * 32;
    int lr = lane & 15, lk = (lane >> 4) << 3;
    int ar = tid >> 2, ac = (tid & 3) << 3;
    int t2 = tid & 127, wq = tid >> 7;
    int bn = (t2 >> 3) << 2, bk = (t2 & 7) << 2;
    const float* bsrc = wq ? Wu : Wg;
    if (MOE) __syncthreads();
    const unsigned short *Xp0, *Xp1;
    {
        int x0 = MOE ? toks[ar] : (m0 + ar);
        int x1 = MOE ? toks[ar + 64] : (m0 + ar + 64);
        Xp0 = X + (size_t)x0 * DMODEL + ac;
        Xp1 = X + (size_t)x1 * DMODEL + ac;
    }
    const float* Bp = bsrc + (size_t)bk * ldb + bn;
    f32x4 ag[4][2] = {}, au[4][2] = {};
    u16x8 aA0, aA1, aB0, aB1;
    f32x4 bA[4], bB[4];

#define GU_LOAD(A0, A1, BV, KK) do {                                      \
        A0 = *(const u16x8*)(Xp0 + (KK));                                 \
        A1 = *(const u16x8*)(Xp1 + (KK));                                 \
        {                                                                 \
            const float* bp_ = Bp + (size_t)(KK) * ldb;                   \
            _Pragma("unroll")                                             \
            for (int j = 0; j < 4; ++j)                                   \
                BV[j] = *(const f32x4*)(bp_ + (size_t)j * ldb);           \
        }                                                                 \
    } while (0)

#define GU_WRITE(BUF, A0, A1, BV) do {                                    \
        *(u16x8*)&As[BUF][ar][ac] = A0;                                   \
        *(u16x8*)&As[BUF][ar + 64][ac] = A1;                              \
        {                                                                 \
            unsigned short (*bl_)[40] = wq ? Bsu[BUF] : Bsg[BUF];         \
            _Pragma("unroll")                                             \
            for (int jj = 0; jj < 4; ++jj) {                              \
                u32x2 pv_;                                                \
                pv_.x = cvtpk(BV[0][jj], BV[1][jj]);                      \
                pv_.y = cvtpk(BV[2][jj], BV[3][jj]);                      \
                *(u32x2*)&bl_[bn + jj][bk] = pv_;                         \
            }                                                             \
        }                                                                 \
    } while (0)

    GU_LOAD(aA0, aA1, bA, 0);
    GU_LOAD(aB0, aB1, bB, 32);
    GU_WRITE(0, aA0, aA1, bA);
    __syncthreads();
    for (int k0 = 0; k0 < DMODEL; k0 += 64) {
        if (k0 + 64 < DMODEL) GU_LOAD(aA0, aA1, bA, k0 + 64);
        gu_mma(As[0], Bsg[0], Bsu[0], wm, wn, lr, lk, ag, au);
        GU_WRITE(1, aB0, aB1, bB);
        __syncthreads();
        if (k0 + 96 < DMODEL) GU_LOAD(aB0, aB1, bB, k0 + 96);
        gu_mma(As[1], Bsg[1], Bsu[1], wm, wn, lr, lk, ag, au);
        if (k0 + 64 < DMODEL) GU_WRITE(0, aA0, aA1, bA);
        __syncthreads();
    }
#undef GU_LOAD
#undef GU_WRITE

    #pragma unroll
    for (int mi = 0; mi < 4; ++mi)
        #pragma unroll
        for (int r = 0; r < 4; ++r) {
            int rloc = wm + mi * 16 + ((lane >> 4) << 2) + r;
            if (MOE && rloc >= rem) continue;
            size_t rowb = MOE ? (size_t)(slot0 + rloc) * FDIM
                              : (size_t)(m0 + rloc) * DSH;
            #pragma unroll
            for (int ni = 0; ni < 2; ++ni) {
                float g = ag[mi][ni][r], u = au[mi][ni][r];
                Hout[rowb + n0 + wn + ni * 16 + lr] = bf16r(g * sigm(g) * u);
            }
        }
}

// ---------------------------------------------------------------------------
// MFMA MoE down: y += sc * (h(bf16) @ Wd^T). Same dbuf/prefetch structure.
// ---------------------------------------------------------------------------
__global__ __launch_bounds__(256) void mfma_moe_down(
        const unsigned short* __restrict__ h_pairs,
        const float* __restrict__ p_experts, const float* __restrict__ f_experts,
        const int* __restrict__ pair_p, const int* __restrict__ counts,
        const int* __restrict__ offsets, const float* __restrict__ sc,
        float* __restrict__ y) {
    __shared__ alignas(16) unsigned short As[2][128][40];
    __shared__ alignas(16) unsigned short Bs[2][128][40];
    __shared__ int   tokd[128];
    __shared__ float scd[128];
    int tid = threadIdx.x;
    int bucket = blockIdx.y;
    int cnt = counts[bucket];
    int tile0 = blockIdx.x * 128;
    if (tile0 >= cnt) return;
    int d0 = blockIdx.z * 128;
    int e = bucket & 15;
    const float* base = (bucket >> 4) ? f_experts : p_experts;
    const float* Wd = base + (size_t)(2 * NEXP + e) * (DMODEL * FDIM);
    int slot0 = offsets[bucket] + tile0;
    int rem = cnt - tile0;
    if (tid < 128) {
        int ok = tid < rem;
        int pr = ok ? pair_p[slot0 + tid] : 0;
        tokd[tid] = pair2tok(pr);
        scd[tid]  = ok ? sc[pr] : 0.0f;
    }
    int w = tid >> 6, lane = tid & 63;
    int wm = (w >> 1) * 64, wn = (w & 1) * 64;
    int lr = lane & 15, lk = (lane >> 4) << 3;
    int ar = tid >> 2, ac = (tid & 3) << 3;
    int br = tid >> 3, bc = (tid & 7) << 2;
    const unsigned short* Ap0 = h_pairs + (size_t)(slot0 + ar) * FDIM + ac;
    const unsigned short* Ap1 = Ap0 + (size_t)64 * FDIM;
    const float* Bp0 = Wd + (size_t)(d0 + br) * FDIM + bc;
    f32x4 acc[4][4] = {};
    u16x8 aA0, aA1, aB0, aB1;
    f32x4 bA[4], bB[4];

#define MD_LOAD(A0, A1, BV, KK) do {                                      \
        A0 = *(const u16x8*)(Ap0 + (KK));                                 \
        A1 = *(const u16x8*)(Ap1 + (KK));                                 \
        _Pragma("unroll")                                                 \
        for (int i = 0; i < 4; ++i)                                       \
            BV[i] = *(const f32x4*)(Bp0 + (size_t)(32 * i) * FDIM + (KK));\
    } while (0)

#define MD_WRITE(BUF, A0, A1, BV) do {                                    \
        *(u16x8*)&As[BUF][ar][ac] = A0;                                   \
        *(u16x8*)&As[BUF][ar + 64][ac] = A1;                              \
        _Pragma("unroll")                                                 \
        for (int i = 0; i < 4; ++i) {                                     \
            u32x2 pv_;                                                    \
            pv_.x = cvtpk(BV[i][0], BV[i][1]);                            \
            pv_.y = cvtpk(BV[i][2], BV[i][3]);                            \
            *(u32x2*)&Bs[BUF][br + 32 * i][bc] = pv_;                     \
        }                                                                 \
    } while (0)

    MD_LOAD(aA0, aA1, bA, 0);
    MD_LOAD(aB0, aB1, bB, 32);
    MD_WRITE(0, aA0, aA1, bA);
    __syncthreads();
    for (int k0 = 0; k0 < FDIM; k0 += 64) {
        if (k0 + 64 < FDIM) MD_LOAD(aA0, aA1, bA, k0 + 64);
        tile_mma<4>(As[0], Bs[0], wm, wn, lr, lk, acc);
        MD_WRITE(1, aB0, aB1, bB);
        __syncthreads();
        if (k0 + 96 < FDIM) MD_LOAD(aB0, aB1, bB, k0 + 96);
        tile_mma<4>(As[1], Bs[1], wm, wn, lr, lk, acc);
        if (k0 + 64 < FDIM) MD_WRITE(0, aA0, aA1, bA);
        __syncthreads();
    }
#undef MD_LOAD
#undef MD_WRITE

    #pragma unroll
    for (int mi = 0; mi < 4; ++mi)
        #pragma unroll
        for (int r = 0; r < 4; ++r) {
            int rloc = wm + mi * 16 + ((lane >> 4) << 2) + r;
            if (rloc < rem) {
                int   t = tokd[rloc];
                float s = scd[rloc];
                float* yp = y + (size_t)t * DMODEL + d0 + wn + lr;
                #pragma unroll
                for (int ni = 0; ni < 4; ++ni)
                    atomicAdd(yp + ni * 16, s * acc[mi][ni][r]);
            }
        }
}

// ===========================================================================
extern "C" void kernel_launch(void* const* d_in, const int* in_sizes, int n_in,
                              void* d_out, int out_size, void* d_ws, size_t ws_size,
                              hipStream_t stream) {
    const float* x_input  = (const float*)d_in[0];
    const int*   p_idx    = (const int*)d_in[1];
    const float* p_val    = (const float*)d_in[2];
    const int*   f_idx    = (const int*)d_in[3];
    const float* f_val    = (const float*)d_in[4];
    const float* attn_w   = (const float*)d_in[5];
    const float* ffn_w    = (const float*)d_in[6];
    const float* W_attn   = (const float*)d_in[7];
    const float* W_attn_o = (const float*)d_in[8];
    const float* ffn_up   = (const float*)d_in[9];
    const float* ffn_down = (const float*)d_in[10];
    const float* p_exp    = (const float*)d_in[11];
    const float* f_exp    = (const float*)d_in[12];
    const float* p_keys   = (const float*)d_in[13];
    const float* f_keys   = (const float*)d_in[14];
    const float* p_bias   = (const float*)d_in[15];
    const float* f_bias   = (const float*)d_in[16];
    float* y32 = (float*)d_out;
    (void)in_sizes; (void)n_in; (void)out_size; (void)ws_size;

    float* ws = (float*)d_ws;
    unsigned short* xnormh    = (unsigned short*)ws;               // 2048x1024 bf16
    unsigned short* attn_outh = (unsigned short*)ws;               // alias (xnorm dead)
    unsigned short* qkvh      = (unsigned short*)(ws + 2097152);   // 2048x3072 bf16
    unsigned short* h_pairsh  = (unsigned short*)(ws + 2097152);   // alias (qkv dead)
    unsigned short* hsh       = (unsigned short*)(ws + 2097152);   // alias (h_pairs dead)
    float* x_ffn_in  = ws + 8388608;                               // f32
    unsigned short* x_ffnh = (unsigned short*)(ws + 10485760);     // 2048x1024 bf16
    float* sc        = ws + 12582912;
    int*   counts    = (int*)(ws + 12591104);
    int*   offsets   = counts + 32;
    int*   pair_p    = offsets + 32;

    // 1) attn-input RMSNorm -> bf16
    rmsnorm_kernel<<<T_TOT, 256, 0, stream>>>(x_input, attn_w, xnormh);
    // 2) QKV projection (bf16 A, bf16 out)
    mfma_gemm<0, 128, 1><<<dim3(24, 16), 256, 0, stream>>>(xnormh, W_attn, qkvh,
                                                           nullptr, T_TOT, 3072, 1024);
    // 3) RoPE in-place on bf16 q,k
    rope_kernel<<<T_TOT, 256, 0, stream>>>(qkvh);
    // 4) causal MFMA flash attention -> bf16
    attn_mfma_kernel<<<dim3(32, NHEADS), 256, 0, stream>>>(qkvh, attn_outh);
    // 5) O-projection + residual -> f32 x_ffn_in
    mfma_gemm<2, 64, 0><<<dim3(16, 16), 256, 0, stream>>>(attn_outh, W_attn_o,
                                                          x_ffn_in, x_input,
                                                          T_TOT, 1024, 1024);
    // 6) ffn RMSNorm -> bf16
    rmsnorm_kernel<<<T_TOT, 256, 0, stream>>>(x_ffn_in, ffn_w, x_ffnh);
    // 7) router scores (bf16 x)
    router_kernel<<<dim3(1024, 2), 256, 0, stream>>>(x_ffnh, p_keys, f_keys,
                                                     p_idx, f_idx, p_val, f_val,
                                                     p_bias, f_bias, sc);
    // 8) expert buckets
    buckets_kernel<<<1, 1024, 0, stream>>>(p_idx, f_idx, counts, offsets, pair_p);
    // 9) MoE gate/up + silu -> bf16 h_pairs
    mfma_gateup<1><<<dim3(4, 32, 8), 256, 0, stream>>>(x_ffnh, p_exp, f_exp,
                                                       pair_p, counts, offsets,
                                                       h_pairsh);
    // 10) y := x_ffn_in
    hipMemcpyAsync(y32, x_ffn_in, (size_t)T_TOT * DMODEL * sizeof(float),
                   hipMemcpyDeviceToDevice, stream);
    // 11) MoE down: atomic accumulate into y
    mfma_moe_down<<<dim3(4, 32, 8), 256, 0, stream>>>(h_pairsh, p_exp, f_exp,
                                                      pair_p, counts, offsets,
                                                      sc, y32);
    // 12) shared expert gate/up -> bf16 hs
    mfma_gateup<0><<<dim3(32, 16), 256, 0, stream>>>(x_ffnh, ffn_up, nullptr,
                                                     nullptr, nullptr, nullptr, hsh);
    // 13) shared expert down, accumulate into y
    mfma_gemm<1, 64, 0><<<dim3(16, 16), 256, 0, stream>>>(hsh, ffn_down, y32,
                                                          nullptr, T_TOT, 1024, 2048);
}

// Round 7
// 620.088 us; speedup vs baseline: 5.2653x; 1.0131x over previous
//
#include <hip/hip_runtime.h>

// ---------------------------------------------------------------------------
// MoE transformer block, MI355X. Round 11: MoE gate/up restructured for DRAM
// page efficiency. Old gateup read 64-col strips of W[k][n] (256B segments of
// 2KB rows -> ~1.7 TB/s wall). New moe_proj computes one matrix x 128-col
// strip per block (512B segments), writes raw g/u bf16 to scratch (aliased
// onto dead attn/qkv regions), then moe_silu combines. XCD-paired 1D grids
// for moe_proj / moe_down (x-tile siblings 8 ids apart -> same XCD L2).
// Dense gateup / qkv / o-proj / shared-down / attn unchanged from round 10.
// Workspace (float offsets), ~50.4MB total (unchanged):
//   [0,2.10M)      xnormh/attn_outh (bf16) -> gtmp (bf16 8192x512)
//   [2.10M,8.39M)  qkvh -> utmp(2.10M..4.19M) + h_pairsh(4.19M..6.29M) -> hsh
//   [8.39M,10.49M) x_ffn_in (f32)
//   [10.49M,11.53M) x_ffnh (bf16)
//   [12.58M...)    sc, counts, offsets, pair_p
// ---------------------------------------------------------------------------

#define T_TOT   2048
#define DMODEL  1024
#define NHEADS  16
#define NEXP    16
#define FDIM    512
#define DSH     2048
#define NPAIR   8192

typedef __attribute__((ext_vector_type(4))) float          f32x4;
typedef __attribute__((ext_vector_type(8))) short          s16x8;   // MFMA A/B frag
typedef __attribute__((ext_vector_type(8))) unsigned short u16x8;
typedef __attribute__((ext_vector_type(2))) unsigned int   u32x2;

__device__ __forceinline__ float sigm(float x) { return 1.0f / (1.0f + __expf(-x)); }

// RTNE f32 -> bf16 (bit trick; scalar epilogues)
__device__ __forceinline__ unsigned short bf16r(float f) {
    union { float f; unsigned int u; } v; v.f = f;
    unsigned int r = v.u + 0x7fffu + ((v.u >> 16) & 1u);
    return (unsigned short)(r >> 16);
}

// hw packed convert: dst.lo = bf16(lo), dst.hi = bf16(hi)  (RNE)
__device__ __forceinline__ unsigned int cvtpk(float lo, float hi) {
    unsigned int r;
    asm("v_cvt_pk_bf16_f32 %0, %1, %2" : "=v"(r) : "v"(lo), "v"(hi));
    return r;
}

__device__ __forceinline__ float ubf(unsigned short u) {
    union { unsigned int i; float f; } v; v.i = (unsigned int)u << 16; return v.f;
}

__device__ __forceinline__ int pair2tok(int p) {
    return ((p >> 12) << 10) + ((p & 4095) >> 2);
}

// shared MFMA micro-tile: 4xNI frags from LDS buffers
template<int NI>
__device__ __forceinline__ void tile_mma(
        const unsigned short (*Asb)[40], const unsigned short (*Bsb)[40],
        int wm, int wn, int lr, int lk, f32x4 (&acc)[4][NI]) {
    s16x8 af[4], bfr[NI];
    #pragma unroll
    for (int mi = 0; mi < 4; ++mi)
        af[mi] = *(const s16x8*)&Asb[wm + mi * 16 + lr][lk];
    #pragma unroll
    for (int ni = 0; ni < NI; ++ni)
        bfr[ni] = *(const s16x8*)&Bsb[wn + ni * 16 + lr][lk];
    #pragma unroll
    for (int mi = 0; mi < 4; ++mi)
        #pragma unroll
        for (int ni = 0; ni < NI; ++ni)
            acc[mi][ni] = __builtin_amdgcn_mfma_f32_16x16x32_bf16(
                              af[mi], bfr[ni], acc[mi][ni], 0, 0, 0);
}

// gate+up micro-tile (dense shared-expert path)
__device__ __forceinline__ void gu_mma(
        const unsigned short (*Asb)[40], const unsigned short (*Bg)[40],
        const unsigned short (*Bu)[40], int wm, int wn, int lr, int lk,
        f32x4 (&ag)[4][2], f32x4 (&au)[4][2]) {
    s16x8 af[4], bg[2], bu[2];
    #pragma unroll
    for (int mi = 0; mi < 4; ++mi)
        af[mi] = *(const s16x8*)&Asb[wm + mi * 16 + lr][lk];
    #pragma unroll
    for (int ni = 0; ni < 2; ++ni) {
        bg[ni] = *(const s16x8*)&Bg[wn + ni * 16 + lr][lk];
        bu[ni] = *(const s16x8*)&Bu[wn + ni * 16 + lr][lk];
    }
    #pragma unroll
    for (int mi = 0; mi < 4; ++mi)
        #pragma unroll
        for (int ni = 0; ni < 2; ++ni) {
            ag[mi][ni] = __builtin_amdgcn_mfma_f32_16x16x32_bf16(
                             af[mi], bg[ni], ag[mi][ni], 0, 0, 0);
            au[mi][ni] = __builtin_amdgcn_mfma_f32_16x16x32_bf16(
                             af[mi], bu[ni], au[mi][ni], 0, 0, 0);
        }
}

// ---------------- RMSNorm (f32 in, bf16 out) ----------------
__global__ void rmsnorm_kernel(const float* __restrict__ x,
                               const float* __restrict__ w,
                               unsigned short* __restrict__ out) {
    int t = blockIdx.x, tid = threadIdx.x;
    float4 xv = *(const float4*)(x + (size_t)t * DMODEL + tid * 4);
    __shared__ float rb[256];
    rb[tid] = xv.x*xv.x + xv.y*xv.y + xv.z*xv.z + xv.w*xv.w;
    __syncthreads();
    for (int s = 128; s > 0; s >>= 1) { if (tid < s) rb[tid] += rb[tid+s]; __syncthreads(); }
    float scale = rsqrtf(rb[0] * (1.0f/1024.0f) + 1e-5f);
    float4 wv = *(const float4*)(w + tid * 4);
    u32x2 pv;
    pv.x = cvtpk(xv.x * scale * wv.x, xv.y * scale * wv.y);
    pv.y = cvtpk(xv.z * scale * wv.z, xv.w * scale * wv.w);
    *(u32x2*)(out + (size_t)t * DMODEL + tid * 4) = pv;
}

// ---------------- RoPE, in-place on bf16 qkv rows (q and k only) -----------
__global__ void rope_kernel(unsigned short* __restrict__ qkv) {
    int t = blockIdx.x, tid = threadIdx.x;
    int s = t & 1023;
    unsigned short* row = qkv + (size_t)t * 3072;
    for (int pp = tid; pp < 512; pp += 256) {
        int h = pp >> 5, i = pp & 31;
        float fr = (float)s * exp2f(-0.41524101186092028f * (float)i);
        float sn, cs;
        sincosf(fr, &sn, &cs);
        int o1 = (h << 6) + i, o2 = o1 + 32;
        float x1 = ubf(row[o1]), x2 = ubf(row[o2]);
        row[o1] = bf16r(x1 * cs + x2 * sn);
        row[o2] = bf16r(x2 * cs - x1 * sn);
        x1 = ubf(row[1024 + o1]); x2 = ubf(row[1024 + o2]);
        row[1024 + o1] = bf16r(x1 * cs + x2 * sn);
        row[1024 + o2] = bf16r(x2 * cs - x1 * sn);
    }
}

// ---------------- MFMA flash attention (causal, online softmax) -------------
__global__ __launch_bounds__(256) void attn_mfma_kernel(
        const unsigned short* __restrict__ qkv,
        unsigned short* __restrict__ attn_out) {
    int qt = blockIdx.x, h = blockIdx.y;
    __shared__ alignas(16) unsigned short Qs[64][72];
    __shared__ alignas(16) unsigned short Ks[64][72];
    __shared__ alignas(16) unsigned short Vt[64][72];    // [d][key^swz]
    __shared__ alignas(16) unsigned short Ps[4][16][72];
    int tid = threadIdx.x;
    int w = tid >> 6, lane = tid & 63;
    int lr = lane & 15, lkg = lane >> 4, lk = lkg << 3;
    int kr = tid >> 3, kc = (tid & 7) << 3;

    #pragma unroll
    for (int i = 0; i < 2; ++i) {
        int rr = kr + 32 * i;
        int p = qt * 64 + rr;
        int t = ((p & 1) << 10) + (p >> 1);
        u16x8 q = *(const u16x8*)(qkv + (size_t)t * 3072 + (h << 6) + kc);
        unsigned int* dst = (unsigned int*)&Qs[rr][kc];
        dst[0] = cvtpk(ubf(q[0]) * 0.125f, ubf(q[1]) * 0.125f);
        dst[1] = cvtpk(ubf(q[2]) * 0.125f, ubf(q[3]) * 0.125f);
        dst[2] = cvtpk(ubf(q[4]) * 0.125f, ubf(q[5]) * 0.125f);
        dst[3] = cvtpk(ubf(q[6]) * 0.125f, ubf(q[7]) * 0.125f);
    }
    u16x8 pkv[2], pvv[2];
    #pragma unroll
    for (int i = 0; i < 2; ++i) {
        int rr = kr + 32 * i;
        int t = ((rr & 1) << 10) + (rr >> 1);
        const unsigned short* b = qkv + (size_t)t * 3072 + (h << 6) + kc;
        pkv[i] = *(const u16x8*)(b + 1024);
        pvv[i] = *(const u16x8*)(b + 2048);
    }
    __syncthreads();
    s16x8 qa0 = *(const s16x8*)&Qs[(w << 4) + lr][lk];
    s16x8 qa1 = *(const s16x8*)&Qs[(w << 4) + lr][32 + lk];

    float m[4], l[4];
    f32x4 oacc[4];
    #pragma unroll
    for (int r = 0; r < 4; ++r) { m[r] = -1e30f; l[r] = 0.0f; }
    #pragma unroll
    for (int df = 0; df < 4; ++df) oacc[df] = (f32x4)0.0f;

    int qrow_base = qt * 64 + w * 16 + lkg * 4;

    for (int kb = 0; kb <= qt; ++kb) {
        __syncthreads();
        u16x8 ck[2], cv[2];
        #pragma unroll
        for (int i = 0; i < 2; ++i) { ck[i] = pkv[i]; cv[i] = pvv[i]; }
        if (kb + 1 <= qt) {
            #pragma unroll
            for (int i = 0; i < 2; ++i) {
                int rr = kr + 32 * i;
                int p = (kb + 1) * 64 + rr;
                int t = ((p & 1) << 10) + (p >> 1);
                const unsigned short* b = qkv + (size_t)t * 3072 + (h << 6) + kc;
                pkv[i] = *(const u16x8*)(b + 1024);
                pvv[i] = *(const u16x8*)(b + 2048);
            }
        }
        #pragma unroll
        for (int i = 0; i < 2; ++i) {
            int rr = kr + 32 * i;
            *(u16x8*)&Ks[rr][kc] = ck[i];
            #pragma unroll
            for (int j = 0; j < 8; ++j) {
                int vrow = kc + j;
                int sw = ((vrow >> 3) & 7) << 3;
                Vt[vrow][rr ^ sw] = cv[i][j];
            }
        }
        __syncthreads();

        f32x4 s[4];
        #pragma unroll
        for (int nf = 0; nf < 4; ++nf) {
            s16x8 b0 = *(const s16x8*)&Ks[nf * 16 + lr][lk];
            s16x8 b1 = *(const s16x8*)&Ks[nf * 16 + lr][32 + lk];
            f32x4 z = (f32x4)0.0f;
            z = __builtin_amdgcn_mfma_f32_16x16x32_bf16(qa0, b0, z, 0, 0, 0);
            z = __builtin_amdgcn_mfma_f32_16x16x32_bf16(qa1, b1, z, 0, 0, 0);
            s[nf] = z;
        }
        if (kb == qt) {
            #pragma unroll
            for (int nf = 0; nf < 4; ++nf) {
                int kcol = kb * 64 + nf * 16 + lr;
                #pragma unroll
                for (int r = 0; r < 4; ++r)
                    if (kcol > qrow_base + r) s[nf][r] = -1e30f;
            }
        }
        float mloc[4];
        #pragma unroll
        for (int r = 0; r < 4; ++r)
            mloc[r] = fmaxf(fmaxf(s[0][r], s[1][r]), fmaxf(s[2][r], s[3][r]));
        #pragma unroll
        for (int r = 0; r < 4; ++r) {
            mloc[r] = fmaxf(mloc[r], __shfl_xor(mloc[r], 1));
            mloc[r] = fmaxf(mloc[r], __shfl_xor(mloc[r], 2));
            mloc[r] = fmaxf(mloc[r], __shfl_xor(mloc[r], 4));
            mloc[r] = fmaxf(mloc[r], __shfl_xor(mloc[r], 8));
        }
        float alpha[4], psum[4];
        #pragma unroll
        for (int r = 0; r < 4; ++r) {
            float mnew = fmaxf(m[r], mloc[r]);
            alpha[r] = __expf(m[r] - mnew);
            m[r] = mnew;
            psum[r] = 0.0f;
        }
        #pragma unroll
        for (int nf = 0; nf < 4; ++nf)
            #pragma unroll
            for (int r = 0; r < 4; ++r) {
                float pv2 = __expf(s[nf][r] - m[r]);
                s[nf][r] = pv2;
                psum[r] += pv2;
            }
        #pragma unroll
        for (int r = 0; r < 4; ++r) {
            psum[r] += __shfl_xor(psum[r], 1);
            psum[r] += __shfl_xor(psum[r], 2);
            psum[r] += __shfl_xor(psum[r], 4);
            psum[r] += __shfl_xor(psum[r], 8);
            l[r] = l[r] * alpha[r] + psum[r];
        }
        #pragma unroll
        for (int nf = 0; nf < 4; ++nf)
            #pragma unroll
            for (int r = 0; r < 4; ++r)
                Ps[w][lkg * 4 + r][nf * 16 + lr] = bf16r(s[nf][r]);
        #pragma unroll
        for (int df = 0; df < 4; ++df)
            #pragma unroll
            for (int r = 0; r < 4; ++r)
                oacc[df][r] *= alpha[r];
        s16x8 pa0 = *(const s16x8*)&Ps[w][lr][lk];
        s16x8 pa1 = *(const s16x8*)&Ps[w][lr][32 + lk];
        #pragma unroll
        for (int df = 0; df < 4; ++df) {
            int vr = df * 16 + lr;
            int sw = ((vr >> 3) & 7) << 3;
            s16x8 v0 = *(const s16x8*)&Vt[vr][lk ^ sw];
            s16x8 v1 = *(const s16x8*)&Vt[vr][(32 + lk) ^ sw];
            oacc[df] = __builtin_amdgcn_mfma_f32_16x16x32_bf16(pa0, v0, oacc[df], 0, 0, 0);
            oacc[df] = __builtin_amdgcn_mfma_f32_16x16x32_bf16(pa1, v1, oacc[df], 0, 0, 0);
        }
    }

    float invl[4];
    #pragma unroll
    for (int r = 0; r < 4; ++r) invl[r] = 1.0f / l[r];
    #pragma unroll
    for (int r = 0; r < 4; ++r) {
        int qrow = qrow_base + r;
        int t = ((qrow & 1) << 10) + (qrow >> 1);
        unsigned short* op = attn_out + (size_t)t * 1024 + (h << 6) + lr;
        #pragma unroll
        for (int df = 0; df < 4; ++df)
            op[df * 16] = bf16r(oacc[df][r] * invl[r]);
    }
}

// ---------------- router (bf16 x) ----------------
__global__ void router_kernel(const unsigned short* __restrict__ xffn,
        const float* __restrict__ p_keys, const float* __restrict__ f_keys,
        const int* __restrict__ p_idx, const int* __restrict__ f_idx,
        const float* __restrict__ p_val, const float* __restrict__ f_val,
        const float* __restrict__ p_bias, const float* __restrict__ f_bias,
        float* __restrict__ sc) {
    int tl = blockIdx.x, hf = blockIdx.y;
    int t = hf * 1024 + tl;
    const float* keys = hf ? f_keys : p_keys;
    const int* idx    = hf ? f_idx  : p_idx;
    const float* val  = hf ? f_val  : p_val;
    const float* bias = hf ? f_bias : p_bias;
    int tid = threadIdx.x;
    float acc[16];
    #pragma unroll
    for (int e = 0; e < 16; ++e) acc[e] = 0.0f;
    const unsigned short* x = xffn + (size_t)t * DMODEL;
    for (int d = tid; d < 1024; d += 256) {
        float xd = ubf(x[d]);
        const float* kr = keys + d * 16;
        #pragma unroll
        for (int e4 = 0; e4 < 4; ++e4) {
            float4 kv = *(const float4*)(kr + e4 * 4);
            acc[e4*4+0] += xd * kv.x;
            acc[e4*4+1] += xd * kv.y;
            acc[e4*4+2] += xd * kv.z;
            acc[e4*4+3] += xd * kv.w;
        }
    }
    #pragma unroll
    for (int e = 0; e < 16; ++e) {
        float v = acc[e];
        v += __shfl_down(v, 32); v += __shfl_down(v, 16); v += __shfl_down(v, 8);
        v += __shfl_down(v, 4);  v += __shfl_down(v, 2);  v += __shfl_down(v, 1);
        acc[e] = v;
    }
    __shared__ float part[4][16];
    __shared__ float logit[16];
    __shared__ float sg[4];
    int wave = tid >> 6, ln = tid & 63;
    if (ln == 0) {
        #pragma unroll
        for (int e = 0; e < 16; ++e) part[wave][e] = acc[e];
    }
    __syncthreads();
    if (tid < 16) logit[tid] = part[0][tid] + part[1][tid] + part[2][tid] + part[3][tid];
    __syncthreads();
    if (tid < 4) {
        int ii = idx[tl * 4 + tid];
        float v = val[tl * 4 + tid] + logit[ii] + bias[ii];
        sg[tid] = 1.0f / (1.0f + expf(-v));
    }
    __syncthreads();
    if (tid < 4) {
        float ssum = sg[0] + sg[1] + sg[2] + sg[3];
        sc[t * 4 + tid] = sg[tid] / ssum;
    }
}

// ---------------- expert bucketing (single workgroup) ----------------
__global__ __launch_bounds__(1024) void buckets_kernel(
        const int* __restrict__ p_idx, const int* __restrict__ f_idx,
        int* __restrict__ counts, int* __restrict__ offsets,
        int* __restrict__ pair_p) {
    __shared__ int lcnt[32], loff[32], lcur[32];
    int tid = threadIdx.x;
    if (tid < 32) { lcnt[tid] = 0; lcur[tid] = 0; }
    __syncthreads();
    for (int p = tid; p < NPAIR; p += 1024) {
        int hf = p >> 12, rem = p & 4095;
        int e = (hf ? f_idx : p_idx)[rem];
        atomicAdd(&lcnt[(hf << 4) + e], 1);
    }
    __syncthreads();
    if (tid == 0) {
        int o = 0;
        for (int b = 0; b < 32; ++b) { loff[b] = o; o += lcnt[b]; }
    }
    __syncthreads();
    for (int p = tid; p < NPAIR; p += 1024) {
        int hf = p >> 12, rem = p & 4095;
        int e = (hf ? f_idx : p_idx)[rem];
        int b = (hf << 4) + e;
        int pos = atomicAdd(&lcur[b], 1);
        pair_p[loff[b] + pos] = p;
    }
    if (tid < 32) { counts[tid] = lcnt[tid]; offsets[tid] = loff[tid]; }
}

// ---------------------------------------------------------------------------
// MFMA GEMM: C = A(bf16)[M,K] @ B(f32->bf16)[K,N]. BM=128, BK=32.
// LDS double-buffer, one barrier per K-step, depth-2 reg prefetch.
// MODE 0: store; 1: C+= ; 2: C=AB+resid. OUTBF: bf16 output.
// ---------------------------------------------------------------------------
template<int MODE, int BN2, int OUTBF>
__global__ __launch_bounds__(256) void mfma_gemm(
        const unsigned short* __restrict__ A, const float* __restrict__ B,
        void* __restrict__ Cv, const float* __restrict__ resid,
        int M, int N, int K) {
    constexpr int NI = BN2 / 32;
    __shared__ alignas(16) unsigned short As[2][128][40];
    __shared__ alignas(16) unsigned short Bs[2][BN2][40];
    int tid = threadIdx.x;
    int m0 = blockIdx.y * 128, n0 = blockIdx.x * BN2;
    int w = tid >> 6, lane = tid & 63;
    int wm = (w >> 1) * 64, wn = (w & 1) * (BN2 / 2);
    int lr = lane & 15, lk = (lane >> 4) << 3;
    int ar = tid >> 2, ac = (tid & 3) << 3;
    int bn = (tid >> 3) << 2, bk = (tid & 7) << 2;
    bool bact = true;
    if (BN2 == 64) bact = (tid < 128);
    const unsigned short* Ap0 = A + (size_t)(m0 + ar) * K + ac;
    const unsigned short* Ap1 = Ap0 + (size_t)64 * K;
    const float* Bp = B + (size_t)bk * N + n0 + bn;

    f32x4 acc[4][NI] = {};
    u16x8 aA0, aA1, aB0, aB1;
    f32x4 bA[4], bB[4];

#define GM_LOAD(A0, A1, BV, KK) do {                                      \
        A0 = *(const u16x8*)(Ap0 + (KK));                                 \
        A1 = *(const u16x8*)(Ap1 + (KK));                                 \
        if (bact) {                                                       \
            const float* bp_ = Bp + (size_t)(KK) * N;                     \
            _Pragma("unroll")                                             \
            for (int j = 0; j < 4; ++j)                                   \
                BV[j] = *(const f32x4*)(bp_ + (size_t)j * N);             \
        }                                                                 \
    } while (0)

#define GM_WRITE(BUF, A0, A1, BV) do {                                    \
        *(u16x8*)&As[BUF][ar][ac] = A0;                                   \
        *(u16x8*)&As[BUF][ar + 64][ac] = A1;                              \
        if (bact) {                                                       \
            _Pragma("unroll")                                             \
            for (int jj = 0; jj < 4; ++jj) {                              \
                u32x2 pv_;                                                \
                pv_.x = cvtpk(BV[0][jj], BV[1][jj]);                      \
                pv_.y = cvtpk(BV[2][jj], BV[3][jj]);                      \
                *(u32x2*)&Bs[BUF][bn + jj][bk] = pv_;                     \
            }                                                             \
        }                                                                 \
    } while (0)

    GM_LOAD(aA0, aA1, bA, 0);
    GM_LOAD(aB0, aB1, bB, 32);
    GM_WRITE(0, aA0, aA1, bA);
    __syncthreads();
    for (int k0 = 0; k0 < K; k0 += 64) {
        if (k0 + 64 < K) GM_LOAD(aA0, aA1, bA, k0 + 64);
        tile_mma<NI>(As[0], Bs[0], wm, wn, lr, lk, acc);
        GM_WRITE(1, aB0, aB1, bB);
        __syncthreads();
        if (k0 + 96 < K) GM_LOAD(aB0, aB1, bB, k0 + 96);
        tile_mma<NI>(As[1], Bs[1], wm, wn, lr, lk, acc);
        if (k0 + 64 < K) GM_WRITE(0, aA0, aA1, bA);
        __syncthreads();
    }
#undef GM_LOAD
#undef GM_WRITE

    #pragma unroll
    for (int mi = 0; mi < 4; ++mi)
        #pragma unroll
        for (int r = 0; r < 4; ++r) {
            int row = m0 + wm + mi * 16 + ((lane >> 4) << 2) + r;
            size_t rb = (size_t)row * N + n0 + wn + lr;
            #pragma unroll
            for (int ni = 0; ni < NI; ++ni) {
                size_t off = rb + ni * 16;
                float v = acc[mi][ni][r];
                if constexpr (OUTBF) {
                    ((unsigned short*)Cv)[off] = bf16r(v);
                } else {
                    float* Cf = (float*)Cv;
                    if (MODE == 1) v += Cf[off];
                    if (MODE == 2) v += resid[off];
                    Cf[off] = v;
                }
            }
        }
}

// ---------------------------------------------------------------------------
// Dense (shared expert) gate+up SwiGLU. BM=128, BN=64 per matrix, dbuf.
// ---------------------------------------------------------------------------
__global__ __launch_bounds__(256) void mfma_gateup_dense(
        const unsigned short* __restrict__ X, const float* __restrict__ W1,
        unsigned short* __restrict__ Hout) {
    __shared__ alignas(16) unsigned short As[2][128][40];
    __shared__ alignas(16) unsigned short Bsg[2][64][40];
    __shared__ alignas(16) unsigned short Bsu[2][64][40];
    int tid = threadIdx.x;
    int m0 = blockIdx.y * 128, n0 = blockIdx.x * 64;
    const float* Wg = W1 + n0;
    const float* Wu = W1 + DSH + n0;
    int ldb = 2 * DSH;
    int w = tid >> 6, lane = tid & 63;
    int wm = (w >> 1) * 64, wn = (w & 1) * 32;
    int lr = lane & 15, lk = (lane >> 4) << 3;
    int ar = tid >> 2, ac = (tid & 3) << 3;
    int t2 = tid & 127, wq = tid >> 7;
    int bn = (t2 >> 3) << 2, bk = (t2 & 7) << 2;
    const float* bsrc = wq ? Wu : Wg;
    const unsigned short* Xp0 = X + (size_t)(m0 + ar) * DMODEL + ac;
    const unsigned short* Xp1 = Xp0 + (size_t)64 * DMODEL;
    const float* Bp = bsrc + (size_t)bk * ldb + bn;
    f32x4 ag[4][2] = {}, au[4][2] = {};
    u16x8 aA0, aA1, aB0, aB1;
    f32x4 bA[4], bB[4];

#define GU_LOAD(A0, A1, BV, KK) do {                                      \
        A0 = *(const u16x8*)(Xp0 + (KK));                                 \
        A1 = *(const u16x8*)(Xp1 + (KK));                                 \
        {                                                                 \
            const float* bp_ = Bp + (size_t)(KK) * ldb;                   \
            _Pragma("unroll")                                             \
            for (int j = 0; j < 4; ++j)                                   \
                BV[j] = *(const f32x4*)(bp_ + (size_t)j * ldb);           \
        }                                                                 \
    } while (0)

#define GU_WRITE(BUF, A0, A1, BV) do {                                    \
        *(u16x8*)&As[BUF][ar][ac] = A0;                                   \
        *(u16x8*)&As[BUF][ar + 64][ac] = A1;                              \
        {                                                                 \
            unsigned short (*bl_)[40] = wq ? Bsu[BUF] : Bsg[BUF];         \
            _Pragma("unroll")                                             \
            for (int jj = 0; jj < 4; ++jj) {                              \
                u32x2 pv_;                                                \
                pv_.x = cvtpk(BV[0][jj], BV[1][jj]);                      \
                pv_.y = cvtpk(BV[2][jj], BV[3][jj]);                      \
                *(u32x2*)&bl_[bn + jj][bk] = pv_;                         \
            }                                                             \
        }                                                                 \
    } while (0)

    GU_LOAD(aA0, aA1, bA, 0);
    GU_LOAD(aB0, aB1, bB, 32);
    GU_WRITE(0, aA0, aA1, bA);
    __syncthreads();
    for (int k0 = 0; k0 < DMODEL; k0 += 64) {
        if (k0 + 64 < DMODEL) GU_LOAD(aA0, aA1, bA, k0 + 64);
        gu_mma(As[0], Bsg[0], Bsu[0], wm, wn, lr, lk, ag, au);
        GU_WRITE(1, aB0, aB1, bB);
        __syncthreads();
        if (k0 + 96 < DMODEL) GU_LOAD(aB0, aB1, bB, k0 + 96);
        gu_mma(As[1], Bsg[1], Bsu[1], wm, wn, lr, lk, ag, au);
        if (k0 + 64 < DMODEL) GU_WRITE(0, aA0, aA1, bA);
        __syncthreads();
    }
#undef GU_LOAD
#undef GU_WRITE

    #pragma unroll
    for (int mi = 0; mi < 4; ++mi)
        #pragma unroll
        for (int r = 0; r < 4; ++r) {
            int rloc = wm + mi * 16 + ((lane >> 4) << 2) + r;
            size_t rowb = (size_t)(m0 + rloc) * DSH;
            #pragma unroll
            for (int ni = 0; ni < 2; ++ni) {
                float g = ag[mi][ni][r], u = au[mi][ni][r];
                Hout[rowb + n0 + wn + ni * 16 + lr] = bf16r(g * sigm(g) * u);
            }
        }
}

// ---------------------------------------------------------------------------
// MoE projection: raw g or u tile. Block = (x-tile 128 pairs, bucket,
// matrix, 128-col f-strip). Weight rows read 128 cols wide (512B segments).
// 1D grid 1024: bucket=i>>5, xt=(i>>3)&3, z=i&7 (mat=z&1, strip=z>>1) —
// x-siblings 8 ids apart -> same XCD L2 for the shared weight strip.
// ---------------------------------------------------------------------------
__global__ __launch_bounds__(256) void moe_proj_kernel(
        const unsigned short* __restrict__ X,
        const float* __restrict__ p_experts, const float* __restrict__ f_experts,
        const int* __restrict__ pair_p, const int* __restrict__ counts,
        const int* __restrict__ offsets,
        unsigned short* __restrict__ gtmp, unsigned short* __restrict__ utmp) {
    __shared__ alignas(16) unsigned short As[2][128][40];
    __shared__ alignas(16) unsigned short Bs[2][128][40];
    __shared__ int toks[128];
    int i = blockIdx.x;
    int bucket = i >> 5, xt = (i >> 3) & 3, z = i & 7;
    int cnt = counts[bucket];
    int tile0 = xt * 128;
    if (tile0 >= cnt) return;
    int mat = z & 1, f0 = (z >> 1) * 128;
    int e = bucket & 15;
    const float* basep = (bucket >> 4) ? f_experts : p_experts;
    const float* W = basep + (size_t)((mat ? NEXP : 0) + e) * (DMODEL * FDIM) + f0;
    unsigned short* out = mat ? utmp : gtmp;
    int slot0 = offsets[bucket] + tile0;
    int rem = cnt - tile0;
    int tid = threadIdx.x;
    if (tid < 128)
        toks[tid] = (tid < rem) ? pair2tok(pair_p[slot0 + tid]) : 0;
    __syncthreads();
    int w = tid >> 6, lane = tid & 63;
    int wm = (w >> 1) * 64, wn = (w & 1) * 64;
    int lr = lane & 15, lk = (lane >> 4) << 3;
    int ar = tid >> 2, ac = (tid & 3) << 3;
    int bn = (tid >> 3) << 2, bk = (tid & 7) << 2;
    const unsigned short* Xp0 = X + (size_t)toks[ar] * DMODEL + ac;
    const unsigned short* Xp1 = X + (size_t)toks[ar + 64] * DMODEL + ac;
    const float* Bp = W + (size_t)bk * FDIM + bn;
    f32x4 acc[4][4] = {};
    u16x8 aA0, aA1, aB0, aB1;
    f32x4 bA[4], bB[4];

#define PR_LOAD(A0, A1, BV, KK) do {                                      \
        A0 = *(const u16x8*)(Xp0 + (KK));                                 \
        A1 = *(const u16x8*)(Xp1 + (KK));                                 \
        {                                                                 \
            const float* bp_ = Bp + (size_t)(KK) * FDIM;                  \
            _Pragma("unroll")                                             \
            for (int j = 0; j < 4; ++j)                                   \
                BV[j] = *(const f32x4*)(bp_ + (size_t)j * FDIM);          \
        }                                                                 \
    } while (0)

#define PR_WRITE(BUF, A0, A1, BV) do {                                    \
        *(u16x8*)&As[BUF][ar][ac] = A0;                                   \
        *(u16x8*)&As[BUF][ar + 64][ac] = A1;                              \
        _Pragma("unroll")                                                 \
        for (int jj = 0; jj < 4; ++jj) {                                  \
            u32x2 pv_;                                                    \
            pv_.x = cvtpk(BV[0][jj], BV[1][jj]);                          \
            pv_.y = cvtpk(BV[2][jj], BV[3][jj]);                          \
            *(u32x2*)&Bs[BUF][bn + jj][bk] = pv_;                         \
        }                                                                 \
    } while (0)

    PR_LOAD(aA0, aA1, bA, 0);
    PR_LOAD(aB0, aB1, bB, 32);
    PR_WRITE(0, aA0, aA1, bA);
    __syncthreads();
    for (int k0 = 0; k0 < DMODEL; k0 += 64) {
        if (k0 + 64 < DMODEL) PR_LOAD(aA0, aA1, bA, k0 + 64);
        tile_mma<4>(As[0], Bs[0], wm, wn, lr, lk, acc);
        PR_WRITE(1, aB0, aB1, bB);
        __syncthreads();
        if (k0 + 96 < DMODEL) PR_LOAD(aB0, aB1, bB, k0 + 96);
        tile_mma<4>(As[1], Bs[1], wm, wn, lr, lk, acc);
        if (k0 + 64 < DMODEL) PR_WRITE(0, aA0, aA1, bA);
        __syncthreads();
    }
#undef PR_LOAD
#undef PR_WRITE

    #pragma unroll
    for (int mi = 0; mi < 4; ++mi)
        #pragma unroll
        for (int r = 0; r < 4; ++r) {
            int rloc = wm + mi * 16 + ((lane >> 4) << 2) + r;
            if (rloc < rem) {
                size_t rowb = (size_t)(slot0 + rloc) * FDIM + f0 + wn + lr;
                #pragma unroll
                for (int ni = 0; ni < 4; ++ni)
                    out[rowb + ni * 16] = bf16r(acc[mi][ni][r]);
            }
        }
}

// ---------------- silu combine: h = silu(g) * u (bf16 in/out) --------------
__global__ void moe_silu_kernel(const unsigned short* __restrict__ g,
                                const unsigned short* __restrict__ u,
                                unsigned short* __restrict__ h) {
    size_t i = ((size_t)blockIdx.x * 256 + threadIdx.x) * 8;
    u16x8 gv = *(const u16x8*)(g + i);
    u16x8 uv = *(const u16x8*)(u + i);
    u16x8 o;
    #pragma unroll
    for (int j = 0; j < 8; ++j) {
        float gf = ubf(gv[j]);
        o[j] = bf16r(gf * sigm(gf) * ubf(uv[j]));
    }
    *(u16x8*)(h + i) = o;
}

// ---------------------------------------------------------------------------
// MFMA MoE down: y += sc * (h(bf16) @ Wd^T). Wd [d][f] contiguous rows.
// 1D grid 1024, same XCD-paired decode as moe_proj (z = 128-d strip).
// ---------------------------------------------------------------------------
__global__ __launch_bounds__(256) void mfma_moe_down(
        const unsigned short* __restrict__ h_pairs,
        const float* __restrict__ p_experts, const float* __restrict__ f_experts,
        const int* __restrict__ pair_p, const int* __restrict__ counts,
        const int* __restrict__ offsets, const float* __restrict__ sc,
        float* __restrict__ y) {
    __shared__ alignas(16) unsigned short As[2][128][40];
    __shared__ alignas(16) unsigned short Bs[2][128][40];
    __shared__ int   tokd[128];
    __shared__ float scd[128];
    int i = blockIdx.x;
    int bucket = i >> 5, xt = (i >> 3) & 3, z = i & 7;
    int cnt = counts[bucket];
    int tile0 = xt * 128;
    if (tile0 >= cnt) return;
    int d0 = z * 128;
    int e = bucket & 15;
    const float* base = (bucket >> 4) ? f_experts : p_experts;
    const float* Wd = base + (size_t)(2 * NEXP + e) * (DMODEL * FDIM);
    int slot0 = offsets[bucket] + tile0;
    int rem = cnt - tile0;
    int tid = threadIdx.x;
    if (tid < 128) {
        int ok = tid < rem;
        int pr = ok ? pair_p[slot0 + tid] : 0;
        tokd[tid] = pair2tok(pr);
        scd[tid]  = ok ? sc[pr] : 0.0f;
    }
    int w = tid >> 6, lane = tid & 63;
    int wm = (w >> 1) * 64, wn = (w & 1) * 64;
    int lr = lane & 15, lk = (lane >> 4) << 3;
    int ar = tid >> 2, ac = (tid & 3) << 3;
    int br = tid >> 3, bc = (tid & 7) << 2;
    const unsigned short* Ap0 = h_pairs + (size_t)(slot0 + ar) * FDIM + ac;
    const unsigned short* Ap1 = Ap0 + (size_t)64 * FDIM;
    const float* Bp0 = Wd + (size_t)(d0 + br) * FDIM + bc;
    f32x4 acc[4][4] = {};
    u16x8 aA0, aA1, aB0, aB1;
    f32x4 bA[4], bB[4];

#define MD_LOAD(A0, A1, BV, KK) do {                                      \
        A0 = *(const u16x8*)(Ap0 + (KK));                                 \
        A1 = *(const u16x8*)(Ap1 + (KK));                                 \
        _Pragma("unroll")                                                 \
        for (int i2 = 0; i2 < 4; ++i2)                                    \
            BV[i2] = *(const f32x4*)(Bp0 + (size_t)(32 * i2) * FDIM + (KK));\
    } while (0)

#define MD_WRITE(BUF, A0, A1, BV) do {                                    \
        *(u16x8*)&As[BUF][ar][ac] = A0;                                   \
        *(u16x8*)&As[BUF][ar + 64][ac] = A1;                              \
        _Pragma("unroll")                                                 \
        for (int i2 = 0; i2 < 4; ++i2) {                                  \
            u32x2 pv_;                                                    \
            pv_.x = cvtpk(BV[i2][0], BV[i2][1]);                          \
            pv_.y = cvtpk(BV[i2][2], BV[i2][3]);                          \
            *(u32x2*)&Bs[BUF][br + 32 * i2][bc] = pv_;                    \
        }                                                                 \
    } while (0)

    __syncthreads();   // tokd/scd visible (also covers Ap gather addresses)
    MD_LOAD(aA0, aA1, bA, 0);
    MD_LOAD(aB0, aB1, bB, 32);
    MD_WRITE(0, aA0, aA1, bA);
    __syncthreads();
    for (int k0 = 0; k0 < FDIM; k0 += 64) {
        if (k0 + 64 < FDIM) MD_LOAD(aA0, aA1, bA, k0 + 64);
        tile_mma<4>(As[0], Bs[0], wm, wn, lr, lk, acc);
        MD_WRITE(1, aB0, aB1, bB);
        __syncthreads();
        if (k0 + 96 < FDIM) MD_LOAD(aB0, aB1, bB, k0 + 96);
        tile_mma<4>(As[1], Bs[1], wm, wn, lr, lk, acc);
        if (k0 + 64 < FDIM) MD_WRITE(0, aA0, aA1, bA);
        __syncthreads();
    }
#undef MD_LOAD
#undef MD_WRITE

    #pragma unroll
    for (int mi = 0; mi < 4; ++mi)
        #pragma unroll
        for (int r = 0; r < 4; ++r) {
            int rloc = wm + mi * 16 + ((lane >> 4) << 2) + r;
            if (rloc < rem) {
                int   t = tokd[rloc];
                float s = scd[rloc];
                float* yp = y + (size_t)t * DMODEL + d0 + wn + lr;
                #pragma unroll
                for (int ni = 0; ni < 4; ++ni)
                    atomicAdd(yp + ni * 16, s * acc[mi][ni][r]);
            }
        }
}

// ===========================================================================
extern "C" void kernel_launch(void* const* d_in, const int* in_sizes, int n_in,
                              void* d_out, int out_size, void* d_ws, size_t ws_size,
                              hipStream_t stream) {
    const float* x_input  = (const float*)d_in[0];
    const int*   p_idx    = (const int*)d_in[1];
    const float* p_val    = (const float*)d_in[2];
    const int*   f_idx    = (const int*)d_in[3];
    const float* f_val    = (const float*)d_in[4];
    const float* attn_w   = (const float*)d_in[5];
    const float* ffn_w    = (const float*)d_in[6];
    const float* W_attn   = (const float*)d_in[7];
    const float* W_attn_o = (const float*)d_in[8];
    const float* ffn_up   = (const float*)d_in[9];
    const float* ffn_down = (const float*)d_in[10];
    const float* p_exp    = (const float*)d_in[11];
    const float* f_exp    = (const float*)d_in[12];
    const float* p_keys   = (const float*)d_in[13];
    const float* f_keys   = (const float*)d_in[14];
    const float* p_bias   = (const float*)d_in[15];
    const float* f_bias   = (const float*)d_in[16];
    float* y32 = (float*)d_out;
    (void)in_sizes; (void)n_in; (void)out_size; (void)ws_size;

    float* ws = (float*)d_ws;
    unsigned short* xnormh    = (unsigned short*)ws;               // region A
    unsigned short* attn_outh = (unsigned short*)ws;               // alias
    unsigned short* gtmp      = (unsigned short*)ws;               // alias (attn_out dead at step 9)
    unsigned short* qkvh      = (unsigned short*)(ws + 2097152);   // R1 base
    unsigned short* utmp      = (unsigned short*)(ws + 2097152);   // alias (qkv dead)
    unsigned short* h_pairsh  = (unsigned short*)(ws + 4194304);   // R1 + 2.10M floats
    unsigned short* hsh       = (unsigned short*)(ws + 2097152);   // alias (utmp dead)
    float* x_ffn_in  = ws + 8388608;                               // f32
    unsigned short* x_ffnh = (unsigned short*)(ws + 10485760);     // bf16
    float* sc        = ws + 12582912;
    int*   counts    = (int*)(ws + 12591104);
    int*   offsets   = counts + 32;
    int*   pair_p    = offsets + 32;

    // 1) attn-input RMSNorm -> bf16
    rmsnorm_kernel<<<T_TOT, 256, 0, stream>>>(x_input, attn_w, xnormh);
    // 2) QKV projection (bf16 A, bf16 out)
    mfma_gemm<0, 128, 1><<<dim3(24, 16), 256, 0, stream>>>(xnormh, W_attn, qkvh,
                                                           nullptr, T_TOT, 3072, 1024);
    // 3) RoPE in-place on bf16 q,k
    rope_kernel<<<T_TOT, 256, 0, stream>>>(qkvh);
    // 4) causal MFMA flash attention -> bf16
    attn_mfma_kernel<<<dim3(32, NHEADS), 256, 0, stream>>>(qkvh, attn_outh);
    // 5) O-projection + residual -> f32 x_ffn_in
    mfma_gemm<2, 64, 0><<<dim3(16, 16), 256, 0, stream>>>(attn_outh, W_attn_o,
                                                          x_ffn_in, x_input,
                                                          T_TOT, 1024, 1024);
    // 6) ffn RMSNorm -> bf16
    rmsnorm_kernel<<<T_TOT, 256, 0, stream>>>(x_ffn_in, ffn_w, x_ffnh);
    // 7) router scores (bf16 x)
    router_kernel<<<dim3(1024, 2), 256, 0, stream>>>(x_ffnh, p_keys, f_keys,
                                                     p_idx, f_idx, p_val, f_val,
                                                     p_bias, f_bias, sc);
    // 8) expert buckets
    buckets_kernel<<<1, 1024, 0, stream>>>(p_idx, f_idx, counts, offsets, pair_p);
    // 9a) MoE projection (wide-strip weight reads; g/u raw bf16)
    moe_proj_kernel<<<1024, 256, 0, stream>>>(x_ffnh, p_exp, f_exp,
                                              pair_p, counts, offsets,
                                              gtmp, utmp);
    // 9b) h = silu(g)*u -> bf16 h_pairs
    moe_silu_kernel<<<2048, 256, 0, stream>>>(gtmp, utmp, h_pairsh);
    // 10) y := x_ffn_in
    hipMemcpyAsync(y32, x_ffn_in, (size_t)T_TOT * DMODEL * sizeof(float),
                   hipMemcpyDeviceToDevice, stream);
    // 11) MoE down: atomic accumulate into y
    mfma_moe_down<<<1024, 256, 0, stream>>>(h_pairsh, p_exp, f_exp,
                                            pair_p, counts, offsets,
                                            sc, y32);
    // 12) shared expert gate/up -> bf16 hs
    mfma_gateup_dense<<<dim3(32, 16), 256, 0, stream>>>(x_ffnh, ffn_up, hsh);
    // 13) shared expert down, accumulate into y
    mfma_gemm<1, 64, 0><<<dim3(16, 16), 256, 0, stream>>>(hsh, ffn_down, y32,
                                                          nullptr, T_TOT, 1024, 2048);
}